// Round 7
// baseline (972.756 us; speedup 1.0000x reference)
//
#include <hip/hip_runtime.h>

// SNN forward: 3x (conv3x3 -> tdBN -> LIF -> maxpool2) + 2x (FC -> LIF)
// Shapes: x [16,32,1,32,400] -> pooled1 [16,32,6,16,200] -> pooled2 [16,32,6,8,100]
//         -> pooled3 [16,32,6,4,50] -> fc1 [16,32,100] -> fc2/out [16,32,2]
//
// Two-pass per conv block: pass-1 BN stats (LDS-tiled conv recompute, no tensor
// store), pass-2 fused conv+BN+LIF+pool (LDS-tiled). Round-5 lesson: without
// LDS staging the conv patch reads amplify ~25x at the L2<->HBM level; tiling
// dropped fuse FETCH 1.72 GB -> noise (round 6), this round does the same for
// the stats pass (974 MB -> ~50 MB predicted).

namespace {

constexpr int T = 16, B = 32;
constexpr int H1 = 32, W1 = 400, P1H = 16, P1W = 200;
constexpr int H2 = 16, W2 = 200, P2H = 8,  P2W = 100;
constexpr int H3 = 8,  W3 = 100, P3H = 4,  P3W = 50;

// stats grids: T*B * tiles-per-slice
constexpr int NWG1 = T * B * (H1 / 32) * (W1 / 100);  // 512*4  = 2048
constexpr int NWG2 = T * B * (H2 / 16) * (W2 / 40);   // 512*5  = 2560
constexpr int NWG3 = T * B * (H3 / 8) * (W3 / 50);    // 512*2  = 1024

// workspace byte offsets
constexpr size_t OFF_PART1 = 0;                                  // NWG1*12 doubles
constexpr size_t OFF_PART2 = OFF_PART1 + (size_t)NWG1 * 12 * 8;
constexpr size_t OFF_PART3 = OFF_PART2 + (size_t)NWG2 * 12 * 8;
constexpr size_t OFF_STATS = OFF_PART3 + (size_t)NWG3 * 12 * 8;  // 6x 8-float slots
constexpr size_t OFF_POOL1 = 589824;
constexpr size_t OFF_POOL2 = OFF_POOL1 + (size_t)T * B * 6 * P1H * P1W * 4;
constexpr size_t OFF_POOL3 = OFF_POOL2 + (size_t)T * B * 6 * P2H * P2W * 4;
constexpr size_t OFF_U1    = OFF_POOL3 + (size_t)T * B * 6 * P3H * P3W * 4;
constexpr size_t OFF_S1    = OFF_U1 + (size_t)T * B * 100 * 4;

} // namespace

__device__ __forceinline__ float lif_step(float& v, float y) {
  v = v + (y - v) * 0.5f;                 // tau=2, decay_input
  float sp = (v >= 1.0f) ? 1.0f : 0.0f;   // threshold 1.0
  v = (sp > 0.0f) ? 0.0f : v;             // hard reset
  return sp;
}

// Block-level reduction of 12 doubles (6 sums + 6 sumsq) -> partials[block*12..]
__device__ __forceinline__ void reduce12(double* s, double* q, double* partials) {
  __shared__ double lds[4][12];
  int lane = threadIdx.x & 63, wid = threadIdx.x >> 6;
#pragma unroll
  for (int k = 0; k < 12; k++) {
    double v = (k < 6) ? s[k] : q[k - 6];
#pragma unroll
    for (int off = 32; off >= 1; off >>= 1) v += __shfl_down(v, off, 64);
    if (lane == 0) lds[wid][k] = v;
  }
  __syncthreads();
  if (threadIdx.x < 12) {
    double v = lds[0][threadIdx.x] + lds[1][threadIdx.x] + lds[2][threadIdx.x] + lds[3][threadIdx.x];
    partials[(size_t)blockIdx.x * 12 + threadIdx.x] = v;
  }
}

// ---- pass 1: conv(NC->6) stats, LDS-tiled ----
// WG = (tb, spatial tile). Stage NC-channel tile+halo once; every thread
// computes conv for its positions (all 6 o) from LDS, accumulates sum/sumsq.
template <int NC, int H, int W, int TH, int TW>
__global__ void conv_stats_lds(const float* __restrict__ in, const float* __restrict__ wt,
                               double* __restrict__ partials) {
  constexpr int IH = TH + 2, IW = TW + 2;
  constexpr int NW = NC * 54;
  constexpr int NTH = H / TH, NTW = W / TW;
  constexpr int NT = NTH * NTW;
  __shared__ float wsm[NW];
  __shared__ float tile[NC][IH][IW];

  int tid = threadIdx.x;
  for (int k = tid; k < NW; k += blockDim.x) wsm[k] = wt[k];

  int wg = blockIdx.x;
  int tb = wg / NT;
  int ti = wg % NT;
  int ty = ti / NTW, tx = ti % NTW;
  int h0 = ty * TH - 1, w0 = tx * TW - 1;
  const float* xb = in + (size_t)tb * NC * H * W;

  for (int k = tid; k < NC * IH * IW; k += blockDim.x) {
    int i = k / (IH * IW);
    int r = k % (IH * IW);
    int rr = r / IW, cc = r % IW;
    int hh = h0 + rr, ww = w0 + cc;
    tile[i][rr][cc] = (hh >= 0 && hh < H && ww >= 0 && ww < W) ? xb[i * H * W + hh * W + ww] : 0.0f;
  }
  __syncthreads();

  double s[6] = {0, 0, 0, 0, 0, 0}, q[6] = {0, 0, 0, 0, 0, 0};
  for (int pos = tid; pos < TH * TW; pos += blockDim.x) {
    int ly = pos / TW, lx = pos % TW;
    float acc[6] = {0, 0, 0, 0, 0, 0};
#pragma unroll
    for (int i = 0; i < NC; i++) {
      float p[9];
#pragma unroll
      for (int ky = 0; ky < 3; ky++)
#pragma unroll
        for (int kx = 0; kx < 3; kx++) p[ky * 3 + kx] = tile[i][ly + ky][lx + kx];
#pragma unroll
      for (int o = 0; o < 6; o++) {
        float a = acc[o];
#pragma unroll
        for (int k2 = 0; k2 < 9; k2++) a = fmaf(p[k2], wsm[(o * NC + i) * 9 + k2], a);
        acc[o] = a;
      }
    }
#pragma unroll
    for (int o = 0; o < 6; o++) {
      s[o] += (double)acc[o];
      q[o] += (double)acc[o] * (double)acc[o];
    }
  }
  reduce12(s, q, partials);
}

// ---- finalize: partials -> mean[6], sg[6] (= gamma * rsqrt(var+eps)) ----
__global__ void finalize_stats(const double* __restrict__ partials, int nb, double n,
                               const float* __restrict__ gamma,
                               float* __restrict__ mean_out, float* __restrict__ sg_out) {
  __shared__ double lds[12][21];
  __shared__ double sums[12];
  int t = threadIdx.x;
  int k = t % 12, j = t / 12;
  if (t < 252) {
    double acc = 0.0;
    for (int b = j; b < nb; b += 21) acc += partials[(size_t)b * 12 + k];
    lds[k][j] = acc;
  }
  __syncthreads();
  if (t < 12) {
    double acc = 0.0;
#pragma unroll
    for (int j2 = 0; j2 < 21; j2++) acc += lds[t][j2];
    sums[t] = acc;
  }
  __syncthreads();
  if (t < 6) {
    double mean = sums[t] / n;
    double var = sums[t + 6] / n - mean * mean;
    double invstd = 1.0 / sqrt(var + 1e-5);
    mean_out[t] = (float)mean;
    sg_out[t] = (float)(invstd * (double)gamma[t]);
  }
}

// ---- pass 2, block 1: conv(1->6)+BN+LIF+pool, LDS-tiled ----
template <int TH, int TW>
__global__ void block1_fuse_lds(const float* __restrict__ x, const float* __restrict__ w1,
                                const float* __restrict__ mean, const float* __restrict__ sg,
                                const float* __restrict__ beta, float* __restrict__ out) {
  constexpr int NTH = P1H / TH, NTW = P1W / TW;
  constexpr int IH = 2 * TH + 2, IW = 2 * TW + 2;
  constexpr int TILE_N = IH * IW;
  constexpr int NACT = 6 * TH * TW;
  __shared__ float tile[IH][IW];

  int wg = blockIdx.x;
  int b = wg / (NTH * NTW);
  int tid2 = wg % (NTH * NTW);
  int ty = tid2 / NTW, tx = tid2 % NTW;
  int h_in0 = 2 * (ty * TH) - 1, w_in0 = 2 * (tx * TW) - 1;

  int tid = threadIdx.x;
  int o = 0, lph = 0, lpw = 0;
  if (tid < NACT) {
    o = tid / (TH * TW);
    int r = tid % (TH * TW);
    lph = r / TW; lpw = r % TW;
  }
  float w[9];
#pragma unroll
  for (int k = 0; k < 9; k++) w[k] = w1[o * 9 + k];
  float m = mean[o], s = sg[o], be = beta[o];
  float v[4] = {0.0f, 0.0f, 0.0f, 0.0f};

  for (int t = 0; t < T; t++) {
    __syncthreads();
    const float* xb = x + (size_t)(t * B + b) * (H1 * W1);
    for (int k = tid; k < TILE_N; k += blockDim.x) {
      int rr = k / IW, cc = k % IW;
      int hh = h_in0 + rr, ww = w_in0 + cc;
      tile[rr][cc] = (hh >= 0 && hh < H1 && ww >= 0 && ww < W1) ? xb[hh * W1 + ww] : 0.0f;
    }
    __syncthreads();
    if (tid < NACT) {
      int ry = 2 * lph, rx = 2 * lpw;
      float p[16];
#pragma unroll
      for (int r = 0; r < 4; r++)
#pragma unroll
        for (int c = 0; c < 4; c++) p[r * 4 + c] = tile[ry + r][rx + c];
      float smax = 0.0f;
#pragma unroll
      for (int dy = 0; dy < 2; dy++) {
#pragma unroll
        for (int dx = 0; dx < 2; dx++) {
          float acc = 0.0f;
#pragma unroll
          for (int ky = 0; ky < 3; ky++)
#pragma unroll
            for (int kx = 0; kx < 3; kx++)
              acc = fmaf(p[(dy + ky) * 4 + dx + kx], w[ky * 3 + kx], acc);
          float y = (acc - m) * s + be;
          float sp = lif_step(v[dy * 2 + dx], y);
          smax = fmaxf(smax, sp);
        }
      }
      out[((size_t)(t * B + b) * 6 + o) * (P1H * P1W) + (ty * TH + lph) * P1W + (tx * TW + lpw)] = smax;
    }
  }
}

// ---- pass 2, blocks 2/3: conv(6->6)+BN+LIF+pool, LDS-tiled ----
template <int H, int W, int PH, int PW, int TH, int TW>
__global__ void block6_fuse_lds(const float* __restrict__ in, const float* __restrict__ wt,
                                const float* __restrict__ mean, const float* __restrict__ sg,
                                const float* __restrict__ beta, float* __restrict__ out) {
  constexpr int NTH = PH / TH, NTW = PW / TW;
  constexpr int IH = 2 * TH + 2, IW = 2 * TW + 2;
  constexpr int TILE_N = IH * IW;
  constexpr int NACT = 6 * TH * TW;
  constexpr int HW = H * W;
  __shared__ float wsm[324];
  __shared__ float tile[6][IH][IW];

  for (int k = threadIdx.x; k < 324; k += blockDim.x) wsm[k] = wt[k];

  int wg = blockIdx.x;
  int b = wg / (NTH * NTW);
  int tid2 = wg % (NTH * NTW);
  int ty = tid2 / NTW, tx = tid2 % NTW;
  int h_in0 = 2 * (ty * TH) - 1, w_in0 = 2 * (tx * TW) - 1;

  int tid = threadIdx.x;
  int o = 0, lph = 0, lpw = 0;
  if (tid < NACT) {
    o = tid / (TH * TW);
    int r = tid % (TH * TW);
    lph = r / TW; lpw = r % TW;
  }
  float m = mean[o], s = sg[o], be = beta[o];
  float v[4] = {0.0f, 0.0f, 0.0f, 0.0f};

  for (int t = 0; t < T; t++) {
    __syncthreads();
    const float* xb = in + (size_t)(t * B + b) * 6 * HW;
    for (int k = tid; k < 6 * TILE_N; k += blockDim.x) {
      int i = k / TILE_N;
      int r2 = k % TILE_N;
      int rr = r2 / IW, cc = r2 % IW;
      int hh = h_in0 + rr, ww = w_in0 + cc;
      tile[i][rr][cc] = (hh >= 0 && hh < H && ww >= 0 && ww < W) ? xb[i * HW + hh * W + ww] : 0.0f;
    }
    __syncthreads();
    if (tid < NACT) {
      int ry = 2 * lph, rx = 2 * lpw;
      float acc[4] = {0.0f, 0.0f, 0.0f, 0.0f};
#pragma unroll
      for (int i = 0; i < 6; i++) {
        float p[16];
#pragma unroll
        for (int r = 0; r < 4; r++)
#pragma unroll
          for (int c = 0; c < 4; c++) p[r * 4 + c] = tile[i][ry + r][rx + c];
        const float* wo = &wsm[(o * 6 + i) * 9];
#pragma unroll
        for (int dy = 0; dy < 2; dy++)
#pragma unroll
          for (int dx = 0; dx < 2; dx++) {
            float a = acc[dy * 2 + dx];
#pragma unroll
            for (int ky = 0; ky < 3; ky++)
#pragma unroll
              for (int kx = 0; kx < 3; kx++)
                a = fmaf(p[(dy + ky) * 4 + dx + kx], wo[ky * 3 + kx], a);
            acc[dy * 2 + dx] = a;
          }
      }
      float smax = 0.0f;
#pragma unroll
      for (int p4 = 0; p4 < 4; p4++) {
        float y = (acc[p4] - m) * s + be;
        float sp = lif_step(v[p4], y);
        smax = fmaxf(smax, sp);
      }
      out[((size_t)(t * B + b) * 6 + o) * (PH * PW) + (ty * TH + lph) * PW + (tx * TW + lpw)] = smax;
    }
  }
}

// ---- FC1 matmul: u1[t,b,o] = dot(pooled3[t,b,:1200], fw1[o,:1200]) ----
__global__ void fc1_mm(const float* __restrict__ p3, const float* __restrict__ fw1,
                       float* __restrict__ u1) {
  int idx = blockIdx.x * blockDim.x + threadIdx.x;
  if (idx >= T * B * 100) return;
  int o = idx % 100;
  int tb = idx / 100;
  const float4* x4 = (const float4*)(p3 + (size_t)tb * 1200);
  const float4* w4 = (const float4*)(fw1 + (size_t)o * 1200);
  float acc = 0.0f;
#pragma unroll 4
  for (int k = 0; k < 300; k++) {
    float4 a = x4[k], w = w4[k];
    acc = fmaf(a.x, w.x, acc);
    acc = fmaf(a.y, w.y, acc);
    acc = fmaf(a.z, w.z, acc);
    acc = fmaf(a.w, w.w, acc);
  }
  u1[idx] = acc;
}

// ---- FC1 LIF scan over T per (b,o) ----
__global__ void fc1_lif(const float* __restrict__ u1, float* __restrict__ s1) {
  int idx = blockIdx.x * blockDim.x + threadIdx.x;
  if (idx >= B * 100) return;
  float v = 0.0f;
  for (int t = 0; t < T; t++) {
    float sp = lif_step(v, u1[(size_t)t * B * 100 + idx]);
    s1[(size_t)t * B * 100 + idx] = sp;
  }
}

// ---- FC2 + LIF fused: out[t,b,o] ----
__global__ void fc2_fused(const float* __restrict__ s1, const float* __restrict__ fw2,
                          float* __restrict__ outp) {
  int idx = blockIdx.x * blockDim.x + threadIdx.x;
  if (idx >= B * 2) return;
  int b = idx >> 1, o = idx & 1;
  const float* wr = fw2 + o * 100;
  float v = 0.0f;
  for (int t = 0; t < T; t++) {
    const float* sr = s1 + (size_t)(t * B + b) * 100;
    float acc = 0.0f;
#pragma unroll
    for (int k = 0; k < 100; k++) acc = fmaf(sr[k], wr[k], acc);
    float sp = lif_step(v, acc);
    outp[(size_t)(t * B + b) * 2 + o] = sp;
  }
}

extern "C" void kernel_launch(void* const* d_in, const int* in_sizes, int n_in,
                              void* d_out, int out_size, void* d_ws, size_t ws_size,
                              hipStream_t stream) {
  const float* x   = (const float*)d_in[0];
  const float* w1  = (const float*)d_in[1];
  const float* g1  = (const float*)d_in[2];
  const float* b1  = (const float*)d_in[3];
  const float* w2  = (const float*)d_in[4];
  const float* g2  = (const float*)d_in[5];
  const float* b2  = (const float*)d_in[6];
  const float* w3  = (const float*)d_in[7];
  const float* g3  = (const float*)d_in[8];
  const float* b3  = (const float*)d_in[9];
  const float* fw1 = (const float*)d_in[10];
  const float* fw2 = (const float*)d_in[11];
  float* out = (float*)d_out;

  char* ws = (char*)d_ws;
  double* part1 = (double*)(ws + OFF_PART1);
  double* part2 = (double*)(ws + OFF_PART2);
  double* part3 = (double*)(ws + OFF_PART3);
  float* mean1 = (float*)(ws + OFF_STATS + 0);
  float* sg1   = (float*)(ws + OFF_STATS + 32);
  float* mean2 = (float*)(ws + OFF_STATS + 64);
  float* sg2   = (float*)(ws + OFF_STATS + 96);
  float* mean3 = (float*)(ws + OFF_STATS + 128);
  float* sg3   = (float*)(ws + OFF_STATS + 160);
  float* pool1 = (float*)(ws + OFF_POOL1);
  float* pool2 = (float*)(ws + OFF_POOL2);
  float* pool3 = (float*)(ws + OFF_POOL3);
  float* u1    = (float*)(ws + OFF_U1);
  float* s1    = (float*)(ws + OFF_S1);

  // Block 1
  conv_stats_lds<1, H1, W1, 32, 100><<<NWG1, 256, 0, stream>>>(x, w1, part1);
  finalize_stats<<<1, 256, 0, stream>>>(part1, NWG1, (double)T * B * H1 * W1, g1, mean1, sg1);
  {
    int nwg = B * (P1H / 4) * (P1W / 10);  // 2560
    block1_fuse_lds<4, 10><<<nwg, 256, 0, stream>>>(x, w1, mean1, sg1, b1, pool1);
  }
  // Block 2
  conv_stats_lds<6, H2, W2, 16, 40><<<NWG2, 256, 0, stream>>>(pool1, w2, part2);
  finalize_stats<<<1, 256, 0, stream>>>(part2, NWG2, (double)T * B * H2 * W2, g2, mean2, sg2);
  {
    int nwg = B * (P2H / 4) * (P2W / 10);  // 640
    block6_fuse_lds<H2, W2, P2H, P2W, 4, 10><<<nwg, 256, 0, stream>>>(pool1, w2, mean2, sg2, b2, pool2);
  }
  // Block 3
  conv_stats_lds<6, H3, W3, 8, 50><<<NWG3, 256, 0, stream>>>(pool2, w3, part3);
  finalize_stats<<<1, 256, 0, stream>>>(part3, NWG3, (double)T * B * H3 * W3, g3, mean3, sg3);
  {
    int nwg = B * (P3H / 4) * (P3W / 10);  // 160
    block6_fuse_lds<H3, W3, P3H, P3W, 4, 10><<<nwg, 256, 0, stream>>>(pool2, w3, mean3, sg3, b3, pool3);
  }
  // FC head
  {
    int n = T * B * 100;
    fc1_mm<<<(n + 255) / 256, 256, 0, stream>>>(pool3, fw1, u1);
  }
  {
    int n = B * 100;
    fc1_lif<<<(n + 255) / 256, 256, 0, stream>>>(u1, s1);
  }
  fc2_fused<<<1, 64, 0, stream>>>(s1, fw2, out);
}

// Round 8
// 726.816 us; speedup vs baseline: 1.3384x; 1.3384x over previous
//
#include <hip/hip_runtime.h>

// SNN forward: 3x (conv3x3 -> tdBN -> LIF -> maxpool2) + 2x (FC -> LIF)
// x [16,32,1,32,400] -> pool1 [16,32,6,16,200] -> pool2 [16,32,6,8,100]
//   -> pool3 [16,32,6,4,50] -> fc1 [16,32,100] -> out [16,32,2]
//
// Round-8 structure: stats for block2/block3 are folded INTO fuse1/fuse2 via
// halo-pool recompute (each WG computes a 1-ring halo of pooled values so it
// can evaluate the next conv at its owned positions and accumulate BN stats
// from LDS, with no global re-read). Kernels: stats1, fin1, fuse1(+stats2),
// fin2, fuse2(+stats3), fin3, block3fuse, fc1_mm, fc1_lif, fc2. (12 -> 10)

namespace {

constexpr int T = 16, B = 32;
constexpr int H1 = 32, W1 = 400, P1H = 16, P1W = 200;
constexpr int H2 = 16, W2 = 200, P2H = 8,  P2W = 100;
constexpr int H3 = 8,  W3 = 100, P3H = 4,  P3W = 50;

constexpr int NWG_S1 = T * B * (H1 / 32) * (W1 / 100);  // 2048
constexpr int NWG_F1 = B * (P1H / 2) * (P1W / 8);       // 6400
constexpr int NWG_F2 = B * (P2H / 2) * (P2W / 5);       // 2560

constexpr size_t OFF_PART1  = 0;                                     // 2048*96
constexpr size_t OFF_PARTF1 = OFF_PART1 + (size_t)NWG_S1 * 12 * 8;   // 6400*96
constexpr size_t OFF_PARTF2 = OFF_PARTF1 + (size_t)NWG_F1 * 12 * 8;  // 2560*96
constexpr size_t OFF_STATS  = OFF_PARTF2 + (size_t)NWG_F2 * 12 * 8;
constexpr size_t OFF_POOL1  = 1310720;
constexpr size_t OFF_POOL2  = OFF_POOL1 + (size_t)T * B * 6 * P1H * P1W * 4;
constexpr size_t OFF_POOL3  = OFF_POOL2 + (size_t)T * B * 6 * P2H * P2W * 4;
constexpr size_t OFF_U1     = OFF_POOL3 + (size_t)T * B * 6 * P3H * P3W * 4;
constexpr size_t OFF_S1     = OFF_U1 + (size_t)T * B * 100 * 4;

} // namespace

__device__ __forceinline__ float lif_step(float& v, float y) {
  v = v + (y - v) * 0.5f;                 // tau=2, decay_input
  float sp = (v >= 1.0f) ? 1.0f : 0.0f;   // threshold 1.0
  v = (sp > 0.0f) ? 0.0f : v;             // hard reset
  return sp;
}

// Block reduction of per-thread 6+6 double counters (array form, unrolled idx).
__device__ __forceinline__ void reduce12(double* s, double* q, double* partials) {
  __shared__ double lds[4][12];
  int lane = threadIdx.x & 63, wid = threadIdx.x >> 6;
#pragma unroll
  for (int k = 0; k < 12; k++) {
    double v = (k < 6) ? s[k] : q[k - 6];
#pragma unroll
    for (int off = 32; off >= 1; off >>= 1) v += __shfl_down(v, off, 64);
    if (lane == 0) lds[wid][k] = v;
  }
  __syncthreads();
  if (threadIdx.x < 12) {
    partials[(size_t)blockIdx.x * 12 + threadIdx.x] =
        lds[0][threadIdx.x] + lds[1][threadIdx.x] + lds[2][threadIdx.x] + lds[3][threadIdx.x];
  }
}

// Select form: each thread contributes (s_acc,q_acc) only to counter `oidx`
// (oidx<0 -> contributes zeros). Avoids runtime-indexed register arrays.
__device__ __forceinline__ void reduce12_sel(int oidx, double s_acc, double q_acc,
                                             double* partials) {
  __shared__ double lds[4][12];
  int lane = threadIdx.x & 63, wid = threadIdx.x >> 6;
#pragma unroll
  for (int k = 0; k < 12; k++) {
    double v = (k == oidx) ? s_acc : ((k == oidx + 6) ? q_acc : 0.0);
#pragma unroll
    for (int off = 32; off >= 1; off >>= 1) v += __shfl_down(v, off, 64);
    if (lane == 0) lds[wid][k] = v;
  }
  __syncthreads();
  if (threadIdx.x < 12) {
    partials[(size_t)blockIdx.x * 12 + threadIdx.x] =
        lds[0][threadIdx.x] + lds[1][threadIdx.x] + lds[2][threadIdx.x] + lds[3][threadIdx.x];
  }
}

// ---- block1 stats: conv(1->6) over x, LDS-tiled ----
template <int NC, int H, int W, int TH, int TW>
__global__ void conv_stats_lds(const float* __restrict__ in, const float* __restrict__ wt,
                               double* __restrict__ partials) {
  constexpr int IH = TH + 2, IW = TW + 2;
  constexpr int NW = NC * 54;
  constexpr int NTH = H / TH, NTW = W / TW;
  constexpr int NT = NTH * NTW;
  __shared__ float wsm[NW];
  __shared__ float tile[NC][IH][IW];

  int tid = threadIdx.x;
  for (int k = tid; k < NW; k += blockDim.x) wsm[k] = wt[k];

  int wg = blockIdx.x;
  int tb = wg / NT;
  int ti = wg % NT;
  int ty = ti / NTW, tx = ti % NTW;
  int h0 = ty * TH - 1, w0 = tx * TW - 1;
  const float* xb = in + (size_t)tb * NC * H * W;

  for (int k = tid; k < NC * IH * IW; k += blockDim.x) {
    int i = k / (IH * IW);
    int r = k % (IH * IW);
    int rr = r / IW, cc = r % IW;
    int hh = h0 + rr, ww = w0 + cc;
    tile[i][rr][cc] = (hh >= 0 && hh < H && ww >= 0 && ww < W) ? xb[i * H * W + hh * W + ww] : 0.0f;
  }
  __syncthreads();

  double s[6] = {0, 0, 0, 0, 0, 0}, q[6] = {0, 0, 0, 0, 0, 0};
  for (int pos = tid; pos < TH * TW; pos += blockDim.x) {
    int ly = pos / TW, lx = pos % TW;
    float acc[6] = {0, 0, 0, 0, 0, 0};
#pragma unroll
    for (int i = 0; i < NC; i++) {
      float p[9];
#pragma unroll
      for (int ky = 0; ky < 3; ky++)
#pragma unroll
        for (int kx = 0; kx < 3; kx++) p[ky * 3 + kx] = tile[i][ly + ky][lx + kx];
#pragma unroll
      for (int o = 0; o < 6; o++) {
        float a = acc[o];
#pragma unroll
        for (int k2 = 0; k2 < 9; k2++) a = fmaf(p[k2], wsm[(o * NC + i) * 9 + k2], a);
        acc[o] = a;
      }
    }
#pragma unroll
    for (int o = 0; o < 6; o++) {
      s[o] += (double)acc[o];
      q[o] += (double)acc[o] * (double)acc[o];
    }
  }
  reduce12(s, q, partials);
}

// ---- finalize: partials -> mean[6], sg[6] ----
__global__ void finalize_stats(const double* __restrict__ partials, int nb, double n,
                               const float* __restrict__ gamma,
                               float* __restrict__ mean_out, float* __restrict__ sg_out) {
  __shared__ double lds[12][21];
  __shared__ double sums[12];
  int t = threadIdx.x;
  int k = t % 12, j = t / 12;
  if (t < 252) {
    double acc = 0.0;
    for (int b = j; b < nb; b += 21) acc += partials[(size_t)b * 12 + k];
    lds[k][j] = acc;
  }
  __syncthreads();
  if (t < 12) {
    double acc = 0.0;
#pragma unroll
    for (int j2 = 0; j2 < 21; j2++) acc += lds[t][j2];
    sums[t] = acc;
  }
  __syncthreads();
  if (t < 6) {
    double mean = sums[t] / n;
    double var = sums[t + 6] / n - mean * mean;
    double invstd = 1.0 / sqrt(var + 1e-5);
    mean_out[t] = (float)mean;
    sg_out[t] = (float)(invstd * (double)gamma[t]);
  }
}

// ---- fuse1 + stats2: conv1+BN+LIF+pool (with 1-ring pooled halo) and
//      conv2-on-pooled-tile stats accumulation, all from LDS ----
// WG: (b, oy 0..7, ox 0..24); own pooled 2x8 at (2oy, 8ox); halo tile 4x10/ch.
__global__ void fuse1_stats(const float* __restrict__ x, const float* __restrict__ w1g,
                            const float* __restrict__ w2g,
                            const float* __restrict__ mean1, const float* __restrict__ sg1,
                            const float* __restrict__ beta1,
                            float* __restrict__ pool1, double* __restrict__ partials2) {
  __shared__ float wsm1[54];
  __shared__ float wsm2[324];
  __shared__ float tile[10][22];
  __shared__ float phl[6][4][10];

  int tid = threadIdx.x;
  for (int k = tid; k < 54; k += 256) wsm1[k] = w1g[k];
  for (int k = tid; k < 324; k += 256) wsm2[k] = w2g[k];
  __syncthreads();

  int wg = blockIdx.x;
  int b = wg / 200;
  int rem = wg % 200;
  int oy = rem / 25, ox = rem % 25;
  int iy0 = 4 * oy - 3, ix0 = 16 * ox - 3;

  bool active = tid < 240;
  int ch = 0, hy = 0, hx = 0, py = 0, px = 0;
  bool pvalid = false, own = false;
  if (active) {
    ch = tid / 40;
    int r = tid % 40;
    hy = r / 10; hx = r % 10;
    py = 2 * oy - 1 + hy; px = 8 * ox - 1 + hx;
    pvalid = (py >= 0 && py < P1H && px >= 0 && px < P1W);
    own = (hy >= 1 && hy <= 2 && hx >= 1 && hx <= 8);
  }
  float wv[9];
#pragma unroll
  for (int k = 0; k < 9; k++) wv[k] = active ? wsm1[ch * 9 + k] : 0.0f;
  float m = active ? mean1[ch] : 0.0f;
  float sc = active ? sg1[ch] : 0.0f;
  float be = active ? beta1[ch] : 0.0f;

  int oidx = (tid < 96) ? (tid / 16) : -1;
  int sy = (tid & 15) >> 3, sx = tid & 7;

  float v[4] = {0.0f, 0.0f, 0.0f, 0.0f};
  double s_acc = 0.0, q_acc = 0.0;

  for (int t = 0; t < T; t++) {
    __syncthreads();  // protect tile/phl from previous-iter readers
    const float* xb = x + (size_t)(t * B + b) * (H1 * W1);
    for (int k = tid; k < 220; k += 256) {
      int rr = k / 22, cc = k % 22;
      int hh = iy0 + rr, ww = ix0 + cc;
      tile[rr][cc] = (hh >= 0 && hh < H1 && ww >= 0 && ww < W1) ? xb[hh * W1 + ww] : 0.0f;
    }
    __syncthreads();
    if (active) {
      float smax = 0.0f;
      if (pvalid) {
        int ry = 2 * hy, rx = 2 * hx;
        float p[16];
#pragma unroll
        for (int r = 0; r < 4; r++)
#pragma unroll
          for (int c = 0; c < 4; c++) p[r * 4 + c] = tile[ry + r][rx + c];
#pragma unroll
        for (int dy = 0; dy < 2; dy++) {
#pragma unroll
          for (int dx = 0; dx < 2; dx++) {
            float acc = 0.0f;
#pragma unroll
            for (int ky = 0; ky < 3; ky++)
#pragma unroll
              for (int kx = 0; kx < 3; kx++)
                acc = fmaf(p[(dy + ky) * 4 + dx + kx], wv[ky * 3 + kx], acc);
            float y = (acc - m) * sc + be;
            float sp = lif_step(v[dy * 2 + dx], y);
            smax = fmaxf(smax, sp);
          }
        }
      }
      phl[ch][hy][hx] = smax;
      if (own)
        pool1[((size_t)(t * B + b) * 6 + ch) * (P1H * P1W) + py * P1W + px] = smax;
    }
    __syncthreads();
    if (oidx >= 0) {  // conv2 at own pooled position (sy,sx), out-ch oidx
      float acc = 0.0f;
#pragma unroll
      for (int i = 0; i < 6; i++) {
        const float* wo = &wsm2[(oidx * 6 + i) * 9];
#pragma unroll
        for (int ky = 0; ky < 3; ky++)
#pragma unroll
          for (int kx = 0; kx < 3; kx++)
            acc = fmaf(phl[i][sy + ky][sx + kx], wo[ky * 3 + kx], acc);
      }
      s_acc += (double)acc;
      q_acc += (double)acc * (double)acc;
    }
  }
  __syncthreads();
  reduce12_sel(oidx, s_acc, q_acc, partials2);
}

// ---- fuse2 + stats3: conv2+BN+LIF+pool (pooled halo) + conv3 stats ----
// WG: (b, oy 0..3, ox 0..19); own pooled 2x5 at (2oy, 5ox); halo tile 4x7/ch.
__global__ void fuse2_stats(const float* __restrict__ in, const float* __restrict__ w2g,
                            const float* __restrict__ w3g,
                            const float* __restrict__ mean2, const float* __restrict__ sg2,
                            const float* __restrict__ beta2,
                            float* __restrict__ pool2, double* __restrict__ partials3) {
  __shared__ float wsm2[324];
  __shared__ float wsm3[324];
  __shared__ float tile[6][10][16];
  __shared__ float phl[6][4][7];

  int tid = threadIdx.x;
  for (int k = tid; k < 324; k += 256) { wsm2[k] = w2g[k]; wsm3[k] = w3g[k]; }
  __syncthreads();

  int wg = blockIdx.x;
  int b = wg / 80;
  int rem = wg % 80;
  int oy = rem / 20, ox = rem % 20;
  int iy0 = 4 * oy - 3, ix0 = 10 * ox - 3;

  bool active = tid < 168;
  int ch = 0, hy = 0, hx = 0, py = 0, px = 0;
  bool pvalid = false, own = false;
  if (active) {
    ch = tid / 28;
    int r = tid % 28;
    hy = r / 7; hx = r % 7;
    py = 2 * oy - 1 + hy; px = 5 * ox - 1 + hx;
    pvalid = (py >= 0 && py < P2H && px >= 0 && px < P2W);
    own = (hy >= 1 && hy <= 2 && hx >= 1 && hx <= 5);
  }
  float m = active ? mean2[ch] : 0.0f;
  float sc = active ? sg2[ch] : 0.0f;
  float be = active ? beta2[ch] : 0.0f;

  int oidx = (tid < 60) ? (tid / 10) : -1;
  int pp = tid % 10;
  int sy = pp / 5, sx = pp % 5;

  float v[4] = {0.0f, 0.0f, 0.0f, 0.0f};
  double s_acc = 0.0, q_acc = 0.0;
  constexpr int HW = H2 * W2;

  for (int t = 0; t < T; t++) {
    __syncthreads();
    const float* xb = in + (size_t)(t * B + b) * 6 * HW;
    for (int k = tid; k < 6 * 160; k += 256) {
      int i = k / 160;
      int r2 = k % 160;
      int rr = r2 / 16, cc = r2 % 16;
      int hh = iy0 + rr, ww = ix0 + cc;
      tile[i][rr][cc] = (hh >= 0 && hh < H2 && ww >= 0 && ww < W2) ? xb[i * HW + hh * W2 + ww] : 0.0f;
    }
    __syncthreads();
    if (active) {
      float smax = 0.0f;
      if (pvalid) {
        int ry = 2 * hy, rx = 2 * hx;
        float acc4[4] = {0.0f, 0.0f, 0.0f, 0.0f};
#pragma unroll
        for (int i = 0; i < 6; i++) {
          float p[16];
#pragma unroll
          for (int r = 0; r < 4; r++)
#pragma unroll
            for (int c = 0; c < 4; c++) p[r * 4 + c] = tile[i][ry + r][rx + c];
          const float* wo = &wsm2[(ch * 6 + i) * 9];
#pragma unroll
          for (int dy = 0; dy < 2; dy++)
#pragma unroll
            for (int dx = 0; dx < 2; dx++) {
              float a = acc4[dy * 2 + dx];
#pragma unroll
              for (int ky = 0; ky < 3; ky++)
#pragma unroll
                for (int kx = 0; kx < 3; kx++)
                  a = fmaf(p[(dy + ky) * 4 + dx + kx], wo[ky * 3 + kx], a);
              acc4[dy * 2 + dx] = a;
            }
        }
#pragma unroll
        for (int p4 = 0; p4 < 4; p4++) {
          float y = (acc4[p4] - m) * sc + be;
          float sp = lif_step(v[p4], y);
          smax = fmaxf(smax, sp);
        }
      }
      phl[ch][hy][hx] = smax;
      if (own)
        pool2[((size_t)(t * B + b) * 6 + ch) * (P2H * P2W) + py * P2W + px] = smax;
    }
    __syncthreads();
    if (oidx >= 0) {  // conv3 at own pooled position (sy,sx), out-ch oidx
      float acc = 0.0f;
#pragma unroll
      for (int i = 0; i < 6; i++) {
        const float* wo = &wsm3[(oidx * 6 + i) * 9];
#pragma unroll
        for (int ky = 0; ky < 3; ky++)
#pragma unroll
          for (int kx = 0; kx < 3; kx++)
            acc = fmaf(phl[i][sy + ky][sx + kx], wo[ky * 3 + kx], acc);
      }
      s_acc += (double)acc;
      q_acc += (double)acc * (double)acc;
    }
  }
  __syncthreads();
  reduce12_sel(oidx, s_acc, q_acc, partials3);
}

// ---- block 3 fuse: conv(6->6)+BN+LIF+pool, LDS-tiled (unchanged) ----
template <int H, int W, int PH, int PW, int TH, int TW>
__global__ void block6_fuse_lds(const float* __restrict__ in, const float* __restrict__ wt,
                                const float* __restrict__ mean, const float* __restrict__ sg,
                                const float* __restrict__ beta, float* __restrict__ out) {
  constexpr int NTH = PH / TH, NTW = PW / TW;
  constexpr int IH = 2 * TH + 2, IW = 2 * TW + 2;
  constexpr int TILE_N = IH * IW;
  constexpr int NACT = 6 * TH * TW;
  constexpr int HW = H * W;
  __shared__ float wsm[324];
  __shared__ float tile[6][IH][IW];

  for (int k = threadIdx.x; k < 324; k += blockDim.x) wsm[k] = wt[k];

  int wg = blockIdx.x;
  int b = wg / (NTH * NTW);
  int tid2 = wg % (NTH * NTW);
  int ty = tid2 / NTW, tx = tid2 % NTW;
  int h_in0 = 2 * (ty * TH) - 1, w_in0 = 2 * (tx * TW) - 1;

  int tid = threadIdx.x;
  int o = 0, lph = 0, lpw = 0;
  if (tid < NACT) {
    o = tid / (TH * TW);
    int r = tid % (TH * TW);
    lph = r / TW; lpw = r % TW;
  }
  float m = mean[o], s = sg[o], be = beta[o];
  float v[4] = {0.0f, 0.0f, 0.0f, 0.0f};

  for (int t = 0; t < T; t++) {
    __syncthreads();
    const float* xb = in + (size_t)(t * B + b) * 6 * HW;
    for (int k = tid; k < 6 * TILE_N; k += blockDim.x) {
      int i = k / TILE_N;
      int r2 = k % TILE_N;
      int rr = r2 / IW, cc = r2 % IW;
      int hh = h_in0 + rr, ww = w_in0 + cc;
      tile[i][rr][cc] = (hh >= 0 && hh < H && ww >= 0 && ww < W) ? xb[i * HW + hh * W + ww] : 0.0f;
    }
    __syncthreads();
    if (tid < NACT) {
      int ry = 2 * lph, rx = 2 * lpw;
      float acc[4] = {0.0f, 0.0f, 0.0f, 0.0f};
#pragma unroll
      for (int i = 0; i < 6; i++) {
        float p[16];
#pragma unroll
        for (int r = 0; r < 4; r++)
#pragma unroll
          for (int c = 0; c < 4; c++) p[r * 4 + c] = tile[i][ry + r][rx + c];
        const float* wo = &wsm[(o * 6 + i) * 9];
#pragma unroll
        for (int dy = 0; dy < 2; dy++)
#pragma unroll
          for (int dx = 0; dx < 2; dx++) {
            float a = acc[dy * 2 + dx];
#pragma unroll
            for (int ky = 0; ky < 3; ky++)
#pragma unroll
              for (int kx = 0; kx < 3; kx++)
                a = fmaf(p[(dy + ky) * 4 + dx + kx], wo[ky * 3 + kx], a);
            acc[dy * 2 + dx] = a;
          }
      }
      float smax = 0.0f;
#pragma unroll
      for (int p4 = 0; p4 < 4; p4++) {
        float y = (acc[p4] - m) * s + be;
        float sp = lif_step(v[p4], y);
        smax = fmaxf(smax, sp);
      }
      out[((size_t)(t * B + b) * 6 + o) * (PH * PW) + (ty * TH + lph) * PW + (tx * TW + lpw)] = smax;
    }
  }
}

// ---- FC head ----
__global__ void fc1_mm(const float* __restrict__ p3, const float* __restrict__ fw1,
                       float* __restrict__ u1) {
  int idx = blockIdx.x * blockDim.x + threadIdx.x;
  if (idx >= T * B * 100) return;
  int o = idx % 100;
  int tb = idx / 100;
  const float4* x4 = (const float4*)(p3 + (size_t)tb * 1200);
  const float4* w4 = (const float4*)(fw1 + (size_t)o * 1200);
  float acc = 0.0f;
#pragma unroll 4
  for (int k = 0; k < 300; k++) {
    float4 a = x4[k], w = w4[k];
    acc = fmaf(a.x, w.x, acc);
    acc = fmaf(a.y, w.y, acc);
    acc = fmaf(a.z, w.z, acc);
    acc = fmaf(a.w, w.w, acc);
  }
  u1[idx] = acc;
}

__global__ void fc1_lif(const float* __restrict__ u1, float* __restrict__ s1) {
  int idx = blockIdx.x * blockDim.x + threadIdx.x;
  if (idx >= B * 100) return;
  float v = 0.0f;
  for (int t = 0; t < T; t++) {
    float sp = lif_step(v, u1[(size_t)t * B * 100 + idx]);
    s1[(size_t)t * B * 100 + idx] = sp;
  }
}

__global__ void fc2_fused(const float* __restrict__ s1, const float* __restrict__ fw2,
                          float* __restrict__ outp) {
  int idx = blockIdx.x * blockDim.x + threadIdx.x;
  if (idx >= B * 2) return;
  int b = idx >> 1, o = idx & 1;
  const float* wr = fw2 + o * 100;
  float v = 0.0f;
  for (int t = 0; t < T; t++) {
    const float* sr = s1 + (size_t)(t * B + b) * 100;
    float acc = 0.0f;
#pragma unroll
    for (int k = 0; k < 100; k++) acc = fmaf(sr[k], wr[k], acc);
    float sp = lif_step(v, acc);
    outp[(size_t)(t * B + b) * 2 + o] = sp;
  }
}

extern "C" void kernel_launch(void* const* d_in, const int* in_sizes, int n_in,
                              void* d_out, int out_size, void* d_ws, size_t ws_size,
                              hipStream_t stream) {
  const float* x   = (const float*)d_in[0];
  const float* w1  = (const float*)d_in[1];
  const float* g1  = (const float*)d_in[2];
  const float* b1  = (const float*)d_in[3];
  const float* w2  = (const float*)d_in[4];
  const float* g2  = (const float*)d_in[5];
  const float* b2  = (const float*)d_in[6];
  const float* w3  = (const float*)d_in[7];
  const float* g3  = (const float*)d_in[8];
  const float* b3  = (const float*)d_in[9];
  const float* fw1 = (const float*)d_in[10];
  const float* fw2 = (const float*)d_in[11];
  float* out = (float*)d_out;

  char* ws = (char*)d_ws;
  double* part1  = (double*)(ws + OFF_PART1);
  double* partf1 = (double*)(ws + OFF_PARTF1);
  double* partf2 = (double*)(ws + OFF_PARTF2);
  float* mean1 = (float*)(ws + OFF_STATS + 0);
  float* sg1   = (float*)(ws + OFF_STATS + 32);
  float* mean2 = (float*)(ws + OFF_STATS + 64);
  float* sg2   = (float*)(ws + OFF_STATS + 96);
  float* mean3 = (float*)(ws + OFF_STATS + 128);
  float* sg3   = (float*)(ws + OFF_STATS + 160);
  float* pool1 = (float*)(ws + OFF_POOL1);
  float* pool2 = (float*)(ws + OFF_POOL2);
  float* pool3 = (float*)(ws + OFF_POOL3);
  float* u1    = (float*)(ws + OFF_U1);
  float* s1    = (float*)(ws + OFF_S1);

  // Block 1 stats + finalize
  conv_stats_lds<1, H1, W1, 32, 100><<<NWG_S1, 256, 0, stream>>>(x, w1, part1);
  finalize_stats<<<1, 256, 0, stream>>>(part1, NWG_S1, (double)T * B * H1 * W1, g1, mean1, sg1);
  // fuse1 (+ stats for block2)
  fuse1_stats<<<NWG_F1, 256, 0, stream>>>(x, w1, w2, mean1, sg1, b1, pool1, partf1);
  finalize_stats<<<1, 256, 0, stream>>>(partf1, NWG_F1, (double)T * B * H2 * W2, g2, mean2, sg2);
  // fuse2 (+ stats for block3)
  fuse2_stats<<<NWG_F2, 256, 0, stream>>>(pool1, w2, w3, mean2, sg2, b2, pool2, partf2);
  finalize_stats<<<1, 256, 0, stream>>>(partf2, NWG_F2, (double)T * B * H3 * W3, g3, mean3, sg3);
  // Block 3 fuse
  {
    int nwg = B * (P3H / 4) * (P3W / 10);  // 160
    block6_fuse_lds<H3, W3, P3H, P3W, 4, 10><<<nwg, 256, 0, stream>>>(pool2, w3, mean3, sg3, b3, pool3);
  }
  // FC head
  {
    int n = T * B * 100;
    fc1_mm<<<(n + 255) / 256, 256, 0, stream>>>(pool3, fw1, u1);
  }
  {
    int n = B * 100;
    fc1_lif<<<(n + 255) / 256, 256, 0, stream>>>(u1, s1);
  }
  fc2_fused<<<1, 64, 0, stream>>>(s1, fw2, out);
}

// Round 9
// 711.662 us; speedup vs baseline: 1.3669x; 1.0213x over previous
//
#include <hip/hip_runtime.h>

// SNN forward: 3x (conv3x3 -> tdBN -> LIF -> maxpool2) + 2x (FC -> LIF)
// x [16,32,1,32,400] -> pool1 [16,32,6,16,200] -> pool2 [16,32,6,8,100]
//   -> pool3 [16,32,6,4,50] -> fc1 [16,32,100] -> out [16,32,2]
//
// Round-9: LDS bank-conflict fix. Round-8 profile: fuse2_stats lost ~36% of
// all CU cycles to SQ_LDS_BANK_CONFLICT=5.5e7 — tile row stride 16 words makes
// (2*hy+r)*16 = 0 mod 32 banks (hy and channel vanish from the bank index ->
// ~8-way serialization on every conv tile read). Fix: odd row strides chosen
// so the row term spreads banks: fuse2 stride 21 (10*hy mod 32), fuse1 stride
// 23 (14*hy), same padding for block3-fuse and stats1 tiles.

namespace {

constexpr int T = 16, B = 32;
constexpr int H1 = 32, W1 = 400, P1H = 16, P1W = 200;
constexpr int H2 = 16, W2 = 200, P2H = 8,  P2W = 100;
constexpr int H3 = 8,  W3 = 100, P3H = 4,  P3W = 50;

constexpr int NWG_S1 = T * B * (H1 / 32) * (W1 / 100);  // 2048
constexpr int NWG_F1 = B * (P1H / 2) * (P1W / 8);       // 6400
constexpr int NWG_F2 = B * (P2H / 2) * (P2W / 5);       // 2560

constexpr size_t OFF_PART1  = 0;                                     // 2048*96
constexpr size_t OFF_PARTF1 = OFF_PART1 + (size_t)NWG_S1 * 12 * 8;   // 6400*96
constexpr size_t OFF_PARTF2 = OFF_PARTF1 + (size_t)NWG_F1 * 12 * 8;  // 2560*96
constexpr size_t OFF_STATS  = OFF_PARTF2 + (size_t)NWG_F2 * 12 * 8;
constexpr size_t OFF_POOL1  = 1310720;
constexpr size_t OFF_POOL2  = OFF_POOL1 + (size_t)T * B * 6 * P1H * P1W * 4;
constexpr size_t OFF_POOL3  = OFF_POOL2 + (size_t)T * B * 6 * P2H * P2W * 4;
constexpr size_t OFF_U1     = OFF_POOL3 + (size_t)T * B * 6 * P3H * P3W * 4;
constexpr size_t OFF_S1     = OFF_U1 + (size_t)T * B * 100 * 4;

} // namespace

__device__ __forceinline__ float lif_step(float& v, float y) {
  v = v + (y - v) * 0.5f;                 // tau=2, decay_input
  float sp = (v >= 1.0f) ? 1.0f : 0.0f;   // threshold 1.0
  v = (sp > 0.0f) ? 0.0f : v;             // hard reset
  return sp;
}

// Block reduction of per-thread 6+6 double counters (array form).
__device__ __forceinline__ void reduce12(double* s, double* q, double* partials) {
  __shared__ double lds[4][12];
  int lane = threadIdx.x & 63, wid = threadIdx.x >> 6;
#pragma unroll
  for (int k = 0; k < 12; k++) {
    double v = (k < 6) ? s[k] : q[k - 6];
#pragma unroll
    for (int off = 32; off >= 1; off >>= 1) v += __shfl_down(v, off, 64);
    if (lane == 0) lds[wid][k] = v;
  }
  __syncthreads();
  if (threadIdx.x < 12) {
    partials[(size_t)blockIdx.x * 12 + threadIdx.x] =
        lds[0][threadIdx.x] + lds[1][threadIdx.x] + lds[2][threadIdx.x] + lds[3][threadIdx.x];
  }
}

// Select form: thread contributes (s_acc,q_acc) only to counter `oidx` (<0: none).
__device__ __forceinline__ void reduce12_sel(int oidx, double s_acc, double q_acc,
                                             double* partials) {
  __shared__ double lds[4][12];
  int lane = threadIdx.x & 63, wid = threadIdx.x >> 6;
#pragma unroll
  for (int k = 0; k < 12; k++) {
    double v = (k == oidx) ? s_acc : ((k == oidx + 6) ? q_acc : 0.0);
#pragma unroll
    for (int off = 32; off >= 1; off >>= 1) v += __shfl_down(v, off, 64);
    if (lane == 0) lds[wid][k] = v;
  }
  __syncthreads();
  if (threadIdx.x < 12) {
    partials[(size_t)blockIdx.x * 12 + threadIdx.x] =
        lds[0][threadIdx.x] + lds[1][threadIdx.x] + lds[2][threadIdx.x] + lds[3][threadIdx.x];
  }
}

// ---- block1 stats: conv(1->6) over x, LDS-tiled (odd-padded stride) ----
template <int NC, int H, int W, int TH, int TW>
__global__ void conv_stats_lds(const float* __restrict__ in, const float* __restrict__ wt,
                               double* __restrict__ partials) {
  constexpr int IH = TH + 2, IW = TW + 2;
  constexpr int IWP = (IW & 1) ? IW : IW + 1;  // odd row stride
  constexpr int NW = NC * 54;
  constexpr int NTH = H / TH, NTW = W / TW;
  constexpr int NT = NTH * NTW;
  __shared__ float wsm[NW];
  __shared__ float tile[NC][IH][IWP];

  int tid = threadIdx.x;
  for (int k = tid; k < NW; k += blockDim.x) wsm[k] = wt[k];

  int wg = blockIdx.x;
  int tb = wg / NT;
  int ti = wg % NT;
  int ty = ti / NTW, tx = ti % NTW;
  int h0 = ty * TH - 1, w0 = tx * TW - 1;
  const float* xb = in + (size_t)tb * NC * H * W;

  for (int k = tid; k < NC * IH * IW; k += blockDim.x) {
    int i = k / (IH * IW);
    int r = k % (IH * IW);
    int rr = r / IW, cc = r % IW;
    int hh = h0 + rr, ww = w0 + cc;
    tile[i][rr][cc] = (hh >= 0 && hh < H && ww >= 0 && ww < W) ? xb[i * H * W + hh * W + ww] : 0.0f;
  }
  __syncthreads();

  double s[6] = {0, 0, 0, 0, 0, 0}, q[6] = {0, 0, 0, 0, 0, 0};
  for (int pos = tid; pos < TH * TW; pos += blockDim.x) {
    int ly = pos / TW, lx = pos % TW;
    float acc[6] = {0, 0, 0, 0, 0, 0};
#pragma unroll
    for (int i = 0; i < NC; i++) {
      float p[9];
#pragma unroll
      for (int ky = 0; ky < 3; ky++)
#pragma unroll
        for (int kx = 0; kx < 3; kx++) p[ky * 3 + kx] = tile[i][ly + ky][lx + kx];
#pragma unroll
      for (int o = 0; o < 6; o++) {
        float a = acc[o];
#pragma unroll
        for (int k2 = 0; k2 < 9; k2++) a = fmaf(p[k2], wsm[(o * NC + i) * 9 + k2], a);
        acc[o] = a;
      }
    }
#pragma unroll
    for (int o = 0; o < 6; o++) {
      s[o] += (double)acc[o];
      q[o] += (double)acc[o] * (double)acc[o];
    }
  }
  reduce12(s, q, partials);
}

// ---- finalize: partials -> mean[6], sg[6] ----
__global__ void finalize_stats(const double* __restrict__ partials, int nb, double n,
                               const float* __restrict__ gamma,
                               float* __restrict__ mean_out, float* __restrict__ sg_out) {
  __shared__ double lds[12][21];
  __shared__ double sums[12];
  int t = threadIdx.x;
  int k = t % 12, j = t / 12;
  if (t < 252) {
    double acc = 0.0;
    for (int b = j; b < nb; b += 21) acc += partials[(size_t)b * 12 + k];
    lds[k][j] = acc;
  }
  __syncthreads();
  if (t < 12) {
    double acc = 0.0;
#pragma unroll
    for (int j2 = 0; j2 < 21; j2++) acc += lds[t][j2];
    sums[t] = acc;
  }
  __syncthreads();
  if (t < 6) {
    double mean = sums[t] / n;
    double var = sums[t + 6] / n - mean * mean;
    double invstd = 1.0 / sqrt(var + 1e-5);
    mean_out[t] = (float)mean;
    sg_out[t] = (float)(invstd * (double)gamma[t]);
  }
}

// ---- fuse1 + stats2: conv1+BN+LIF+pool (1-ring pooled halo) + conv2 stats ----
// WG: (b, oy 0..7, ox 0..24); own pooled 2x8 at (2oy, 8ox); halo tile 4x10/ch.
// tile stride 23 (odd): bank = 14*hy + 2*hx + ... spreads across banks.
__global__ void fuse1_stats(const float* __restrict__ x, const float* __restrict__ w1g,
                            const float* __restrict__ w2g,
                            const float* __restrict__ mean1, const float* __restrict__ sg1,
                            const float* __restrict__ beta1,
                            float* __restrict__ pool1, double* __restrict__ partials2) {
  __shared__ float wsm1[54];
  __shared__ float wsm2[324];
  __shared__ float tile[10][23];
  __shared__ float phl[6][4][10];

  int tid = threadIdx.x;
  for (int k = tid; k < 54; k += 256) wsm1[k] = w1g[k];
  for (int k = tid; k < 324; k += 256) wsm2[k] = w2g[k];
  __syncthreads();

  int wg = blockIdx.x;
  int b = wg / 200;
  int rem = wg % 200;
  int oy = rem / 25, ox = rem % 25;
  int iy0 = 4 * oy - 3, ix0 = 16 * ox - 3;

  bool active = tid < 240;
  int ch = 0, hy = 0, hx = 0, py = 0, px = 0;
  bool pvalid = false, own = false;
  if (active) {
    ch = tid / 40;
    int r = tid % 40;
    hy = r / 10; hx = r % 10;
    py = 2 * oy - 1 + hy; px = 8 * ox - 1 + hx;
    pvalid = (py >= 0 && py < P1H && px >= 0 && px < P1W);
    own = (hy >= 1 && hy <= 2 && hx >= 1 && hx <= 8);
  }
  float wv[9];
#pragma unroll
  for (int k = 0; k < 9; k++) wv[k] = active ? wsm1[ch * 9 + k] : 0.0f;
  float m = active ? mean1[ch] : 0.0f;
  float sc = active ? sg1[ch] : 0.0f;
  float be = active ? beta1[ch] : 0.0f;

  int oidx = (tid < 96) ? (tid / 16) : -1;
  int sy = (tid & 15) >> 3, sx = tid & 7;

  float v[4] = {0.0f, 0.0f, 0.0f, 0.0f};
  double s_acc = 0.0, q_acc = 0.0;

  for (int t = 0; t < T; t++) {
    __syncthreads();  // protect tile/phl from previous-iter readers
    const float* xb = x + (size_t)(t * B + b) * (H1 * W1);
    for (int k = tid; k < 220; k += 256) {
      int rr = k / 22, cc = k % 22;
      int hh = iy0 + rr, ww = ix0 + cc;
      tile[rr][cc] = (hh >= 0 && hh < H1 && ww >= 0 && ww < W1) ? xb[hh * W1 + ww] : 0.0f;
    }
    __syncthreads();
    if (active) {
      float smax = 0.0f;
      if (pvalid) {
        int ry = 2 * hy, rx = 2 * hx;
        float p[16];
#pragma unroll
        for (int r = 0; r < 4; r++)
#pragma unroll
          for (int c = 0; c < 4; c++) p[r * 4 + c] = tile[ry + r][rx + c];
#pragma unroll
        for (int dy = 0; dy < 2; dy++) {
#pragma unroll
          for (int dx = 0; dx < 2; dx++) {
            float acc = 0.0f;
#pragma unroll
            for (int ky = 0; ky < 3; ky++)
#pragma unroll
              for (int kx = 0; kx < 3; kx++)
                acc = fmaf(p[(dy + ky) * 4 + dx + kx], wv[ky * 3 + kx], acc);
            float y = (acc - m) * sc + be;
            float sp = lif_step(v[dy * 2 + dx], y);
            smax = fmaxf(smax, sp);
          }
        }
      }
      phl[ch][hy][hx] = smax;
      if (own)
        pool1[((size_t)(t * B + b) * 6 + ch) * (P1H * P1W) + py * P1W + px] = smax;
    }
    __syncthreads();
    if (oidx >= 0) {  // conv2 at own pooled position (sy,sx), out-ch oidx
      float acc = 0.0f;
#pragma unroll
      for (int i = 0; i < 6; i++) {
        const float* wo = &wsm2[(oidx * 6 + i) * 9];
#pragma unroll
        for (int ky = 0; ky < 3; ky++)
#pragma unroll
          for (int kx = 0; kx < 3; kx++)
            acc = fmaf(phl[i][sy + ky][sx + kx], wo[ky * 3 + kx], acc);
      }
      s_acc += (double)acc;
      q_acc += (double)acc * (double)acc;
    }
  }
  __syncthreads();
  reduce12_sel(oidx, s_acc, q_acc, partials2);
}

// ---- fuse2 + stats3: conv2+BN+LIF+pool (pooled halo) + conv3 stats ----
// WG: (b, oy 0..3, ox 0..19); own pooled 2x5 at (2oy, 5ox); halo tile 4x7/ch.
// tile stride 21 (odd): bank = 10*i + 2*hy + 2*hx + ... spreads across banks.
__global__ void fuse2_stats(const float* __restrict__ in, const float* __restrict__ w2g,
                            const float* __restrict__ w3g,
                            const float* __restrict__ mean2, const float* __restrict__ sg2,
                            const float* __restrict__ beta2,
                            float* __restrict__ pool2, double* __restrict__ partials3) {
  __shared__ float wsm2[324];
  __shared__ float wsm3[324];
  __shared__ float tile[6][10][21];
  __shared__ float phl[6][4][7];

  int tid = threadIdx.x;
  for (int k = tid; k < 324; k += 256) { wsm2[k] = w2g[k]; wsm3[k] = w3g[k]; }
  __syncthreads();

  int wg = blockIdx.x;
  int b = wg / 80;
  int rem = wg % 80;
  int oy = rem / 20, ox = rem % 20;
  int iy0 = 4 * oy - 3, ix0 = 10 * ox - 3;

  bool active = tid < 168;
  int ch = 0, hy = 0, hx = 0, py = 0, px = 0;
  bool pvalid = false, own = false;
  if (active) {
    ch = tid / 28;
    int r = tid % 28;
    hy = r / 7; hx = r % 7;
    py = 2 * oy - 1 + hy; px = 5 * ox - 1 + hx;
    pvalid = (py >= 0 && py < P2H && px >= 0 && px < P2W);
    own = (hy >= 1 && hy <= 2 && hx >= 1 && hx <= 5);
  }
  float m = active ? mean2[ch] : 0.0f;
  float sc = active ? sg2[ch] : 0.0f;
  float be = active ? beta2[ch] : 0.0f;

  int oidx = (tid < 60) ? (tid / 10) : -1;
  int pp = tid % 10;
  int sy = pp / 5, sx = pp % 5;

  float v[4] = {0.0f, 0.0f, 0.0f, 0.0f};
  double s_acc = 0.0, q_acc = 0.0;
  constexpr int HW = H2 * W2;

  for (int t = 0; t < T; t++) {
    __syncthreads();
    const float* xb = in + (size_t)(t * B + b) * 6 * HW;
    for (int k = tid; k < 6 * 160; k += 256) {
      int i = k / 160;
      int r2 = k % 160;
      int rr = r2 / 16, cc = r2 % 16;
      int hh = iy0 + rr, ww = ix0 + cc;
      tile[i][rr][cc] = (hh >= 0 && hh < H2 && ww >= 0 && ww < W2) ? xb[i * HW + hh * W2 + ww] : 0.0f;
    }
    __syncthreads();
    if (active) {
      float smax = 0.0f;
      if (pvalid) {
        int ry = 2 * hy, rx = 2 * hx;
        float acc4[4] = {0.0f, 0.0f, 0.0f, 0.0f};
#pragma unroll
        for (int i = 0; i < 6; i++) {
          float p[16];
#pragma unroll
          for (int r = 0; r < 4; r++)
#pragma unroll
            for (int c = 0; c < 4; c++) p[r * 4 + c] = tile[i][ry + r][rx + c];
          const float* wo = &wsm2[(ch * 6 + i) * 9];
#pragma unroll
          for (int dy = 0; dy < 2; dy++)
#pragma unroll
            for (int dx = 0; dx < 2; dx++) {
              float a = acc4[dy * 2 + dx];
#pragma unroll
              for (int ky = 0; ky < 3; ky++)
#pragma unroll
                for (int kx = 0; kx < 3; kx++)
                  a = fmaf(p[(dy + ky) * 4 + dx + kx], wo[ky * 3 + kx], a);
              acc4[dy * 2 + dx] = a;
            }
        }
#pragma unroll
        for (int p4 = 0; p4 < 4; p4++) {
          float y = (acc4[p4] - m) * sc + be;
          float sp = lif_step(v[p4], y);
          smax = fmaxf(smax, sp);
        }
      }
      phl[ch][hy][hx] = smax;
      if (own)
        pool2[((size_t)(t * B + b) * 6 + ch) * (P2H * P2W) + py * P2W + px] = smax;
    }
    __syncthreads();
    if (oidx >= 0) {  // conv3 at own pooled position (sy,sx), out-ch oidx
      float acc = 0.0f;
#pragma unroll
      for (int i = 0; i < 6; i++) {
        const float* wo = &wsm3[(oidx * 6 + i) * 9];
#pragma unroll
        for (int ky = 0; ky < 3; ky++)
#pragma unroll
          for (int kx = 0; kx < 3; kx++)
            acc = fmaf(phl[i][sy + ky][sx + kx], wo[ky * 3 + kx], acc);
      }
      s_acc += (double)acc;
      q_acc += (double)acc * (double)acc;
    }
  }
  __syncthreads();
  reduce12_sel(oidx, s_acc, q_acc, partials3);
}

// ---- block 3 fuse: conv(6->6)+BN+LIF+pool, LDS-tiled (odd-padded stride) ----
template <int H, int W, int PH, int PW, int TH, int TW>
__global__ void block6_fuse_lds(const float* __restrict__ in, const float* __restrict__ wt,
                                const float* __restrict__ mean, const float* __restrict__ sg,
                                const float* __restrict__ beta, float* __restrict__ out) {
  constexpr int NTH = PH / TH, NTW = PW / TW;
  constexpr int IH = 2 * TH + 2, IW = 2 * TW + 2;
  constexpr int IWP = (IW & 1) ? IW : IW + 1;  // odd row stride
  constexpr int TILE_N = IH * IW;
  constexpr int NACT = 6 * TH * TW;
  constexpr int HW = H * W;
  __shared__ float wsm[324];
  __shared__ float tile[6][IH][IWP];

  for (int k = threadIdx.x; k < 324; k += blockDim.x) wsm[k] = wt[k];

  int wg = blockIdx.x;
  int b = wg / (NTH * NTW);
  int tid2 = wg % (NTH * NTW);
  int ty = tid2 / NTW, tx = tid2 % NTW;
  int h_in0 = 2 * (ty * TH) - 1, w_in0 = 2 * (tx * TW) - 1;

  int tid = threadIdx.x;
  int o = 0, lph = 0, lpw = 0;
  if (tid < NACT) {
    o = tid / (TH * TW);
    int r = tid % (TH * TW);
    lph = r / TW; lpw = r % TW;
  }
  float m = mean[o], s = sg[o], be = beta[o];
  float v[4] = {0.0f, 0.0f, 0.0f, 0.0f};

  for (int t = 0; t < T; t++) {
    __syncthreads();
    const float* xb = in + (size_t)(t * B + b) * 6 * HW;
    for (int k = tid; k < 6 * TILE_N; k += blockDim.x) {
      int i = k / TILE_N;
      int r2 = k % TILE_N;
      int rr = r2 / IW, cc = r2 % IW;
      int hh = h_in0 + rr, ww = w_in0 + cc;
      tile[i][rr][cc] = (hh >= 0 && hh < H && ww >= 0 && ww < W) ? xb[i * HW + hh * W + ww] : 0.0f;
    }
    __syncthreads();
    if (tid < NACT) {
      int ry = 2 * lph, rx = 2 * lpw;
      float acc[4] = {0.0f, 0.0f, 0.0f, 0.0f};
#pragma unroll
      for (int i = 0; i < 6; i++) {
        float p[16];
#pragma unroll
        for (int r = 0; r < 4; r++)
#pragma unroll
          for (int c = 0; c < 4; c++) p[r * 4 + c] = tile[i][ry + r][rx + c];
        const float* wo = &wsm[(o * 6 + i) * 9];
#pragma unroll
        for (int dy = 0; dy < 2; dy++)
#pragma unroll
          for (int dx = 0; dx < 2; dx++) {
            float a = acc[dy * 2 + dx];
#pragma unroll
            for (int ky = 0; ky < 3; ky++)
#pragma unroll
              for (int kx = 0; kx < 3; kx++)
                a = fmaf(p[(dy + ky) * 4 + dx + kx], wo[ky * 3 + kx], a);
            acc[dy * 2 + dx] = a;
          }
      }
      float smax = 0.0f;
#pragma unroll
      for (int p4 = 0; p4 < 4; p4++) {
        float y = (acc[p4] - m) * s + be;
        float sp = lif_step(v[p4], y);
        smax = fmaxf(smax, sp);
      }
      out[((size_t)(t * B + b) * 6 + o) * (PH * PW) + (ty * TH + lph) * PW + (tx * TW + lpw)] = smax;
    }
  }
}

// ---- FC head ----
__global__ void fc1_mm(const float* __restrict__ p3, const float* __restrict__ fw1,
                       float* __restrict__ u1) {
  int idx = blockIdx.x * blockDim.x + threadIdx.x;
  if (idx >= T * B * 100) return;
  int o = idx % 100;
  int tb = idx / 100;
  const float4* x4 = (const float4*)(p3 + (size_t)tb * 1200);
  const float4* w4 = (const float4*)(fw1 + (size_t)o * 1200);
  float acc = 0.0f;
#pragma unroll 4
  for (int k = 0; k < 300; k++) {
    float4 a = x4[k], w = w4[k];
    acc = fmaf(a.x, w.x, acc);
    acc = fmaf(a.y, w.y, acc);
    acc = fmaf(a.z, w.z, acc);
    acc = fmaf(a.w, w.w, acc);
  }
  u1[idx] = acc;
}

__global__ void fc1_lif(const float* __restrict__ u1, float* __restrict__ s1) {
  int idx = blockIdx.x * blockDim.x + threadIdx.x;
  if (idx >= B * 100) return;
  float v = 0.0f;
  for (int t = 0; t < T; t++) {
    float sp = lif_step(v, u1[(size_t)t * B * 100 + idx]);
    s1[(size_t)t * B * 100 + idx] = sp;
  }
}

__global__ void fc2_fused(const float* __restrict__ s1, const float* __restrict__ fw2,
                          float* __restrict__ outp) {
  int idx = blockIdx.x * blockDim.x + threadIdx.x;
  if (idx >= B * 2) return;
  int b = idx >> 1, o = idx & 1;
  const float* wr = fw2 + o * 100;
  float v = 0.0f;
  for (int t = 0; t < T; t++) {
    const float* sr = s1 + (size_t)(t * B + b) * 100;
    float acc = 0.0f;
#pragma unroll
    for (int k = 0; k < 100; k++) acc = fmaf(sr[k], wr[k], acc);
    float sp = lif_step(v, acc);
    outp[(size_t)(t * B + b) * 2 + o] = sp;
  }
}

extern "C" void kernel_launch(void* const* d_in, const int* in_sizes, int n_in,
                              void* d_out, int out_size, void* d_ws, size_t ws_size,
                              hipStream_t stream) {
  const float* x   = (const float*)d_in[0];
  const float* w1  = (const float*)d_in[1];
  const float* g1  = (const float*)d_in[2];
  const float* b1  = (const float*)d_in[3];
  const float* w2  = (const float*)d_in[4];
  const float* g2  = (const float*)d_in[5];
  const float* b2  = (const float*)d_in[6];
  const float* w3  = (const float*)d_in[7];
  const float* g3  = (const float*)d_in[8];
  const float* b3  = (const float*)d_in[9];
  const float* fw1 = (const float*)d_in[10];
  const float* fw2 = (const float*)d_in[11];
  float* out = (float*)d_out;

  char* ws = (char*)d_ws;
  double* part1  = (double*)(ws + OFF_PART1);
  double* partf1 = (double*)(ws + OFF_PARTF1);
  double* partf2 = (double*)(ws + OFF_PARTF2);
  float* mean1 = (float*)(ws + OFF_STATS + 0);
  float* sg1   = (float*)(ws + OFF_STATS + 32);
  float* mean2 = (float*)(ws + OFF_STATS + 64);
  float* sg2   = (float*)(ws + OFF_STATS + 96);
  float* mean3 = (float*)(ws + OFF_STATS + 128);
  float* sg3   = (float*)(ws + OFF_STATS + 160);
  float* pool1 = (float*)(ws + OFF_POOL1);
  float* pool2 = (float*)(ws + OFF_POOL2);
  float* pool3 = (float*)(ws + OFF_POOL3);
  float* u1    = (float*)(ws + OFF_U1);
  float* s1    = (float*)(ws + OFF_S1);

  // Block 1 stats + finalize
  conv_stats_lds<1, H1, W1, 32, 100><<<NWG_S1, 256, 0, stream>>>(x, w1, part1);
  finalize_stats<<<1, 256, 0, stream>>>(part1, NWG_S1, (double)T * B * H1 * W1, g1, mean1, sg1);
  // fuse1 (+ stats for block2)
  fuse1_stats<<<NWG_F1, 256, 0, stream>>>(x, w1, w2, mean1, sg1, b1, pool1, partf1);
  finalize_stats<<<1, 256, 0, stream>>>(partf1, NWG_F1, (double)T * B * H2 * W2, g2, mean2, sg2);
  // fuse2 (+ stats for block3)
  fuse2_stats<<<NWG_F2, 256, 0, stream>>>(pool1, w2, w3, mean2, sg2, b2, pool2, partf2);
  finalize_stats<<<1, 256, 0, stream>>>(partf2, NWG_F2, (double)T * B * H3 * W3, g3, mean3, sg3);
  // Block 3 fuse
  {
    int nwg = B * (P3H / 4) * (P3W / 10);  // 160
    block6_fuse_lds<H3, W3, P3H, P3W, 4, 10><<<nwg, 256, 0, stream>>>(pool2, w3, mean3, sg3, b3, pool3);
  }
  // FC head
  {
    int n = T * B * 100;
    fc1_mm<<<(n + 255) / 256, 256, 0, stream>>>(pool3, fw1, u1);
  }
  {
    int n = B * 100;
    fc1_lif<<<(n + 255) / 256, 256, 0, stream>>>(u1, s1);
  }
  fc2_fused<<<1, 64, 0, stream>>>(s1, fw2, out);
}

// Round 10
// 614.526 us; speedup vs baseline: 1.5829x; 1.1581x over previous
//
#include <hip/hip_runtime.h>

// SNN forward: 3x (conv3x3 -> tdBN -> LIF -> maxpool2) + 2x (FC -> LIF)
// x [16,32,1,32,400] -> pool1 [16,32,6,16,200] -> pool2 [16,32,6,8,100]
//   -> pool3 [16,32,6,4,50] -> fc1 [16,32,100] -> out [16,32,2]
//
// Round-10: parity-split LDS tiles. Round-9 showed odd row strides cut only
// 28% of conflicts: conv patch reads start at rx=2*hx (pool stride 2), so the
// lane-varying bank term is ALWAYS even -> <=16 banks for 64 lanes (~4-way).
// Fix: store tiles split by column parity (til_e[j]=raw[2j], til_o[j]=raw[2j+1],
// odd row strides). Patch cols become {til_e[hx], til_o[hx], til_e[hx+1],
// til_o[hx+1]} -> stride-1 in hx -> consecutive banks; cross-channel same-addr
// reads broadcast. Identical FMA order -> bit-identical output.

namespace {

constexpr int T = 16, B = 32;
constexpr int H1 = 32, W1 = 400, P1H = 16, P1W = 200;
constexpr int H2 = 16, W2 = 200, P2H = 8,  P2W = 100;
constexpr int H3 = 8,  W3 = 100, P3H = 4,  P3W = 50;

constexpr int NWG_S1 = T * B * (H1 / 32) * (W1 / 100);  // 2048
constexpr int NWG_F1 = B * (P1H / 2) * (P1W / 8);       // 6400
constexpr int NWG_F2 = B * (P2H / 2) * (P2W / 5);       // 2560

constexpr size_t OFF_PART1  = 0;                                     // 2048*96
constexpr size_t OFF_PARTF1 = OFF_PART1 + (size_t)NWG_S1 * 12 * 8;   // 6400*96
constexpr size_t OFF_PARTF2 = OFF_PARTF1 + (size_t)NWG_F1 * 12 * 8;  // 2560*96
constexpr size_t OFF_STATS  = OFF_PARTF2 + (size_t)NWG_F2 * 12 * 8;
constexpr size_t OFF_POOL1  = 1310720;
constexpr size_t OFF_POOL2  = OFF_POOL1 + (size_t)T * B * 6 * P1H * P1W * 4;
constexpr size_t OFF_POOL3  = OFF_POOL2 + (size_t)T * B * 6 * P2H * P2W * 4;
constexpr size_t OFF_U1     = OFF_POOL3 + (size_t)T * B * 6 * P3H * P3W * 4;
constexpr size_t OFF_S1     = OFF_U1 + (size_t)T * B * 100 * 4;

} // namespace

__device__ __forceinline__ float lif_step(float& v, float y) {
  v = v + (y - v) * 0.5f;                 // tau=2, decay_input
  float sp = (v >= 1.0f) ? 1.0f : 0.0f;   // threshold 1.0
  v = (sp > 0.0f) ? 0.0f : v;             // hard reset
  return sp;
}

// Block reduction of per-thread 6+6 double counters (array form).
__device__ __forceinline__ void reduce12(double* s, double* q, double* partials) {
  __shared__ double lds[4][12];
  int lane = threadIdx.x & 63, wid = threadIdx.x >> 6;
#pragma unroll
  for (int k = 0; k < 12; k++) {
    double v = (k < 6) ? s[k] : q[k - 6];
#pragma unroll
    for (int off = 32; off >= 1; off >>= 1) v += __shfl_down(v, off, 64);
    if (lane == 0) lds[wid][k] = v;
  }
  __syncthreads();
  if (threadIdx.x < 12) {
    partials[(size_t)blockIdx.x * 12 + threadIdx.x] =
        lds[0][threadIdx.x] + lds[1][threadIdx.x] + lds[2][threadIdx.x] + lds[3][threadIdx.x];
  }
}

// Select form: thread contributes (s_acc,q_acc) only to counter `oidx` (<0: none).
__device__ __forceinline__ void reduce12_sel(int oidx, double s_acc, double q_acc,
                                             double* partials) {
  __shared__ double lds[4][12];
  int lane = threadIdx.x & 63, wid = threadIdx.x >> 6;
#pragma unroll
  for (int k = 0; k < 12; k++) {
    double v = (k == oidx) ? s_acc : ((k == oidx + 6) ? q_acc : 0.0);
#pragma unroll
    for (int off = 32; off >= 1; off >>= 1) v += __shfl_down(v, off, 64);
    if (lane == 0) lds[wid][k] = v;
  }
  __syncthreads();
  if (threadIdx.x < 12) {
    partials[(size_t)blockIdx.x * 12 + threadIdx.x] =
        lds[0][threadIdx.x] + lds[1][threadIdx.x] + lds[2][threadIdx.x] + lds[3][threadIdx.x];
  }
}

// ---- block1 stats: conv(1->6) over x, LDS-tiled (lane access already stride-1) ----
template <int NC, int H, int W, int TH, int TW>
__global__ void conv_stats_lds(const float* __restrict__ in, const float* __restrict__ wt,
                               double* __restrict__ partials) {
  constexpr int IH = TH + 2, IW = TW + 2;
  constexpr int IWP = (IW & 1) ? IW : IW + 1;  // odd row stride
  constexpr int NW = NC * 54;
  constexpr int NTH = H / TH, NTW = W / TW;
  constexpr int NT = NTH * NTW;
  __shared__ float wsm[NW];
  __shared__ float tile[NC][IH][IWP];

  int tid = threadIdx.x;
  for (int k = tid; k < NW; k += blockDim.x) wsm[k] = wt[k];

  int wg = blockIdx.x;
  int tb = wg / NT;
  int ti = wg % NT;
  int ty = ti / NTW, tx = ti % NTW;
  int h0 = ty * TH - 1, w0 = tx * TW - 1;
  const float* xb = in + (size_t)tb * NC * H * W;

  for (int k = tid; k < NC * IH * IW; k += blockDim.x) {
    int i = k / (IH * IW);
    int r = k % (IH * IW);
    int rr = r / IW, cc = r % IW;
    int hh = h0 + rr, ww = w0 + cc;
    tile[i][rr][cc] = (hh >= 0 && hh < H && ww >= 0 && ww < W) ? xb[i * H * W + hh * W + ww] : 0.0f;
  }
  __syncthreads();

  double s[6] = {0, 0, 0, 0, 0, 0}, q[6] = {0, 0, 0, 0, 0, 0};
  for (int pos = tid; pos < TH * TW; pos += blockDim.x) {
    int ly = pos / TW, lx = pos % TW;
    float acc[6] = {0, 0, 0, 0, 0, 0};
#pragma unroll
    for (int i = 0; i < NC; i++) {
      float p[9];
#pragma unroll
      for (int ky = 0; ky < 3; ky++)
#pragma unroll
        for (int kx = 0; kx < 3; kx++) p[ky * 3 + kx] = tile[i][ly + ky][lx + kx];
#pragma unroll
      for (int o = 0; o < 6; o++) {
        float a = acc[o];
#pragma unroll
        for (int k2 = 0; k2 < 9; k2++) a = fmaf(p[k2], wsm[(o * NC + i) * 9 + k2], a);
        acc[o] = a;
      }
    }
#pragma unroll
    for (int o = 0; o < 6; o++) {
      s[o] += (double)acc[o];
      q[o] += (double)acc[o] * (double)acc[o];
    }
  }
  reduce12(s, q, partials);
}

// ---- finalize: partials -> mean[6], sg[6] ----
__global__ void finalize_stats(const double* __restrict__ partials, int nb, double n,
                               const float* __restrict__ gamma,
                               float* __restrict__ mean_out, float* __restrict__ sg_out) {
  __shared__ double lds[12][21];
  __shared__ double sums[12];
  int t = threadIdx.x;
  int k = t % 12, j = t / 12;
  if (t < 252) {
    double acc = 0.0;
    for (int b = j; b < nb; b += 21) acc += partials[(size_t)b * 12 + k];
    lds[k][j] = acc;
  }
  __syncthreads();
  if (t < 12) {
    double acc = 0.0;
#pragma unroll
    for (int j2 = 0; j2 < 21; j2++) acc += lds[t][j2];
    sums[t] = acc;
  }
  __syncthreads();
  if (t < 6) {
    double mean = sums[t] / n;
    double var = sums[t + 6] / n - mean * mean;
    double invstd = 1.0 / sqrt(var + 1e-5);
    mean_out[t] = (float)mean;
    sg_out[t] = (float)(invstd * (double)gamma[t]);
  }
}

// ---- fuse1 + stats2: conv1+BN+LIF+pool (1-ring pooled halo) + conv2 stats ----
// WG: (b, oy 0..7, ox 0..24); own pooled 2x8 at (2oy, 8ox); halo tile 4x10/ch.
// Raw tile 10x22 stored parity-split: til_e[r][j]=raw[r][2j], til_o=raw[r][2j+1].
__global__ void fuse1_stats(const float* __restrict__ x, const float* __restrict__ w1g,
                            const float* __restrict__ w2g,
                            const float* __restrict__ mean1, const float* __restrict__ sg1,
                            const float* __restrict__ beta1,
                            float* __restrict__ pool1, double* __restrict__ partials2) {
  __shared__ float wsm1[54];
  __shared__ float wsm2[324];
  __shared__ float til_e[10][11];
  __shared__ float til_o[10][11];
  __shared__ float phl[6][4][10];

  int tid = threadIdx.x;
  for (int k = tid; k < 54; k += 256) wsm1[k] = w1g[k];
  for (int k = tid; k < 324; k += 256) wsm2[k] = w2g[k];
  __syncthreads();

  int wg = blockIdx.x;
  int b = wg / 200;
  int rem = wg % 200;
  int oy = rem / 25, ox = rem % 25;
  int iy0 = 4 * oy - 3, ix0 = 16 * ox - 3;

  bool active = tid < 240;
  int ch = 0, hy = 0, hx = 0, py = 0, px = 0;
  bool pvalid = false, own = false;
  if (active) {
    ch = tid / 40;
    int r = tid % 40;
    hy = r / 10; hx = r % 10;
    py = 2 * oy - 1 + hy; px = 8 * ox - 1 + hx;
    pvalid = (py >= 0 && py < P1H && px >= 0 && px < P1W);
    own = (hy >= 1 && hy <= 2 && hx >= 1 && hx <= 8);
  }
  float wv[9];
#pragma unroll
  for (int k = 0; k < 9; k++) wv[k] = active ? wsm1[ch * 9 + k] : 0.0f;
  float m = active ? mean1[ch] : 0.0f;
  float sc = active ? sg1[ch] : 0.0f;
  float be = active ? beta1[ch] : 0.0f;

  int oidx = (tid < 96) ? (tid / 16) : -1;
  int sy = (tid & 15) >> 3, sx = tid & 7;

  float v[4] = {0.0f, 0.0f, 0.0f, 0.0f};
  double s_acc = 0.0, q_acc = 0.0;

  for (int t = 0; t < T; t++) {
    __syncthreads();  // protect tile/phl from previous-iter readers
    const float* xb = x + (size_t)(t * B + b) * (H1 * W1);
    for (int k = tid; k < 220; k += 256) {
      int rr = k / 22, cc = k % 22;
      int hh = iy0 + rr, ww = ix0 + cc;
      float val = (hh >= 0 && hh < H1 && ww >= 0 && ww < W1) ? xb[hh * W1 + ww] : 0.0f;
      if (cc & 1) til_o[rr][cc >> 1] = val;
      else        til_e[rr][cc >> 1] = val;
    }
    __syncthreads();
    if (active) {
      float smax = 0.0f;
      if (pvalid) {
        int ry = 2 * hy;
        float p[16];
#pragma unroll
        for (int r = 0; r < 4; r++) {
          p[r * 4 + 0] = til_e[ry + r][hx];
          p[r * 4 + 1] = til_o[ry + r][hx];
          p[r * 4 + 2] = til_e[ry + r][hx + 1];
          p[r * 4 + 3] = til_o[ry + r][hx + 1];
        }
#pragma unroll
        for (int dy = 0; dy < 2; dy++) {
#pragma unroll
          for (int dx = 0; dx < 2; dx++) {
            float acc = 0.0f;
#pragma unroll
            for (int ky = 0; ky < 3; ky++)
#pragma unroll
              for (int kx = 0; kx < 3; kx++)
                acc = fmaf(p[(dy + ky) * 4 + dx + kx], wv[ky * 3 + kx], acc);
            float y = (acc - m) * sc + be;
            float sp = lif_step(v[dy * 2 + dx], y);
            smax = fmaxf(smax, sp);
          }
        }
      }
      phl[ch][hy][hx] = smax;
      if (own)
        pool1[((size_t)(t * B + b) * 6 + ch) * (P1H * P1W) + py * P1W + px] = smax;
    }
    __syncthreads();
    if (oidx >= 0) {  // conv2 at own pooled position (sy,sx), out-ch oidx
      float acc = 0.0f;
#pragma unroll
      for (int i = 0; i < 6; i++) {
        const float* wo = &wsm2[(oidx * 6 + i) * 9];
#pragma unroll
        for (int ky = 0; ky < 3; ky++)
#pragma unroll
          for (int kx = 0; kx < 3; kx++)
            acc = fmaf(phl[i][sy + ky][sx + kx], wo[ky * 3 + kx], acc);
      }
      s_acc += (double)acc;
      q_acc += (double)acc * (double)acc;
    }
  }
  __syncthreads();
  reduce12_sel(oidx, s_acc, q_acc, partials2);
}

// ---- fuse2 + stats3: conv2+BN+LIF+pool (pooled halo) + conv3 stats ----
// WG: (b, oy 0..3, ox 0..19); own pooled 2x5 at (2oy, 5ox); halo tile 4x7/ch.
// Raw tile 6x10x16 stored parity-split with odd row stride 9.
__global__ void fuse2_stats(const float* __restrict__ in, const float* __restrict__ w2g,
                            const float* __restrict__ w3g,
                            const float* __restrict__ mean2, const float* __restrict__ sg2,
                            const float* __restrict__ beta2,
                            float* __restrict__ pool2, double* __restrict__ partials3) {
  __shared__ float wsm2[324];
  __shared__ float wsm3[324];
  __shared__ float til_e[6][10][9];
  __shared__ float til_o[6][10][9];
  __shared__ float phl[6][4][7];

  int tid = threadIdx.x;
  for (int k = tid; k < 324; k += 256) { wsm2[k] = w2g[k]; wsm3[k] = w3g[k]; }
  __syncthreads();

  int wg = blockIdx.x;
  int b = wg / 80;
  int rem = wg % 80;
  int oy = rem / 20, ox = rem % 20;
  int iy0 = 4 * oy - 3, ix0 = 10 * ox - 3;

  bool active = tid < 168;
  int ch = 0, hy = 0, hx = 0, py = 0, px = 0;
  bool pvalid = false, own = false;
  if (active) {
    ch = tid / 28;
    int r = tid % 28;
    hy = r / 7; hx = r % 7;
    py = 2 * oy - 1 + hy; px = 5 * ox - 1 + hx;
    pvalid = (py >= 0 && py < P2H && px >= 0 && px < P2W);
    own = (hy >= 1 && hy <= 2 && hx >= 1 && hx <= 5);
  }
  float m = active ? mean2[ch] : 0.0f;
  float sc = active ? sg2[ch] : 0.0f;
  float be = active ? beta2[ch] : 0.0f;

  int oidx = (tid < 60) ? (tid / 10) : -1;
  int pp = tid % 10;
  int sy = pp / 5, sx = pp % 5;

  float v[4] = {0.0f, 0.0f, 0.0f, 0.0f};
  double s_acc = 0.0, q_acc = 0.0;
  constexpr int HW = H2 * W2;

  for (int t = 0; t < T; t++) {
    __syncthreads();
    const float* xb = in + (size_t)(t * B + b) * 6 * HW;
    for (int k = tid; k < 6 * 160; k += 256) {
      int i = k / 160;
      int r2 = k % 160;
      int rr = r2 / 16, cc = r2 % 16;
      int hh = iy0 + rr, ww = ix0 + cc;
      float val = (hh >= 0 && hh < H2 && ww >= 0 && ww < W2) ? xb[i * HW + hh * W2 + ww] : 0.0f;
      if (cc & 1) til_o[i][rr][cc >> 1] = val;
      else        til_e[i][rr][cc >> 1] = val;
    }
    __syncthreads();
    if (active) {
      float smax = 0.0f;
      if (pvalid) {
        int ry = 2 * hy;
        float acc4[4] = {0.0f, 0.0f, 0.0f, 0.0f};
#pragma unroll
        for (int i = 0; i < 6; i++) {
          float p[16];
#pragma unroll
          for (int r = 0; r < 4; r++) {
            p[r * 4 + 0] = til_e[i][ry + r][hx];
            p[r * 4 + 1] = til_o[i][ry + r][hx];
            p[r * 4 + 2] = til_e[i][ry + r][hx + 1];
            p[r * 4 + 3] = til_o[i][ry + r][hx + 1];
          }
          const float* wo = &wsm2[(ch * 6 + i) * 9];
#pragma unroll
          for (int dy = 0; dy < 2; dy++)
#pragma unroll
            for (int dx = 0; dx < 2; dx++) {
              float a = acc4[dy * 2 + dx];
#pragma unroll
              for (int ky = 0; ky < 3; ky++)
#pragma unroll
                for (int kx = 0; kx < 3; kx++)
                  a = fmaf(p[(dy + ky) * 4 + dx + kx], wo[ky * 3 + kx], a);
              acc4[dy * 2 + dx] = a;
            }
        }
#pragma unroll
        for (int p4 = 0; p4 < 4; p4++) {
          float y = (acc4[p4] - m) * sc + be;
          float sp = lif_step(v[p4], y);
          smax = fmaxf(smax, sp);
        }
      }
      phl[ch][hy][hx] = smax;
      if (own)
        pool2[((size_t)(t * B + b) * 6 + ch) * (P2H * P2W) + py * P2W + px] = smax;
    }
    __syncthreads();
    if (oidx >= 0) {  // conv3 at own pooled position (sy,sx), out-ch oidx
      float acc = 0.0f;
#pragma unroll
      for (int i = 0; i < 6; i++) {
        const float* wo = &wsm3[(oidx * 6 + i) * 9];
#pragma unroll
        for (int ky = 0; ky < 3; ky++)
#pragma unroll
          for (int kx = 0; kx < 3; kx++)
            acc = fmaf(phl[i][sy + ky][sx + kx], wo[ky * 3 + kx], acc);
      }
      s_acc += (double)acc;
      q_acc += (double)acc * (double)acc;
    }
  }
  __syncthreads();
  reduce12_sel(oidx, s_acc, q_acc, partials3);
}

// ---- block 3 fuse: conv(6->6)+BN+LIF+pool, parity-split LDS tiles ----
template <int H, int W, int PH, int PW, int TH, int TW>
__global__ void block6_fuse_lds(const float* __restrict__ in, const float* __restrict__ wt,
                                const float* __restrict__ mean, const float* __restrict__ sg,
                                const float* __restrict__ beta, float* __restrict__ out) {
  constexpr int NTH = PH / TH, NTW = PW / TW;
  constexpr int IH = 2 * TH + 2, IW = 2 * TW + 2;
  constexpr int EW = IW / 2;  // 11 for TW=10 (odd stride)
  constexpr int TILE_N = IH * IW;
  constexpr int NACT = 6 * TH * TW;
  constexpr int HW = H * W;
  __shared__ float wsm[324];
  __shared__ float til_e[6][IH][EW];
  __shared__ float til_o[6][IH][EW];

  for (int k = threadIdx.x; k < 324; k += blockDim.x) wsm[k] = wt[k];

  int wg = blockIdx.x;
  int b = wg / (NTH * NTW);
  int tid2 = wg % (NTH * NTW);
  int ty = tid2 / NTW, tx = tid2 % NTW;
  int h_in0 = 2 * (ty * TH) - 1, w_in0 = 2 * (tx * TW) - 1;

  int tid = threadIdx.x;
  int o = 0, lph = 0, lpw = 0;
  if (tid < NACT) {
    o = tid / (TH * TW);
    int r = tid % (TH * TW);
    lph = r / TW; lpw = r % TW;
  }
  float m = mean[o], s = sg[o], be = beta[o];
  float v[4] = {0.0f, 0.0f, 0.0f, 0.0f};

  for (int t = 0; t < T; t++) {
    __syncthreads();
    const float* xb = in + (size_t)(t * B + b) * 6 * HW;
    for (int k = tid; k < 6 * TILE_N; k += blockDim.x) {
      int i = k / TILE_N;
      int r2 = k % TILE_N;
      int rr = r2 / IW, cc = r2 % IW;
      int hh = h_in0 + rr, ww = w_in0 + cc;
      float val = (hh >= 0 && hh < H && ww >= 0 && ww < W) ? xb[i * HW + hh * W + ww] : 0.0f;
      if (cc & 1) til_o[i][rr][cc >> 1] = val;
      else        til_e[i][rr][cc >> 1] = val;
    }
    __syncthreads();
    if (tid < NACT) {
      int ry = 2 * lph;
      float acc[4] = {0.0f, 0.0f, 0.0f, 0.0f};
#pragma unroll
      for (int i = 0; i < 6; i++) {
        float p[16];
#pragma unroll
        for (int r = 0; r < 4; r++) {
          p[r * 4 + 0] = til_e[i][ry + r][lpw];
          p[r * 4 + 1] = til_o[i][ry + r][lpw];
          p[r * 4 + 2] = til_e[i][ry + r][lpw + 1];
          p[r * 4 + 3] = til_o[i][ry + r][lpw + 1];
        }
        const float* wo = &wsm[(o * 6 + i) * 9];
#pragma unroll
        for (int dy = 0; dy < 2; dy++)
#pragma unroll
          for (int dx = 0; dx < 2; dx++) {
            float a = acc[dy * 2 + dx];
#pragma unroll
            for (int ky = 0; ky < 3; ky++)
#pragma unroll
              for (int kx = 0; kx < 3; kx++)
                a = fmaf(p[(dy + ky) * 4 + dx + kx], wo[ky * 3 + kx], a);
            acc[dy * 2 + dx] = a;
          }
      }
      float smax = 0.0f;
#pragma unroll
      for (int p4 = 0; p4 < 4; p4++) {
        float y = (acc[p4] - m) * s + be;
        float sp = lif_step(v[p4], y);
        smax = fmaxf(smax, sp);
      }
      out[((size_t)(t * B + b) * 6 + o) * (PH * PW) + (ty * TH + lph) * PW + (tx * TW + lpw)] = smax;
    }
  }
}

// ---- FC head ----
__global__ void fc1_mm(const float* __restrict__ p3, const float* __restrict__ fw1,
                       float* __restrict__ u1) {
  int idx = blockIdx.x * blockDim.x + threadIdx.x;
  if (idx >= T * B * 100) return;
  int o = idx % 100;
  int tb = idx / 100;
  const float4* x4 = (const float4*)(p3 + (size_t)tb * 1200);
  const float4* w4 = (const float4*)(fw1 + (size_t)o * 1200);
  float acc = 0.0f;
#pragma unroll 4
  for (int k = 0; k < 300; k++) {
    float4 a = x4[k], w = w4[k];
    acc = fmaf(a.x, w.x, acc);
    acc = fmaf(a.y, w.y, acc);
    acc = fmaf(a.z, w.z, acc);
    acc = fmaf(a.w, w.w, acc);
  }
  u1[idx] = acc;
}

__global__ void fc1_lif(const float* __restrict__ u1, float* __restrict__ s1) {
  int idx = blockIdx.x * blockDim.x + threadIdx.x;
  if (idx >= B * 100) return;
  float v = 0.0f;
  for (int t = 0; t < T; t++) {
    float sp = lif_step(v, u1[(size_t)t * B * 100 + idx]);
    s1[(size_t)t * B * 100 + idx] = sp;
  }
}

__global__ void fc2_fused(const float* __restrict__ s1, const float* __restrict__ fw2,
                          float* __restrict__ outp) {
  int idx = blockIdx.x * blockDim.x + threadIdx.x;
  if (idx >= B * 2) return;
  int b = idx >> 1, o = idx & 1;
  const float* wr = fw2 + o * 100;
  float v = 0.0f;
  for (int t = 0; t < T; t++) {
    const float* sr = s1 + (size_t)(t * B + b) * 100;
    float acc = 0.0f;
#pragma unroll
    for (int k = 0; k < 100; k++) acc = fmaf(sr[k], wr[k], acc);
    float sp = lif_step(v, acc);
    outp[(size_t)(t * B + b) * 2 + o] = sp;
  }
}

extern "C" void kernel_launch(void* const* d_in, const int* in_sizes, int n_in,
                              void* d_out, int out_size, void* d_ws, size_t ws_size,
                              hipStream_t stream) {
  const float* x   = (const float*)d_in[0];
  const float* w1  = (const float*)d_in[1];
  const float* g1  = (const float*)d_in[2];
  const float* b1  = (const float*)d_in[3];
  const float* w2  = (const float*)d_in[4];
  const float* g2  = (const float*)d_in[5];
  const float* b2  = (const float*)d_in[6];
  const float* w3  = (const float*)d_in[7];
  const float* g3  = (const float*)d_in[8];
  const float* b3  = (const float*)d_in[9];
  const float* fw1 = (const float*)d_in[10];
  const float* fw2 = (const float*)d_in[11];
  float* out = (float*)d_out;

  char* ws = (char*)d_ws;
  double* part1  = (double*)(ws + OFF_PART1);
  double* partf1 = (double*)(ws + OFF_PARTF1);
  double* partf2 = (double*)(ws + OFF_PARTF2);
  float* mean1 = (float*)(ws + OFF_STATS + 0);
  float* sg1   = (float*)(ws + OFF_STATS + 32);
  float* mean2 = (float*)(ws + OFF_STATS + 64);
  float* sg2   = (float*)(ws + OFF_STATS + 96);
  float* mean3 = (float*)(ws + OFF_STATS + 128);
  float* sg3   = (float*)(ws + OFF_STATS + 160);
  float* pool1 = (float*)(ws + OFF_POOL1);
  float* pool2 = (float*)(ws + OFF_POOL2);
  float* pool3 = (float*)(ws + OFF_POOL3);
  float* u1    = (float*)(ws + OFF_U1);
  float* s1    = (float*)(ws + OFF_S1);

  // Block 1 stats + finalize
  conv_stats_lds<1, H1, W1, 32, 100><<<NWG_S1, 256, 0, stream>>>(x, w1, part1);
  finalize_stats<<<1, 256, 0, stream>>>(part1, NWG_S1, (double)T * B * H1 * W1, g1, mean1, sg1);
  // fuse1 (+ stats for block2)
  fuse1_stats<<<NWG_F1, 256, 0, stream>>>(x, w1, w2, mean1, sg1, b1, pool1, partf1);
  finalize_stats<<<1, 256, 0, stream>>>(partf1, NWG_F1, (double)T * B * H2 * W2, g2, mean2, sg2);
  // fuse2 (+ stats for block3)
  fuse2_stats<<<NWG_F2, 256, 0, stream>>>(pool1, w2, w3, mean2, sg2, b2, pool2, partf2);
  finalize_stats<<<1, 256, 0, stream>>>(partf2, NWG_F2, (double)T * B * H3 * W3, g3, mean3, sg3);
  // Block 3 fuse
  {
    int nwg = B * (P3H / 4) * (P3W / 10);  // 160
    block6_fuse_lds<H3, W3, P3H, P3W, 4, 10><<<nwg, 256, 0, stream>>>(pool2, w3, mean3, sg3, b3, pool3);
  }
  // FC head
  {
    int n = T * B * 100;
    fc1_mm<<<(n + 255) / 256, 256, 0, stream>>>(pool3, fw1, u1);
  }
  {
    int n = B * 100;
    fc1_lif<<<(n + 255) / 256, 256, 0, stream>>>(u1, s1);
  }
  fc2_fused<<<1, 64, 0, stream>>>(s1, fw2, out);
}

// Round 11
// 596.357 us; speedup vs baseline: 1.6312x; 1.0305x over previous
//
#include <hip/hip_runtime.h>

// SNN forward: 3x (conv3x3 -> tdBN -> LIF -> maxpool2) + 2x (FC -> LIF)
// x [16,32,1,32,400] -> pool1 [16,32,6,16,200] -> pool2 [16,32,6,8,100]
//   -> pool3 [16,32,6,4,50] -> fc1 [16,32,100] -> out [16,32,2]
//
// Round-11: software-pipelined staging in fuse1/fuse2. Round-10 profile:
// fuse1_stats 187us with VALUBusy 39%, occ 80%, HBM 7%, conflicts 7.5% —
// latency-bound: __syncthreads drains vmcnt(0), so per-t global stage latency
// serializes with compute 16x. Fix: prefetch t+1 into regs after the LDS
// write of t; intra-iter barriers use s_waitcnt lgkmcnt(0) + raw s_barrier
// (LDS-only drain, prefetch stays in flight); the full __syncthreads at the
// top of the next iter drains the prefetch exactly where it's consumed.

namespace {

constexpr int T = 16, B = 32;
constexpr int H1 = 32, W1 = 400, P1H = 16, P1W = 200;
constexpr int H2 = 16, W2 = 200, P2H = 8,  P2W = 100;
constexpr int H3 = 8,  W3 = 100, P3H = 4,  P3W = 50;

constexpr int NWG_S1 = T * B * (H1 / 32) * (W1 / 100);  // 2048
constexpr int NWG_F1 = B * (P1H / 2) * (P1W / 8);       // 6400
constexpr int NWG_F2 = B * (P2H / 2) * (P2W / 5);       // 2560

constexpr size_t OFF_PART1  = 0;
constexpr size_t OFF_PARTF1 = OFF_PART1 + (size_t)NWG_S1 * 12 * 8;
constexpr size_t OFF_PARTF2 = OFF_PARTF1 + (size_t)NWG_F1 * 12 * 8;
constexpr size_t OFF_STATS  = OFF_PARTF2 + (size_t)NWG_F2 * 12 * 8;
constexpr size_t OFF_POOL1  = 1310720;
constexpr size_t OFF_POOL2  = OFF_POOL1 + (size_t)T * B * 6 * P1H * P1W * 4;
constexpr size_t OFF_POOL3  = OFF_POOL2 + (size_t)T * B * 6 * P2H * P2W * 4;
constexpr size_t OFF_U1     = OFF_POOL3 + (size_t)T * B * 6 * P3H * P3W * 4;
constexpr size_t OFF_S1     = OFF_U1 + (size_t)T * B * 100 * 4;

} // namespace

// LDS-only phase barrier: waits own ds ops, does NOT drain vmcnt (prefetch
// loads stay in flight across it). "memory" clobber pins memory-op order.
#define LDS_PHASE_BARRIER()                                   \
  do {                                                        \
    asm volatile("s_waitcnt lgkmcnt(0)" ::: "memory");        \
    __builtin_amdgcn_s_barrier();                             \
    __builtin_amdgcn_sched_barrier(0);                        \
  } while (0)

__device__ __forceinline__ float lif_step(float& v, float y) {
  v = v + (y - v) * 0.5f;                 // tau=2, decay_input
  float sp = (v >= 1.0f) ? 1.0f : 0.0f;   // threshold 1.0
  v = (sp > 0.0f) ? 0.0f : v;             // hard reset
  return sp;
}

// Block reduction of per-thread 6+6 double counters (array form).
__device__ __forceinline__ void reduce12(double* s, double* q, double* partials) {
  __shared__ double lds[4][12];
  int lane = threadIdx.x & 63, wid = threadIdx.x >> 6;
#pragma unroll
  for (int k = 0; k < 12; k++) {
    double v = (k < 6) ? s[k] : q[k - 6];
#pragma unroll
    for (int off = 32; off >= 1; off >>= 1) v += __shfl_down(v, off, 64);
    if (lane == 0) lds[wid][k] = v;
  }
  __syncthreads();
  if (threadIdx.x < 12) {
    partials[(size_t)blockIdx.x * 12 + threadIdx.x] =
        lds[0][threadIdx.x] + lds[1][threadIdx.x] + lds[2][threadIdx.x] + lds[3][threadIdx.x];
  }
}

// Select form: thread contributes (s_acc,q_acc) only to counter `oidx` (<0: none).
__device__ __forceinline__ void reduce12_sel(int oidx, double s_acc, double q_acc,
                                             double* partials) {
  __shared__ double lds[4][12];
  int lane = threadIdx.x & 63, wid = threadIdx.x >> 6;
#pragma unroll
  for (int k = 0; k < 12; k++) {
    double v = (k == oidx) ? s_acc : ((k == oidx + 6) ? q_acc : 0.0);
#pragma unroll
    for (int off = 32; off >= 1; off >>= 1) v += __shfl_down(v, off, 64);
    if (lane == 0) lds[wid][k] = v;
  }
  __syncthreads();
  if (threadIdx.x < 12) {
    partials[(size_t)blockIdx.x * 12 + threadIdx.x] =
        lds[0][threadIdx.x] + lds[1][threadIdx.x] + lds[2][threadIdx.x] + lds[3][threadIdx.x];
  }
}

// ---- block1 stats: conv(1->6) over x, LDS-tiled (single-shot, no t-loop) ----
template <int NC, int H, int W, int TH, int TW>
__global__ void conv_stats_lds(const float* __restrict__ in, const float* __restrict__ wt,
                               double* __restrict__ partials) {
  constexpr int IH = TH + 2, IW = TW + 2;
  constexpr int IWP = (IW & 1) ? IW : IW + 1;  // odd row stride
  constexpr int NW = NC * 54;
  constexpr int NTH = H / TH, NTW = W / TW;
  constexpr int NT = NTH * NTW;
  __shared__ float wsm[NW];
  __shared__ float tile[NC][IH][IWP];

  int tid = threadIdx.x;
  for (int k = tid; k < NW; k += blockDim.x) wsm[k] = wt[k];

  int wg = blockIdx.x;
  int tb = wg / NT;
  int ti = wg % NT;
  int ty = ti / NTW, tx = ti % NTW;
  int h0 = ty * TH - 1, w0 = tx * TW - 1;
  const float* xb = in + (size_t)tb * NC * H * W;

  for (int k = tid; k < NC * IH * IW; k += blockDim.x) {
    int i = k / (IH * IW);
    int r = k % (IH * IW);
    int rr = r / IW, cc = r % IW;
    int hh = h0 + rr, ww = w0 + cc;
    tile[i][rr][cc] = (hh >= 0 && hh < H && ww >= 0 && ww < W) ? xb[i * H * W + hh * W + ww] : 0.0f;
  }
  __syncthreads();

  double s[6] = {0, 0, 0, 0, 0, 0}, q[6] = {0, 0, 0, 0, 0, 0};
  for (int pos = tid; pos < TH * TW; pos += blockDim.x) {
    int ly = pos / TW, lx = pos % TW;
    float acc[6] = {0, 0, 0, 0, 0, 0};
#pragma unroll
    for (int i = 0; i < NC; i++) {
      float p[9];
#pragma unroll
      for (int ky = 0; ky < 3; ky++)
#pragma unroll
        for (int kx = 0; kx < 3; kx++) p[ky * 3 + kx] = tile[i][ly + ky][lx + kx];
#pragma unroll
      for (int o = 0; o < 6; o++) {
        float a = acc[o];
#pragma unroll
        for (int k2 = 0; k2 < 9; k2++) a = fmaf(p[k2], wsm[(o * NC + i) * 9 + k2], a);
        acc[o] = a;
      }
    }
#pragma unroll
    for (int o = 0; o < 6; o++) {
      s[o] += (double)acc[o];
      q[o] += (double)acc[o] * (double)acc[o];
    }
  }
  reduce12(s, q, partials);
}

// ---- finalize: partials -> mean[6], sg[6] ----
__global__ void finalize_stats(const double* __restrict__ partials, int nb, double n,
                               const float* __restrict__ gamma,
                               float* __restrict__ mean_out, float* __restrict__ sg_out) {
  __shared__ double lds[12][21];
  __shared__ double sums[12];
  int t = threadIdx.x;
  int k = t % 12, j = t / 12;
  if (t < 252) {
    double acc = 0.0;
    for (int b = j; b < nb; b += 21) acc += partials[(size_t)b * 12 + k];
    lds[k][j] = acc;
  }
  __syncthreads();
  if (t < 12) {
    double acc = 0.0;
#pragma unroll
    for (int j2 = 0; j2 < 21; j2++) acc += lds[t][j2];
    sums[t] = acc;
  }
  __syncthreads();
  if (t < 6) {
    double mean = sums[t] / n;
    double var = sums[t + 6] / n - mean * mean;
    double invstd = 1.0 / sqrt(var + 1e-5);
    mean_out[t] = (float)mean;
    sg_out[t] = (float)(invstd * (double)gamma[t]);
  }
}

// ---- fuse1 + stats2: conv1+BN+LIF+pool (pooled halo) + conv2 stats ----
// WG: (b, oy 0..7, ox 0..24); own pooled 2x8; halo 4x10/ch. Raw tile 10x22
// stored parity-major til[2][10][11]. Staging software-pipelined (1 reg).
__global__ void fuse1_stats(const float* __restrict__ x, const float* __restrict__ w1g,
                            const float* __restrict__ w2g,
                            const float* __restrict__ mean1, const float* __restrict__ sg1,
                            const float* __restrict__ beta1,
                            float* __restrict__ pool1, double* __restrict__ partials2) {
  __shared__ float wsm1[54];
  __shared__ float wsm2[324];
  __shared__ float til[2][10][11];
  __shared__ float phl[6][4][10];

  int tid = threadIdx.x;
  for (int k = tid; k < 54; k += 256) wsm1[k] = w1g[k];
  for (int k = tid; k < 324; k += 256) wsm2[k] = w2g[k];

  int wg = blockIdx.x;
  int b = wg / 200;
  int rem = wg % 200;
  int oy = rem / 25, ox = rem % 25;
  int iy0 = 4 * oy - 3, ix0 = 16 * ox - 3;

  // staging geometry (t-invariant): thread tid<220 owns raw element (srr,scc)
  bool sactive = tid < 220;
  int srr = tid / 22, scc = tid % 22;
  int shh = iy0 + srr, sww = ix0 + scc;
  bool s_in = sactive && shh >= 0 && shh < H1 && sww >= 0 && sww < W1;
  int s_off = shh * W1 + sww;
  int lofs = (scc & 1) * 110 + srr * 11 + (scc >> 1);  // flat idx into til
  float* tilf = &til[0][0][0];

  bool active = tid < 240;
  int ch = 0, hy = 0, hx = 0, py = 0, px = 0;
  bool pvalid = false, own = false;
  if (active) {
    ch = tid / 40;
    int r = tid % 40;
    hy = r / 10; hx = r % 10;
    py = 2 * oy - 1 + hy; px = 8 * ox - 1 + hx;
    pvalid = (py >= 0 && py < P1H && px >= 0 && px < P1W);
    own = (hy >= 1 && hy <= 2 && hx >= 1 && hx <= 8);
  }
  float wv[9];
#pragma unroll
  for (int k = 0; k < 9; k++) wv[k] = active ? wsm1[ch * 9 + k] : 0.0f;
  float m = active ? mean1[ch] : 0.0f;
  float sc = active ? sg1[ch] : 0.0f;
  float be = active ? beta1[ch] : 0.0f;

  int oidx = (tid < 96) ? (tid / 16) : -1;
  int sy = (tid & 15) >> 3, sx = tid & 7;

  float v[4] = {0.0f, 0.0f, 0.0f, 0.0f};
  double s_acc = 0.0, q_acc = 0.0;

  // prologue: prefetch t=0
  float rstage = 0.0f;
  if (s_in) rstage = x[(size_t)(0 * B + b) * (H1 * W1) + s_off];

  for (int t = 0; t < T; t++) {
    __syncthreads();  // full drain: prefetch complete, prev-iter readers done
    if (sactive) tilf[lofs] = rstage;
    if (t + 1 < T && s_in)
      rstage = x[(size_t)((t + 1) * B + b) * (H1 * W1) + s_off];  // in flight across raw barriers
    LDS_PHASE_BARRIER();  // tile ready; prefetch NOT drained
    if (active) {
      float smax = 0.0f;
      if (pvalid) {
        int ry = 2 * hy;
        float p[16];
#pragma unroll
        for (int r = 0; r < 4; r++) {
          p[r * 4 + 0] = til[0][ry + r][hx];
          p[r * 4 + 1] = til[1][ry + r][hx];
          p[r * 4 + 2] = til[0][ry + r][hx + 1];
          p[r * 4 + 3] = til[1][ry + r][hx + 1];
        }
#pragma unroll
        for (int dy = 0; dy < 2; dy++) {
#pragma unroll
          for (int dx = 0; dx < 2; dx++) {
            float acc = 0.0f;
#pragma unroll
            for (int ky = 0; ky < 3; ky++)
#pragma unroll
              for (int kx = 0; kx < 3; kx++)
                acc = fmaf(p[(dy + ky) * 4 + dx + kx], wv[ky * 3 + kx], acc);
            float y = (acc - m) * sc + be;
            float sp = lif_step(v[dy * 2 + dx], y);
            smax = fmaxf(smax, sp);
          }
        }
      }
      phl[ch][hy][hx] = smax;
      if (own)
        pool1[((size_t)(t * B + b) * 6 + ch) * (P1H * P1W) + py * P1W + px] = smax;
    }
    LDS_PHASE_BARRIER();  // phl ready; prefetch still in flight
    if (oidx >= 0) {
      float acc = 0.0f;
#pragma unroll
      for (int i = 0; i < 6; i++) {
        const float* wo = &wsm2[(oidx * 6 + i) * 9];
#pragma unroll
        for (int ky = 0; ky < 3; ky++)
#pragma unroll
          for (int kx = 0; kx < 3; kx++)
            acc = fmaf(phl[i][sy + ky][sx + kx], wo[ky * 3 + kx], acc);
      }
      s_acc += (double)acc;
      q_acc += (double)acc * (double)acc;
    }
  }
  __syncthreads();
  reduce12_sel(oidx, s_acc, q_acc, partials2);
}

// ---- fuse2 + stats3: conv2+BN+LIF+pool (pooled halo) + conv3 stats ----
// WG: (b, oy 0..3, ox 0..19); own pooled 2x5; halo 4x7/ch. Raw tile 6x10x16
// stored parity-major til[2][6][10][9]. Staging pipelined (4 reg slots).
__global__ void fuse2_stats(const float* __restrict__ in, const float* __restrict__ w2g,
                            const float* __restrict__ w3g,
                            const float* __restrict__ mean2, const float* __restrict__ sg2,
                            const float* __restrict__ beta2,
                            float* __restrict__ pool2, double* __restrict__ partials3) {
  __shared__ float wsm2[324];
  __shared__ float wsm3[324];
  __shared__ float til[2][6][10][9];
  __shared__ float phl[6][4][7];

  int tid = threadIdx.x;
  for (int k = tid; k < 324; k += 256) { wsm2[k] = w2g[k]; wsm3[k] = w3g[k]; }

  int wg = blockIdx.x;
  int b = wg / 80;
  int rem = wg % 80;
  int oy = rem / 20, ox = rem % 20;
  int iy0 = 4 * oy - 3, ix0 = 10 * ox - 3;
  constexpr int HW = H2 * W2;

  // staging geometry (t-invariant): 960 raw elements, 4 slots per thread
  bool s_in[4];
  int s_off[4], s_lofs[4];
#pragma unroll
  for (int j = 0; j < 4; j++) {
    int k = tid + 256 * j;
    bool valid = k < 960;
    int i = k / 160;
    int r2 = k % 160;
    int rr = r2 / 16, cc = r2 % 16;
    int hh = iy0 + rr, ww = ix0 + cc;
    s_in[j] = valid && hh >= 0 && hh < H2 && ww >= 0 && ww < W2;
    s_off[j] = i * HW + hh * W2 + ww;
    s_lofs[j] = valid ? (((cc & 1) * 6 + i) * 90 + rr * 9 + (cc >> 1)) : -1;
  }
  float* tilf = &til[0][0][0][0];

  bool active = tid < 168;
  int ch = 0, hy = 0, hx = 0, py = 0, px = 0;
  bool pvalid = false, own = false;
  if (active) {
    ch = tid / 28;
    int r = tid % 28;
    hy = r / 7; hx = r % 7;
    py = 2 * oy - 1 + hy; px = 5 * ox - 1 + hx;
    pvalid = (py >= 0 && py < P2H && px >= 0 && px < P2W);
    own = (hy >= 1 && hy <= 2 && hx >= 1 && hx <= 5);
  }
  float m = active ? mean2[ch] : 0.0f;
  float sc = active ? sg2[ch] : 0.0f;
  float be = active ? beta2[ch] : 0.0f;

  int oidx = (tid < 60) ? (tid / 10) : -1;
  int pp = tid % 10;
  int sy = pp / 5, sx = pp % 5;

  float v[4] = {0.0f, 0.0f, 0.0f, 0.0f};
  double s_acc = 0.0, q_acc = 0.0;

  // prologue: prefetch t=0
  float rs[4] = {0.0f, 0.0f, 0.0f, 0.0f};
  {
    const float* xb = in + (size_t)(0 * B + b) * 6 * HW;
#pragma unroll
    for (int j = 0; j < 4; j++)
      if (s_in[j]) rs[j] = xb[s_off[j]];
  }

  for (int t = 0; t < T; t++) {
    __syncthreads();  // full drain: prefetch complete, prev readers done
#pragma unroll
    for (int j = 0; j < 4; j++)
      if (s_lofs[j] >= 0) tilf[s_lofs[j]] = rs[j];
    if (t + 1 < T) {
      const float* xb = in + (size_t)((t + 1) * B + b) * 6 * HW;
#pragma unroll
      for (int j = 0; j < 4; j++)
        if (s_in[j]) rs[j] = xb[s_off[j]];
    }
    LDS_PHASE_BARRIER();  // tile ready; prefetch NOT drained
    if (active) {
      float smax = 0.0f;
      if (pvalid) {
        int ry = 2 * hy;
        float acc4[4] = {0.0f, 0.0f, 0.0f, 0.0f};
#pragma unroll
        for (int i = 0; i < 6; i++) {
          float p[16];
#pragma unroll
          for (int r = 0; r < 4; r++) {
            p[r * 4 + 0] = til[0][i][ry + r][hx];
            p[r * 4 + 1] = til[1][i][ry + r][hx];
            p[r * 4 + 2] = til[0][i][ry + r][hx + 1];
            p[r * 4 + 3] = til[1][i][ry + r][hx + 1];
          }
          const float* wo = &wsm2[(ch * 6 + i) * 9];
#pragma unroll
          for (int dy = 0; dy < 2; dy++)
#pragma unroll
            for (int dx = 0; dx < 2; dx++) {
              float a = acc4[dy * 2 + dx];
#pragma unroll
              for (int ky = 0; ky < 3; ky++)
#pragma unroll
                for (int kx = 0; kx < 3; kx++)
                  a = fmaf(p[(dy + ky) * 4 + dx + kx], wo[ky * 3 + kx], a);
              acc4[dy * 2 + dx] = a;
            }
        }
#pragma unroll
        for (int p4 = 0; p4 < 4; p4++) {
          float y = (acc4[p4] - m) * sc + be;
          float sp = lif_step(v[p4], y);
          smax = fmaxf(smax, sp);
        }
      }
      phl[ch][hy][hx] = smax;
      if (own)
        pool2[((size_t)(t * B + b) * 6 + ch) * (P2H * P2W) + py * P2W + px] = smax;
    }
    LDS_PHASE_BARRIER();  // phl ready; prefetch still in flight
    if (oidx >= 0) {
      float acc = 0.0f;
#pragma unroll
      for (int i = 0; i < 6; i++) {
        const float* wo = &wsm3[(oidx * 6 + i) * 9];
#pragma unroll
        for (int ky = 0; ky < 3; ky++)
#pragma unroll
          for (int kx = 0; kx < 3; kx++)
            acc = fmaf(phl[i][sy + ky][sx + kx], wo[ky * 3 + kx], acc);
      }
      s_acc += (double)acc;
      q_acc += (double)acc * (double)acc;
    }
  }
  __syncthreads();
  reduce12_sel(oidx, s_acc, q_acc, partials3);
}

// ---- block 3 fuse: conv(6->6)+BN+LIF+pool, parity-split LDS tiles ----
template <int H, int W, int PH, int PW, int TH, int TW>
__global__ void block6_fuse_lds(const float* __restrict__ in, const float* __restrict__ wt,
                                const float* __restrict__ mean, const float* __restrict__ sg,
                                const float* __restrict__ beta, float* __restrict__ out) {
  constexpr int NTH = PH / TH, NTW = PW / TW;
  constexpr int IH = 2 * TH + 2, IW = 2 * TW + 2;
  constexpr int EW = IW / 2;  // 11 for TW=10 (odd stride)
  constexpr int TILE_N = IH * IW;
  constexpr int NACT = 6 * TH * TW;
  constexpr int HW = H * W;
  __shared__ float wsm[324];
  __shared__ float til_e[6][IH][EW];
  __shared__ float til_o[6][IH][EW];

  for (int k = threadIdx.x; k < 324; k += blockDim.x) wsm[k] = wt[k];

  int wg = blockIdx.x;
  int b = wg / (NTH * NTW);
  int tid2 = wg % (NTH * NTW);
  int ty = tid2 / NTW, tx = tid2 % NTW;
  int h_in0 = 2 * (ty * TH) - 1, w_in0 = 2 * (tx * TW) - 1;

  int tid = threadIdx.x;
  int o = 0, lph = 0, lpw = 0;
  if (tid < NACT) {
    o = tid / (TH * TW);
    int r = tid % (TH * TW);
    lph = r / TW; lpw = r % TW;
  }
  float m = mean[o], s = sg[o], be = beta[o];
  float v[4] = {0.0f, 0.0f, 0.0f, 0.0f};

  for (int t = 0; t < T; t++) {
    __syncthreads();
    const float* xb = in + (size_t)(t * B + b) * 6 * HW;
    for (int k = tid; k < 6 * TILE_N; k += blockDim.x) {
      int i = k / TILE_N;
      int r2 = k % TILE_N;
      int rr = r2 / IW, cc = r2 % IW;
      int hh = h_in0 + rr, ww = w_in0 + cc;
      float val = (hh >= 0 && hh < H && ww >= 0 && ww < W) ? xb[i * HW + hh * W + ww] : 0.0f;
      if (cc & 1) til_o[i][rr][cc >> 1] = val;
      else        til_e[i][rr][cc >> 1] = val;
    }
    __syncthreads();
    if (tid < NACT) {
      int ry = 2 * lph;
      float acc[4] = {0.0f, 0.0f, 0.0f, 0.0f};
#pragma unroll
      for (int i = 0; i < 6; i++) {
        float p[16];
#pragma unroll
        for (int r = 0; r < 4; r++) {
          p[r * 4 + 0] = til_e[i][ry + r][lpw];
          p[r * 4 + 1] = til_o[i][ry + r][lpw];
          p[r * 4 + 2] = til_e[i][ry + r][lpw + 1];
          p[r * 4 + 3] = til_o[i][ry + r][lpw + 1];
        }
        const float* wo = &wsm[(o * 6 + i) * 9];
#pragma unroll
        for (int dy = 0; dy < 2; dy++)
#pragma unroll
          for (int dx = 0; dx < 2; dx++) {
            float a = acc[dy * 2 + dx];
#pragma unroll
            for (int ky = 0; ky < 3; ky++)
#pragma unroll
              for (int kx = 0; kx < 3; kx++)
                a = fmaf(p[(dy + ky) * 4 + dx + kx], wo[ky * 3 + kx], a);
            acc[dy * 2 + dx] = a;
          }
      }
      float smax = 0.0f;
#pragma unroll
      for (int p4 = 0; p4 < 4; p4++) {
        float y = (acc[p4] - m) * s + be;
        float sp = lif_step(v[p4], y);
        smax = fmaxf(smax, sp);
      }
      out[((size_t)(t * B + b) * 6 + o) * (PH * PW) + (ty * TH + lph) * PW + (tx * TW + lpw)] = smax;
    }
  }
}

// ---- FC head ----
__global__ void fc1_mm(const float* __restrict__ p3, const float* __restrict__ fw1,
                       float* __restrict__ u1) {
  int idx = blockIdx.x * blockDim.x + threadIdx.x;
  if (idx >= T * B * 100) return;
  int o = idx % 100;
  int tb = idx / 100;
  const float4* x4 = (const float4*)(p3 + (size_t)tb * 1200);
  const float4* w4 = (const float4*)(fw1 + (size_t)o * 1200);
  float acc = 0.0f;
#pragma unroll 4
  for (int k = 0; k < 300; k++) {
    float4 a = x4[k], w = w4[k];
    acc = fmaf(a.x, w.x, acc);
    acc = fmaf(a.y, w.y, acc);
    acc = fmaf(a.z, w.z, acc);
    acc = fmaf(a.w, w.w, acc);
  }
  u1[idx] = acc;
}

__global__ void fc1_lif(const float* __restrict__ u1, float* __restrict__ s1) {
  int idx = blockIdx.x * blockDim.x + threadIdx.x;
  if (idx >= B * 100) return;
  float v = 0.0f;
  for (int t = 0; t < T; t++) {
    float sp = lif_step(v, u1[(size_t)t * B * 100 + idx]);
    s1[(size_t)t * B * 100 + idx] = sp;
  }
}

__global__ void fc2_fused(const float* __restrict__ s1, const float* __restrict__ fw2,
                          float* __restrict__ outp) {
  int idx = blockIdx.x * blockDim.x + threadIdx.x;
  if (idx >= B * 2) return;
  int b = idx >> 1, o = idx & 1;
  const float* wr = fw2 + o * 100;
  float v = 0.0f;
  for (int t = 0; t < T; t++) {
    const float* sr = s1 + (size_t)(t * B + b) * 100;
    float acc = 0.0f;
#pragma unroll
    for (int k = 0; k < 100; k++) acc = fmaf(sr[k], wr[k], acc);
    float sp = lif_step(v, acc);
    outp[(size_t)(t * B + b) * 2 + o] = sp;
  }
}

extern "C" void kernel_launch(void* const* d_in, const int* in_sizes, int n_in,
                              void* d_out, int out_size, void* d_ws, size_t ws_size,
                              hipStream_t stream) {
  const float* x   = (const float*)d_in[0];
  const float* w1  = (const float*)d_in[1];
  const float* g1  = (const float*)d_in[2];
  const float* b1  = (const float*)d_in[3];
  const float* w2  = (const float*)d_in[4];
  const float* g2  = (const float*)d_in[5];
  const float* b2  = (const float*)d_in[6];
  const float* w3  = (const float*)d_in[7];
  const float* g3  = (const float*)d_in[8];
  const float* b3  = (const float*)d_in[9];
  const float* fw1 = (const float*)d_in[10];
  const float* fw2 = (const float*)d_in[11];
  float* out = (float*)d_out;

  char* ws = (char*)d_ws;
  double* part1  = (double*)(ws + OFF_PART1);
  double* partf1 = (double*)(ws + OFF_PARTF1);
  double* partf2 = (double*)(ws + OFF_PARTF2);
  float* mean1 = (float*)(ws + OFF_STATS + 0);
  float* sg1   = (float*)(ws + OFF_STATS + 32);
  float* mean2 = (float*)(ws + OFF_STATS + 64);
  float* sg2   = (float*)(ws + OFF_STATS + 96);
  float* mean3 = (float*)(ws + OFF_STATS + 128);
  float* sg3   = (float*)(ws + OFF_STATS + 160);
  float* pool1 = (float*)(ws + OFF_POOL1);
  float* pool2 = (float*)(ws + OFF_POOL2);
  float* pool3 = (float*)(ws + OFF_POOL3);
  float* u1    = (float*)(ws + OFF_U1);
  float* s1    = (float*)(ws + OFF_S1);

  // Block 1 stats + finalize
  conv_stats_lds<1, H1, W1, 32, 100><<<NWG_S1, 256, 0, stream>>>(x, w1, part1);
  finalize_stats<<<1, 256, 0, stream>>>(part1, NWG_S1, (double)T * B * H1 * W1, g1, mean1, sg1);
  // fuse1 (+ stats for block2)
  fuse1_stats<<<NWG_F1, 256, 0, stream>>>(x, w1, w2, mean1, sg1, b1, pool1, partf1);
  finalize_stats<<<1, 256, 0, stream>>>(partf1, NWG_F1, (double)T * B * H2 * W2, g2, mean2, sg2);
  // fuse2 (+ stats for block3)
  fuse2_stats<<<NWG_F2, 256, 0, stream>>>(pool1, w2, w3, mean2, sg2, b2, pool2, partf2);
  finalize_stats<<<1, 256, 0, stream>>>(partf2, NWG_F2, (double)T * B * H3 * W3, g3, mean3, sg3);
  // Block 3 fuse
  {
    int nwg = B * (P3H / 4) * (P3W / 10);  // 160
    block6_fuse_lds<H3, W3, P3H, P3W, 4, 10><<<nwg, 256, 0, stream>>>(pool2, w3, mean3, sg3, b3, pool3);
  }
  // FC head
  {
    int n = T * B * 100;
    fc1_mm<<<(n + 255) / 256, 256, 0, stream>>>(pool3, fw1, u1);
  }
  {
    int n = B * 100;
    fc1_lif<<<(n + 255) / 256, 256, 0, stream>>>(u1, s1);
  }
  fc2_fused<<<1, 64, 0, stream>>>(s1, fw2, out);
}

// Round 12
// 594.512 us; speedup vs baseline: 1.6362x; 1.0031x over previous
//
#include <hip/hip_runtime.h>

// SNN forward: 3x (conv3x3 -> tdBN -> LIF -> maxpool2) + 2x (FC -> LIF)
// x [16,32,1,32,400] -> pool1 [16,32,6,16,200] -> pool2 [16,32,6,8,100]
//   -> pool3 [16,32,6,4,50] -> fc1 [16,32,100] -> out [16,32,2]
//
// Round-12: fuse kernels are LDS-issue-bound (r11 model: 176 wave LDS-ops/WG-t
// x 25 WG/CU x 16 t x 5.8cyc ~= 170us, matches measured 182). Biggest consumer:
// conv-stats phase, 54 scalar phl reads/thread with no reuse. Fix: i-split —
// thread (i,pos) reads its channel's 9 taps, computes 6 out-ch partials, LDS
// partial buffer + double-sum reduce by (o,pos) threads. 108 -> ~42 wave-ops.
// Output-path FMA order unchanged (stats perturbation <=1ulp, washed out in
// double aggregation).

namespace {

constexpr int T = 16, B = 32;
constexpr int H1 = 32, W1 = 400, P1H = 16, P1W = 200;
constexpr int H2 = 16, W2 = 200, P2H = 8,  P2W = 100;
constexpr int H3 = 8,  W3 = 100, P3H = 4,  P3W = 50;

constexpr int NWG_S1 = T * B * (H1 / 32) * (W1 / 100);  // 2048
constexpr int NWG_F1 = B * (P1H / 2) * (P1W / 8);       // 6400
constexpr int NWG_F2 = B * (P2H / 2) * (P2W / 5);       // 2560

constexpr size_t OFF_PART1  = 0;
constexpr size_t OFF_PARTF1 = OFF_PART1 + (size_t)NWG_S1 * 12 * 8;
constexpr size_t OFF_PARTF2 = OFF_PARTF1 + (size_t)NWG_F1 * 12 * 8;
constexpr size_t OFF_STATS  = OFF_PARTF2 + (size_t)NWG_F2 * 12 * 8;
constexpr size_t OFF_POOL1  = 1310720;
constexpr size_t OFF_POOL2  = OFF_POOL1 + (size_t)T * B * 6 * P1H * P1W * 4;
constexpr size_t OFF_POOL3  = OFF_POOL2 + (size_t)T * B * 6 * P2H * P2W * 4;
constexpr size_t OFF_U1     = OFF_POOL3 + (size_t)T * B * 6 * P3H * P3W * 4;
constexpr size_t OFF_S1     = OFF_U1 + (size_t)T * B * 100 * 4;

} // namespace

// LDS-only phase barrier: waits own ds ops, does NOT drain vmcnt (prefetch
// loads stay in flight across it). "memory" clobber pins memory-op order.
#define LDS_PHASE_BARRIER()                                   \
  do {                                                        \
    asm volatile("s_waitcnt lgkmcnt(0)" ::: "memory");        \
    __builtin_amdgcn_s_barrier();                             \
    __builtin_amdgcn_sched_barrier(0);                        \
  } while (0)

__device__ __forceinline__ float lif_step(float& v, float y) {
  v = v + (y - v) * 0.5f;                 // tau=2, decay_input
  float sp = (v >= 1.0f) ? 1.0f : 0.0f;   // threshold 1.0
  v = (sp > 0.0f) ? 0.0f : v;             // hard reset
  return sp;
}

// Block reduction of per-thread 6+6 double counters (array form).
__device__ __forceinline__ void reduce12(double* s, double* q, double* partials) {
  __shared__ double lds[4][12];
  int lane = threadIdx.x & 63, wid = threadIdx.x >> 6;
#pragma unroll
  for (int k = 0; k < 12; k++) {
    double v = (k < 6) ? s[k] : q[k - 6];
#pragma unroll
    for (int off = 32; off >= 1; off >>= 1) v += __shfl_down(v, off, 64);
    if (lane == 0) lds[wid][k] = v;
  }
  __syncthreads();
  if (threadIdx.x < 12) {
    partials[(size_t)blockIdx.x * 12 + threadIdx.x] =
        lds[0][threadIdx.x] + lds[1][threadIdx.x] + lds[2][threadIdx.x] + lds[3][threadIdx.x];
  }
}

// Select form: thread contributes (s_acc,q_acc) only to counter `oidx` (<0: none).
__device__ __forceinline__ void reduce12_sel(int oidx, double s_acc, double q_acc,
                                             double* partials) {
  __shared__ double lds[4][12];
  int lane = threadIdx.x & 63, wid = threadIdx.x >> 6;
#pragma unroll
  for (int k = 0; k < 12; k++) {
    double v = (k == oidx) ? s_acc : ((k == oidx + 6) ? q_acc : 0.0);
#pragma unroll
    for (int off = 32; off >= 1; off >>= 1) v += __shfl_down(v, off, 64);
    if (lane == 0) lds[wid][k] = v;
  }
  __syncthreads();
  if (threadIdx.x < 12) {
    partials[(size_t)blockIdx.x * 12 + threadIdx.x] =
        lds[0][threadIdx.x] + lds[1][threadIdx.x] + lds[2][threadIdx.x] + lds[3][threadIdx.x];
  }
}

// ---- block1 stats: conv(1->6) over x, LDS-tiled (single-shot, no t-loop) ----
template <int NC, int H, int W, int TH, int TW>
__global__ void conv_stats_lds(const float* __restrict__ in, const float* __restrict__ wt,
                               double* __restrict__ partials) {
  constexpr int IH = TH + 2, IW = TW + 2;
  constexpr int IWP = (IW & 1) ? IW : IW + 1;  // odd row stride
  constexpr int NW = NC * 54;
  constexpr int NTH = H / TH, NTW = W / TW;
  constexpr int NT = NTH * NTW;
  __shared__ float wsm[NW];
  __shared__ float tile[NC][IH][IWP];

  int tid = threadIdx.x;
  for (int k = tid; k < NW; k += blockDim.x) wsm[k] = wt[k];

  int wg = blockIdx.x;
  int tb = wg / NT;
  int ti = wg % NT;
  int ty = ti / NTW, tx = ti % NTW;
  int h0 = ty * TH - 1, w0 = tx * TW - 1;
  const float* xb = in + (size_t)tb * NC * H * W;

  for (int k = tid; k < NC * IH * IW; k += blockDim.x) {
    int i = k / (IH * IW);
    int r = k % (IH * IW);
    int rr = r / IW, cc = r % IW;
    int hh = h0 + rr, ww = w0 + cc;
    tile[i][rr][cc] = (hh >= 0 && hh < H && ww >= 0 && ww < W) ? xb[i * H * W + hh * W + ww] : 0.0f;
  }
  __syncthreads();

  double s[6] = {0, 0, 0, 0, 0, 0}, q[6] = {0, 0, 0, 0, 0, 0};
  for (int pos = tid; pos < TH * TW; pos += blockDim.x) {
    int ly = pos / TW, lx = pos % TW;
    float acc[6] = {0, 0, 0, 0, 0, 0};
#pragma unroll
    for (int i = 0; i < NC; i++) {
      float p[9];
#pragma unroll
      for (int ky = 0; ky < 3; ky++)
#pragma unroll
        for (int kx = 0; kx < 3; kx++) p[ky * 3 + kx] = tile[i][ly + ky][lx + kx];
#pragma unroll
      for (int o = 0; o < 6; o++) {
        float a = acc[o];
#pragma unroll
        for (int k2 = 0; k2 < 9; k2++) a = fmaf(p[k2], wsm[(o * NC + i) * 9 + k2], a);
        acc[o] = a;
      }
    }
#pragma unroll
    for (int o = 0; o < 6; o++) {
      s[o] += (double)acc[o];
      q[o] += (double)acc[o] * (double)acc[o];
    }
  }
  reduce12(s, q, partials);
}

// ---- finalize: partials -> mean[6], sg[6] ----
__global__ void finalize_stats(const double* __restrict__ partials, int nb, double n,
                               const float* __restrict__ gamma,
                               float* __restrict__ mean_out, float* __restrict__ sg_out) {
  __shared__ double lds[12][21];
  __shared__ double sums[12];
  int t = threadIdx.x;
  int k = t % 12, j = t / 12;
  if (t < 252) {
    double acc = 0.0;
    for (int b = j; b < nb; b += 21) acc += partials[(size_t)b * 12 + k];
    lds[k][j] = acc;
  }
  __syncthreads();
  if (t < 12) {
    double acc = 0.0;
#pragma unroll
    for (int j2 = 0; j2 < 21; j2++) acc += lds[t][j2];
    sums[t] = acc;
  }
  __syncthreads();
  if (t < 6) {
    double mean = sums[t] / n;
    double var = sums[t + 6] / n - mean * mean;
    double invstd = 1.0 / sqrt(var + 1e-5);
    mean_out[t] = (float)mean;
    sg_out[t] = (float)(invstd * (double)gamma[t]);
  }
}

// ---- fuse1 + stats2: conv1+BN+LIF+pool (pooled halo) + conv2 stats ----
// WG: (b, oy 0..7, ox 0..24); own pooled 2x8; halo 4x10/ch. Raw tile 10x22
// stored parity-major til[2][10][11]. Staging software-pipelined (1 reg).
// conv2-stats: i-split — thread (i,pos) computes 6-o partials from 9 reads,
// LDS partial buffer pr, reduce by (o,pos) threads in double.
__global__ void fuse1_stats(const float* __restrict__ x, const float* __restrict__ w1g,
                            const float* __restrict__ w2g,
                            const float* __restrict__ mean1, const float* __restrict__ sg1,
                            const float* __restrict__ beta1,
                            float* __restrict__ pool1, double* __restrict__ partials2) {
  __shared__ float wsm1[54];
  __shared__ float wsm2[324];
  __shared__ float til[2][10][11];
  __shared__ float phl[6][4][10];
  __shared__ float pr[16][6][7];  // [pos][i][o], odd i-stride

  int tid = threadIdx.x;
  for (int k = tid; k < 54; k += 256) wsm1[k] = w1g[k];
  for (int k = tid; k < 324; k += 256) wsm2[k] = w2g[k];

  int wg = blockIdx.x;
  int b = wg / 200;
  int rem = wg % 200;
  int oy = rem / 25, ox = rem % 25;
  int iy0 = 4 * oy - 3, ix0 = 16 * ox - 3;

  // staging geometry (t-invariant)
  bool sactive = tid < 220;
  int srr = tid / 22, scc = tid % 22;
  int shh = iy0 + srr, sww = ix0 + scc;
  bool s_in = sactive && shh >= 0 && shh < H1 && sww >= 0 && sww < W1;
  int s_off = shh * W1 + sww;
  int lofs = (scc & 1) * 110 + srr * 11 + (scc >> 1);
  float* tilf = &til[0][0][0];

  bool active = tid < 240;
  int ch = 0, hy = 0, hx = 0, py = 0, px = 0;
  bool pvalid = false, own = false;
  if (active) {
    ch = tid / 40;
    int r = tid % 40;
    hy = r / 10; hx = r % 10;
    py = 2 * oy - 1 + hy; px = 8 * ox - 1 + hx;
    pvalid = (py >= 0 && py < P1H && px >= 0 && px < P1W);
    own = (hy >= 1 && hy <= 2 && hx >= 1 && hx <= 8);
  }
  float wv[9];
#pragma unroll
  for (int k = 0; k < 9; k++) wv[k] = active ? wsm1[ch * 9 + k] : 0.0f;
  float m = active ? mean1[ch] : 0.0f;
  float sc = active ? sg1[ch] : 0.0f;
  float be = active ? beta1[ch] : 0.0f;

  int oidx = (tid < 96) ? (tid / 16) : -1;  // out-ch for reduce phase
  int pos16 = tid & 15;
  int i2 = tid / 16;                         // input ch for partial phase (tid<96)
  int psy = (pos16 >> 3), psx = pos16 & 7;

  float v[4] = {0.0f, 0.0f, 0.0f, 0.0f};
  double s_acc = 0.0, q_acc = 0.0;

  // prologue: prefetch t=0
  float rstage = 0.0f;
  if (s_in) rstage = x[(size_t)(0 * B + b) * (H1 * W1) + s_off];

  for (int t = 0; t < T; t++) {
    __syncthreads();  // full drain: prefetch complete, prev-iter readers done
    if (sactive) tilf[lofs] = rstage;
    if (t + 1 < T && s_in)
      rstage = x[(size_t)((t + 1) * B + b) * (H1 * W1) + s_off];  // stays in flight
    LDS_PHASE_BARRIER();  // tile ready; prefetch NOT drained
    if (active) {
      float smax = 0.0f;
      if (pvalid) {
        int ry = 2 * hy;
        float p[16];
#pragma unroll
        for (int r = 0; r < 4; r++) {
          p[r * 4 + 0] = til[0][ry + r][hx];
          p[r * 4 + 1] = til[1][ry + r][hx];
          p[r * 4 + 2] = til[0][ry + r][hx + 1];
          p[r * 4 + 3] = til[1][ry + r][hx + 1];
        }
#pragma unroll
        for (int dy = 0; dy < 2; dy++) {
#pragma unroll
          for (int dx = 0; dx < 2; dx++) {
            float acc = 0.0f;
#pragma unroll
            for (int ky = 0; ky < 3; ky++)
#pragma unroll
              for (int kx = 0; kx < 3; kx++)
                acc = fmaf(p[(dy + ky) * 4 + dx + kx], wv[ky * 3 + kx], acc);
            float y = (acc - m) * sc + be;
            float sp = lif_step(v[dy * 2 + dx], y);
            smax = fmaxf(smax, sp);
          }
        }
      }
      phl[ch][hy][hx] = smax;
      if (own)
        pool1[((size_t)(t * B + b) * 6 + ch) * (P1H * P1W) + py * P1W + px] = smax;
    }
    LDS_PHASE_BARRIER();  // phl ready
    if (tid < 96) {  // partial: input ch i2, position (psy,psx)
      float pt[9];
#pragma unroll
      for (int ky = 0; ky < 3; ky++)
#pragma unroll
        for (int kx = 0; kx < 3; kx++)
          pt[ky * 3 + kx] = phl[i2][psy + ky][psx + kx];
      float p6[6];
#pragma unroll
      for (int o = 0; o < 6; o++) {
        float a = 0.0f;
#pragma unroll
        for (int k2 = 0; k2 < 9; k2++) a = fmaf(pt[k2], wsm2[(o * 6 + i2) * 9 + k2], a);
        p6[o] = a;
      }
#pragma unroll
      for (int o = 0; o < 6; o++) pr[pos16][i2][o] = p6[o];
    }
    LDS_PHASE_BARRIER();  // pr ready
    if (oidx >= 0) {  // reduce: out-ch oidx, position pos16
      double acc = 0.0;
#pragma unroll
      for (int ic = 0; ic < 6; ic++) acc += (double)pr[pos16][ic][oidx];
      s_acc += acc;
      q_acc += acc * acc;
    }
  }
  __syncthreads();
  reduce12_sel(oidx, s_acc, q_acc, partials2);
}

// ---- fuse2 + stats3: conv2+BN+LIF+pool (pooled halo) + conv3 stats ----
// WG: (b, oy 0..3, ox 0..19); own pooled 2x5; halo 4x7/ch. Raw tile 6x10x16
// stored parity-major til[2][6][10][9]. Staging pipelined (4 reg slots).
// conv3-stats i-split as in fuse1.
__global__ void fuse2_stats(const float* __restrict__ in, const float* __restrict__ w2g,
                            const float* __restrict__ w3g,
                            const float* __restrict__ mean2, const float* __restrict__ sg2,
                            const float* __restrict__ beta2,
                            float* __restrict__ pool2, double* __restrict__ partials3) {
  __shared__ float wsm2[324];
  __shared__ float wsm3[324];
  __shared__ float til[2][6][10][9];
  __shared__ float phl[6][4][7];
  __shared__ float pr[10][6][7];  // [pos][i][o]

  int tid = threadIdx.x;
  for (int k = tid; k < 324; k += 256) { wsm2[k] = w2g[k]; wsm3[k] = w3g[k]; }

  int wg = blockIdx.x;
  int b = wg / 80;
  int rem = wg % 80;
  int oy = rem / 20, ox = rem % 20;
  int iy0 = 4 * oy - 3, ix0 = 10 * ox - 3;
  constexpr int HW = H2 * W2;

  // staging geometry (t-invariant): 960 raw elements, 4 slots per thread
  bool s_in[4];
  int s_off[4], s_lofs[4];
#pragma unroll
  for (int j = 0; j < 4; j++) {
    int k = tid + 256 * j;
    bool valid = k < 960;
    int i = k / 160;
    int r2 = k % 160;
    int rr = r2 / 16, cc = r2 % 16;
    int hh = iy0 + rr, ww = ix0 + cc;
    s_in[j] = valid && hh >= 0 && hh < H2 && ww >= 0 && ww < W2;
    s_off[j] = i * HW + hh * W2 + ww;
    s_lofs[j] = valid ? (((cc & 1) * 6 + i) * 90 + rr * 9 + (cc >> 1)) : -1;
  }
  float* tilf = &til[0][0][0][0];

  bool active = tid < 168;
  int ch = 0, hy = 0, hx = 0, py = 0, px = 0;
  bool pvalid = false, own = false;
  if (active) {
    ch = tid / 28;
    int r = tid % 28;
    hy = r / 7; hx = r % 7;
    py = 2 * oy - 1 + hy; px = 5 * ox - 1 + hx;
    pvalid = (py >= 0 && py < P2H && px >= 0 && px < P2W);
    own = (hy >= 1 && hy <= 2 && hx >= 1 && hx <= 5);
  }
  float m = active ? mean2[ch] : 0.0f;
  float sc = active ? sg2[ch] : 0.0f;
  float be = active ? beta2[ch] : 0.0f;

  int oidx = (tid < 60) ? (tid / 10) : -1;  // out-ch for reduce; also i2 for partial
  int pp = tid % 10;
  int psy = pp / 5, psx = pp % 5;
  int i2 = tid / 10;

  float v[4] = {0.0f, 0.0f, 0.0f, 0.0f};
  double s_acc = 0.0, q_acc = 0.0;

  // prologue: prefetch t=0
  float rs[4] = {0.0f, 0.0f, 0.0f, 0.0f};
  {
    const float* xb = in + (size_t)(0 * B + b) * 6 * HW;
#pragma unroll
    for (int j = 0; j < 4; j++)
      if (s_in[j]) rs[j] = xb[s_off[j]];
  }

  for (int t = 0; t < T; t++) {
    __syncthreads();  // full drain
#pragma unroll
    for (int j = 0; j < 4; j++)
      if (s_lofs[j] >= 0) tilf[s_lofs[j]] = rs[j];
    if (t + 1 < T) {
      const float* xb = in + (size_t)((t + 1) * B + b) * 6 * HW;
#pragma unroll
      for (int j = 0; j < 4; j++)
        if (s_in[j]) rs[j] = xb[s_off[j]];
    }
    LDS_PHASE_BARRIER();  // tile ready
    if (active) {
      float smax = 0.0f;
      if (pvalid) {
        int ry = 2 * hy;
        float acc4[4] = {0.0f, 0.0f, 0.0f, 0.0f};
#pragma unroll
        for (int i = 0; i < 6; i++) {
          float p[16];
#pragma unroll
          for (int r = 0; r < 4; r++) {
            p[r * 4 + 0] = til[0][i][ry + r][hx];
            p[r * 4 + 1] = til[1][i][ry + r][hx];
            p[r * 4 + 2] = til[0][i][ry + r][hx + 1];
            p[r * 4 + 3] = til[1][i][ry + r][hx + 1];
          }
          const float* wo = &wsm2[(ch * 6 + i) * 9];
#pragma unroll
          for (int dy = 0; dy < 2; dy++)
#pragma unroll
            for (int dx = 0; dx < 2; dx++) {
              float a = acc4[dy * 2 + dx];
#pragma unroll
              for (int ky = 0; ky < 3; ky++)
#pragma unroll
                for (int kx = 0; kx < 3; kx++)
                  a = fmaf(p[(dy + ky) * 4 + dx + kx], wo[ky * 3 + kx], a);
              acc4[dy * 2 + dx] = a;
            }
        }
#pragma unroll
        for (int p4 = 0; p4 < 4; p4++) {
          float y = (acc4[p4] - m) * sc + be;
          float sp = lif_step(v[p4], y);
          smax = fmaxf(smax, sp);
        }
      }
      phl[ch][hy][hx] = smax;
      if (own)
        pool2[((size_t)(t * B + b) * 6 + ch) * (P2H * P2W) + py * P2W + px] = smax;
    }
    LDS_PHASE_BARRIER();  // phl ready
    if (tid < 60) {  // partial: input ch i2, position (psy,psx)
      float pt[9];
#pragma unroll
      for (int ky = 0; ky < 3; ky++)
#pragma unroll
        for (int kx = 0; kx < 3; kx++)
          pt[ky * 3 + kx] = phl[i2][psy + ky][psx + kx];
      float p6[6];
#pragma unroll
      for (int o = 0; o < 6; o++) {
        float a = 0.0f;
#pragma unroll
        for (int k2 = 0; k2 < 9; k2++) a = fmaf(pt[k2], wsm3[(o * 6 + i2) * 9 + k2], a);
        p6[o] = a;
      }
#pragma unroll
      for (int o = 0; o < 6; o++) pr[pp][i2][o] = p6[o];
    }
    LDS_PHASE_BARRIER();  // pr ready
    if (oidx >= 0) {
      double acc = 0.0;
#pragma unroll
      for (int ic = 0; ic < 6; ic++) acc += (double)pr[pp][ic][oidx];
      s_acc += acc;
      q_acc += acc * acc;
    }
  }
  __syncthreads();
  reduce12_sel(oidx, s_acc, q_acc, partials3);
}

// ---- block 3 fuse: conv(6->6)+BN+LIF+pool, parity-split LDS tiles ----
template <int H, int W, int PH, int PW, int TH, int TW>
__global__ void block6_fuse_lds(const float* __restrict__ in, const float* __restrict__ wt,
                                const float* __restrict__ mean, const float* __restrict__ sg,
                                const float* __restrict__ beta, float* __restrict__ out) {
  constexpr int NTH = PH / TH, NTW = PW / TW;
  constexpr int IH = 2 * TH + 2, IW = 2 * TW + 2;
  constexpr int EW = IW / 2;  // 11 for TW=10 (odd stride)
  constexpr int TILE_N = IH * IW;
  constexpr int NACT = 6 * TH * TW;
  constexpr int HW = H * W;
  __shared__ float wsm[324];
  __shared__ float til_e[6][IH][EW];
  __shared__ float til_o[6][IH][EW];

  for (int k = threadIdx.x; k < 324; k += blockDim.x) wsm[k] = wt[k];

  int wg = blockIdx.x;
  int b = wg / (NTH * NTW);
  int tid2 = wg % (NTH * NTW);
  int ty = tid2 / NTW, tx = tid2 % NTW;
  int h_in0 = 2 * (ty * TH) - 1, w_in0 = 2 * (tx * TW) - 1;

  int tid = threadIdx.x;
  int o = 0, lph = 0, lpw = 0;
  if (tid < NACT) {
    o = tid / (TH * TW);
    int r = tid % (TH * TW);
    lph = r / TW; lpw = r % TW;
  }
  float m = mean[o], s = sg[o], be = beta[o];
  float v[4] = {0.0f, 0.0f, 0.0f, 0.0f};

  for (int t = 0; t < T; t++) {
    __syncthreads();
    const float* xb = in + (size_t)(t * B + b) * 6 * HW;
    for (int k = tid; k < 6 * TILE_N; k += blockDim.x) {
      int i = k / TILE_N;
      int r2 = k % TILE_N;
      int rr = r2 / IW, cc = r2 % IW;
      int hh = h_in0 + rr, ww = w_in0 + cc;
      float val = (hh >= 0 && hh < H && ww >= 0 && ww < W) ? xb[i * HW + hh * W + ww] : 0.0f;
      if (cc & 1) til_o[i][rr][cc >> 1] = val;
      else        til_e[i][rr][cc >> 1] = val;
    }
    __syncthreads();
    if (tid < NACT) {
      int ry = 2 * lph;
      float acc[4] = {0.0f, 0.0f, 0.0f, 0.0f};
#pragma unroll
      for (int i = 0; i < 6; i++) {
        float p[16];
#pragma unroll
        for (int r = 0; r < 4; r++) {
          p[r * 4 + 0] = til_e[i][ry + r][lpw];
          p[r * 4 + 1] = til_o[i][ry + r][lpw];
          p[r * 4 + 2] = til_e[i][ry + r][lpw + 1];
          p[r * 4 + 3] = til_o[i][ry + r][lpw + 1];
        }
        const float* wo = &wsm[(o * 6 + i) * 9];
#pragma unroll
        for (int dy = 0; dy < 2; dy++)
#pragma unroll
          for (int dx = 0; dx < 2; dx++) {
            float a = acc[dy * 2 + dx];
#pragma unroll
            for (int ky = 0; ky < 3; ky++)
#pragma unroll
              for (int kx = 0; kx < 3; kx++)
                a = fmaf(p[(dy + ky) * 4 + dx + kx], wo[ky * 3 + kx], a);
            acc[dy * 2 + dx] = a;
          }
      }
      float smax = 0.0f;
#pragma unroll
      for (int p4 = 0; p4 < 4; p4++) {
        float y = (acc[p4] - m) * s + be;
        float sp = lif_step(v[p4], y);
        smax = fmaxf(smax, sp);
      }
      out[((size_t)(t * B + b) * 6 + o) * (PH * PW) + (ty * TH + lph) * PW + (tx * TW + lpw)] = smax;
    }
  }
}

// ---- FC head ----
__global__ void fc1_mm(const float* __restrict__ p3, const float* __restrict__ fw1,
                       float* __restrict__ u1) {
  int idx = blockIdx.x * blockDim.x + threadIdx.x;
  if (idx >= T * B * 100) return;
  int o = idx % 100;
  int tb = idx / 100;
  const float4* x4 = (const float4*)(p3 + (size_t)tb * 1200);
  const float4* w4 = (const float4*)(fw1 + (size_t)o * 1200);
  float acc = 0.0f;
#pragma unroll 4
  for (int k = 0; k < 300; k++) {
    float4 a = x4[k], w = w4[k];
    acc = fmaf(a.x, w.x, acc);
    acc = fmaf(a.y, w.y, acc);
    acc = fmaf(a.z, w.z, acc);
    acc = fmaf(a.w, w.w, acc);
  }
  u1[idx] = acc;
}

__global__ void fc1_lif(const float* __restrict__ u1, float* __restrict__ s1) {
  int idx = blockIdx.x * blockDim.x + threadIdx.x;
  if (idx >= B * 100) return;
  float v = 0.0f;
  for (int t = 0; t < T; t++) {
    float sp = lif_step(v, u1[(size_t)t * B * 100 + idx]);
    s1[(size_t)t * B * 100 + idx] = sp;
  }
}

__global__ void fc2_fused(const float* __restrict__ s1, const float* __restrict__ fw2,
                          float* __restrict__ outp) {
  int idx = blockIdx.x * blockDim.x + threadIdx.x;
  if (idx >= B * 2) return;
  int b = idx >> 1, o = idx & 1;
  const float* wr = fw2 + o * 100;
  float v = 0.0f;
  for (int t = 0; t < T; t++) {
    const float* sr = s1 + (size_t)(t * B + b) * 100;
    float acc = 0.0f;
#pragma unroll
    for (int k = 0; k < 100; k++) acc = fmaf(sr[k], wr[k], acc);
    float sp = lif_step(v, acc);
    outp[(size_t)(t * B + b) * 2 + o] = sp;
  }
}

extern "C" void kernel_launch(void* const* d_in, const int* in_sizes, int n_in,
                              void* d_out, int out_size, void* d_ws, size_t ws_size,
                              hipStream_t stream) {
  const float* x   = (const float*)d_in[0];
  const float* w1  = (const float*)d_in[1];
  const float* g1  = (const float*)d_in[2];
  const float* b1  = (const float*)d_in[3];
  const float* w2  = (const float*)d_in[4];
  const float* g2  = (const float*)d_in[5];
  const float* b2  = (const float*)d_in[6];
  const float* w3  = (const float*)d_in[7];
  const float* g3  = (const float*)d_in[8];
  const float* b3  = (const float*)d_in[9];
  const float* fw1 = (const float*)d_in[10];
  const float* fw2 = (const float*)d_in[11];
  float* out = (float*)d_out;

  char* ws = (char*)d_ws;
  double* part1  = (double*)(ws + OFF_PART1);
  double* partf1 = (double*)(ws + OFF_PARTF1);
  double* partf2 = (double*)(ws + OFF_PARTF2);
  float* mean1 = (float*)(ws + OFF_STATS + 0);
  float* sg1   = (float*)(ws + OFF_STATS + 32);
  float* mean2 = (float*)(ws + OFF_STATS + 64);
  float* sg2   = (float*)(ws + OFF_STATS + 96);
  float* mean3 = (float*)(ws + OFF_STATS + 128);
  float* sg3   = (float*)(ws + OFF_STATS + 160);
  float* pool1 = (float*)(ws + OFF_POOL1);
  float* pool2 = (float*)(ws + OFF_POOL2);
  float* pool3 = (float*)(ws + OFF_POOL3);
  float* u1    = (float*)(ws + OFF_U1);
  float* s1    = (float*)(ws + OFF_S1);

  // Block 1 stats + finalize
  conv_stats_lds<1, H1, W1, 32, 100><<<NWG_S1, 256, 0, stream>>>(x, w1, part1);
  finalize_stats<<<1, 256, 0, stream>>>(part1, NWG_S1, (double)T * B * H1 * W1, g1, mean1, sg1);
  // fuse1 (+ stats for block2)
  fuse1_stats<<<NWG_F1, 256, 0, stream>>>(x, w1, w2, mean1, sg1, b1, pool1, partf1);
  finalize_stats<<<1, 256, 0, stream>>>(partf1, NWG_F1, (double)T * B * H2 * W2, g2, mean2, sg2);
  // fuse2 (+ stats for block3)
  fuse2_stats<<<NWG_F2, 256, 0, stream>>>(pool1, w2, w3, mean2, sg2, b2, pool2, partf2);
  finalize_stats<<<1, 256, 0, stream>>>(partf2, NWG_F2, (double)T * B * H3 * W3, g3, mean3, sg3);
  // Block 3 fuse
  {
    int nwg = B * (P3H / 4) * (P3W / 10);  // 160
    block6_fuse_lds<H3, W3, P3H, P3W, 4, 10><<<nwg, 256, 0, stream>>>(pool2, w3, mean3, sg3, b3, pool3);
  }
  // FC head
  {
    int n = T * B * 100;
    fc1_mm<<<(n + 255) / 256, 256, 0, stream>>>(pool3, fw1, u1);
  }
  {
    int n = B * 100;
    fc1_lif<<<(n + 255) / 256, 256, 0, stream>>>(u1, s1);
  }
  fc2_fused<<<1, 64, 0, stream>>>(s1, fw2, out);
}

// Round 13
// 525.482 us; speedup vs baseline: 1.8512x; 1.1314x over previous
//
#include <hip/hip_runtime.h>

// SNN forward: 3x (conv3x3 -> tdBN -> LIF -> maxpool2) + 2x (FC -> LIF)
// x [16,32,1,32,400] -> pool1 [16,32,6,16,200] -> pool2 [16,32,6,8,100]
//   -> pool3 [16,32,6,4,50] -> fc1 [16,32,100] -> out [16,32,2]
//
// Round-13: rebalance the non-fuse1 kernels (fuse1 is at its structural floor
// ~179us; total 594 = fuse1 + ~415 unprofiled). (a) fuse2 retiled own-2x5 ->
// own-4x5: conv phase 168->252 active threads, partial/reduce 60->120, halo
// waste 2.8x->2.1x, WGs 2560->1280. (b) block3 retiled 4x10->2x5 with 64-thr
// WGs: 160 -> 640 WGs (was leaving 96 CUs idle). (c) fc1_lif+fc2 merged into
// fc_tail (one less launch, s1 stays in LDS).

namespace {

constexpr int T = 16, B = 32;
constexpr int H1 = 32, W1 = 400, P1H = 16, P1W = 200;
constexpr int H2 = 16, W2 = 200, P2H = 8,  P2W = 100;
constexpr int H3 = 8,  W3 = 100, P3H = 4,  P3W = 50;

constexpr int NWG_S1 = T * B * (H1 / 32) * (W1 / 100);  // 2048
constexpr int NWG_F1 = B * (P1H / 2) * (P1W / 8);       // 6400
constexpr int NWG_F2 = B * (P2H / 4) * (P2W / 5);       // 1280

constexpr size_t OFF_PART1  = 0;
constexpr size_t OFF_PARTF1 = OFF_PART1 + (size_t)NWG_S1 * 12 * 8;
constexpr size_t OFF_PARTF2 = OFF_PARTF1 + (size_t)NWG_F1 * 12 * 8;
constexpr size_t OFF_STATS  = OFF_PARTF2 + (size_t)2560 * 12 * 8;  // slack
constexpr size_t OFF_POOL1  = 1310720;
constexpr size_t OFF_POOL2  = OFF_POOL1 + (size_t)T * B * 6 * P1H * P1W * 4;
constexpr size_t OFF_POOL3  = OFF_POOL2 + (size_t)T * B * 6 * P2H * P2W * 4;
constexpr size_t OFF_U1     = OFF_POOL3 + (size_t)T * B * 6 * P3H * P3W * 4;

} // namespace

// LDS-only phase barrier: waits own ds ops, does NOT drain vmcnt (prefetch
// loads stay in flight across it). "memory" clobber pins memory-op order.
#define LDS_PHASE_BARRIER()                                   \
  do {                                                        \
    asm volatile("s_waitcnt lgkmcnt(0)" ::: "memory");        \
    __builtin_amdgcn_s_barrier();                             \
    __builtin_amdgcn_sched_barrier(0);                        \
  } while (0)

__device__ __forceinline__ float lif_step(float& v, float y) {
  v = v + (y - v) * 0.5f;                 // tau=2, decay_input
  float sp = (v >= 1.0f) ? 1.0f : 0.0f;   // threshold 1.0
  v = (sp > 0.0f) ? 0.0f : v;             // hard reset
  return sp;
}

// Block reduction of per-thread 6+6 double counters (array form).
__device__ __forceinline__ void reduce12(double* s, double* q, double* partials) {
  __shared__ double lds[4][12];
  int lane = threadIdx.x & 63, wid = threadIdx.x >> 6;
#pragma unroll
  for (int k = 0; k < 12; k++) {
    double v = (k < 6) ? s[k] : q[k - 6];
#pragma unroll
    for (int off = 32; off >= 1; off >>= 1) v += __shfl_down(v, off, 64);
    if (lane == 0) lds[wid][k] = v;
  }
  __syncthreads();
  if (threadIdx.x < 12) {
    partials[(size_t)blockIdx.x * 12 + threadIdx.x] =
        lds[0][threadIdx.x] + lds[1][threadIdx.x] + lds[2][threadIdx.x] + lds[3][threadIdx.x];
  }
}

// Select form: thread contributes (s_acc,q_acc) only to counter `oidx` (<0: none).
__device__ __forceinline__ void reduce12_sel(int oidx, double s_acc, double q_acc,
                                             double* partials) {
  __shared__ double lds[4][12];
  int lane = threadIdx.x & 63, wid = threadIdx.x >> 6;
#pragma unroll
  for (int k = 0; k < 12; k++) {
    double v = (k == oidx) ? s_acc : ((k == oidx + 6) ? q_acc : 0.0);
#pragma unroll
    for (int off = 32; off >= 1; off >>= 1) v += __shfl_down(v, off, 64);
    if (lane == 0) lds[wid][k] = v;
  }
  __syncthreads();
  if (threadIdx.x < 12) {
    partials[(size_t)blockIdx.x * 12 + threadIdx.x] =
        lds[0][threadIdx.x] + lds[1][threadIdx.x] + lds[2][threadIdx.x] + lds[3][threadIdx.x];
  }
}

// ---- block1 stats: conv(1->6) over x, LDS-tiled (single-shot) ----
template <int NC, int H, int W, int TH, int TW>
__global__ void conv_stats_lds(const float* __restrict__ in, const float* __restrict__ wt,
                               double* __restrict__ partials) {
  constexpr int IH = TH + 2, IW = TW + 2;
  constexpr int IWP = (IW & 1) ? IW : IW + 1;  // odd row stride
  constexpr int NW = NC * 54;
  constexpr int NTH = H / TH, NTW = W / TW;
  constexpr int NT = NTH * NTW;
  __shared__ float wsm[NW];
  __shared__ float tile[NC][IH][IWP];

  int tid = threadIdx.x;
  for (int k = tid; k < NW; k += blockDim.x) wsm[k] = wt[k];

  int wg = blockIdx.x;
  int tb = wg / NT;
  int ti = wg % NT;
  int ty = ti / NTW, tx = ti % NTW;
  int h0 = ty * TH - 1, w0 = tx * TW - 1;
  const float* xb = in + (size_t)tb * NC * H * W;

  for (int k = tid; k < NC * IH * IW; k += blockDim.x) {
    int i = k / (IH * IW);
    int r = k % (IH * IW);
    int rr = r / IW, cc = r % IW;
    int hh = h0 + rr, ww = w0 + cc;
    tile[i][rr][cc] = (hh >= 0 && hh < H && ww >= 0 && ww < W) ? xb[i * H * W + hh * W + ww] : 0.0f;
  }
  __syncthreads();

  double s[6] = {0, 0, 0, 0, 0, 0}, q[6] = {0, 0, 0, 0, 0, 0};
  for (int pos = tid; pos < TH * TW; pos += blockDim.x) {
    int ly = pos / TW, lx = pos % TW;
    float acc[6] = {0, 0, 0, 0, 0, 0};
#pragma unroll
    for (int i = 0; i < NC; i++) {
      float p[9];
#pragma unroll
      for (int ky = 0; ky < 3; ky++)
#pragma unroll
        for (int kx = 0; kx < 3; kx++) p[ky * 3 + kx] = tile[i][ly + ky][lx + kx];
#pragma unroll
      for (int o = 0; o < 6; o++) {
        float a = acc[o];
#pragma unroll
        for (int k2 = 0; k2 < 9; k2++) a = fmaf(p[k2], wsm[(o * NC + i) * 9 + k2], a);
        acc[o] = a;
      }
    }
#pragma unroll
    for (int o = 0; o < 6; o++) {
      s[o] += (double)acc[o];
      q[o] += (double)acc[o] * (double)acc[o];
    }
  }
  reduce12(s, q, partials);
}

// ---- finalize: partials -> mean[6], sg[6] ----
__global__ void finalize_stats(const double* __restrict__ partials, int nb, double n,
                               const float* __restrict__ gamma,
                               float* __restrict__ mean_out, float* __restrict__ sg_out) {
  __shared__ double lds[12][21];
  __shared__ double sums[12];
  int t = threadIdx.x;
  int k = t % 12, j = t / 12;
  if (t < 252) {
    double acc = 0.0;
    for (int b = j; b < nb; b += 21) acc += partials[(size_t)b * 12 + k];
    lds[k][j] = acc;
  }
  __syncthreads();
  if (t < 12) {
    double acc = 0.0;
#pragma unroll
    for (int j2 = 0; j2 < 21; j2++) acc += lds[t][j2];
    sums[t] = acc;
  }
  __syncthreads();
  if (t < 6) {
    double mean = sums[t] / n;
    double var = sums[t + 6] / n - mean * mean;
    double invstd = 1.0 / sqrt(var + 1e-5);
    mean_out[t] = (float)mean;
    sg_out[t] = (float)(invstd * (double)gamma[t]);
  }
}

// ---- fuse1 + stats2 (unchanged from round 12) ----
__global__ void fuse1_stats(const float* __restrict__ x, const float* __restrict__ w1g,
                            const float* __restrict__ w2g,
                            const float* __restrict__ mean1, const float* __restrict__ sg1,
                            const float* __restrict__ beta1,
                            float* __restrict__ pool1, double* __restrict__ partials2) {
  __shared__ float wsm1[54];
  __shared__ float wsm2[324];
  __shared__ float til[2][10][11];
  __shared__ float phl[6][4][10];
  __shared__ float pr[16][6][7];  // [pos][i][o]

  int tid = threadIdx.x;
  for (int k = tid; k < 54; k += 256) wsm1[k] = w1g[k];
  for (int k = tid; k < 324; k += 256) wsm2[k] = w2g[k];

  int wg = blockIdx.x;
  int b = wg / 200;
  int rem = wg % 200;
  int oy = rem / 25, ox = rem % 25;
  int iy0 = 4 * oy - 3, ix0 = 16 * ox - 3;

  bool sactive = tid < 220;
  int srr = tid / 22, scc = tid % 22;
  int shh = iy0 + srr, sww = ix0 + scc;
  bool s_in = sactive && shh >= 0 && shh < H1 && sww >= 0 && sww < W1;
  int s_off = shh * W1 + sww;
  int lofs = (scc & 1) * 110 + srr * 11 + (scc >> 1);
  float* tilf = &til[0][0][0];

  bool active = tid < 240;
  int ch = 0, hy = 0, hx = 0, py = 0, px = 0;
  bool pvalid = false, own = false;
  if (active) {
    ch = tid / 40;
    int r = tid % 40;
    hy = r / 10; hx = r % 10;
    py = 2 * oy - 1 + hy; px = 8 * ox - 1 + hx;
    pvalid = (py >= 0 && py < P1H && px >= 0 && px < P1W);
    own = (hy >= 1 && hy <= 2 && hx >= 1 && hx <= 8);
  }
  float wv[9];
#pragma unroll
  for (int k = 0; k < 9; k++) wv[k] = active ? wsm1[ch * 9 + k] : 0.0f;
  float m = active ? mean1[ch] : 0.0f;
  float sc = active ? sg1[ch] : 0.0f;
  float be = active ? beta1[ch] : 0.0f;

  int oidx = (tid < 96) ? (tid / 16) : -1;
  int pos16 = tid & 15;
  int i2 = tid / 16;
  int psy = (pos16 >> 3), psx = pos16 & 7;

  float v[4] = {0.0f, 0.0f, 0.0f, 0.0f};
  double s_acc = 0.0, q_acc = 0.0;

  float rstage = 0.0f;
  if (s_in) rstage = x[(size_t)(0 * B + b) * (H1 * W1) + s_off];

  for (int t = 0; t < T; t++) {
    __syncthreads();
    if (sactive) tilf[lofs] = rstage;
    if (t + 1 < T && s_in)
      rstage = x[(size_t)((t + 1) * B + b) * (H1 * W1) + s_off];
    LDS_PHASE_BARRIER();
    if (active) {
      float smax = 0.0f;
      if (pvalid) {
        int ry = 2 * hy;
        float p[16];
#pragma unroll
        for (int r = 0; r < 4; r++) {
          p[r * 4 + 0] = til[0][ry + r][hx];
          p[r * 4 + 1] = til[1][ry + r][hx];
          p[r * 4 + 2] = til[0][ry + r][hx + 1];
          p[r * 4 + 3] = til[1][ry + r][hx + 1];
        }
#pragma unroll
        for (int dy = 0; dy < 2; dy++) {
#pragma unroll
          for (int dx = 0; dx < 2; dx++) {
            float acc = 0.0f;
#pragma unroll
            for (int ky = 0; ky < 3; ky++)
#pragma unroll
              for (int kx = 0; kx < 3; kx++)
                acc = fmaf(p[(dy + ky) * 4 + dx + kx], wv[ky * 3 + kx], acc);
            float y = (acc - m) * sc + be;
            float sp = lif_step(v[dy * 2 + dx], y);
            smax = fmaxf(smax, sp);
          }
        }
      }
      phl[ch][hy][hx] = smax;
      if (own)
        pool1[((size_t)(t * B + b) * 6 + ch) * (P1H * P1W) + py * P1W + px] = smax;
    }
    LDS_PHASE_BARRIER();
    if (tid < 96) {
      float pt[9];
#pragma unroll
      for (int ky = 0; ky < 3; ky++)
#pragma unroll
        for (int kx = 0; kx < 3; kx++)
          pt[ky * 3 + kx] = phl[i2][psy + ky][psx + kx];
      float p6[6];
#pragma unroll
      for (int o = 0; o < 6; o++) {
        float a = 0.0f;
#pragma unroll
        for (int k2 = 0; k2 < 9; k2++) a = fmaf(pt[k2], wsm2[(o * 6 + i2) * 9 + k2], a);
        p6[o] = a;
      }
#pragma unroll
      for (int o = 0; o < 6; o++) pr[pos16][i2][o] = p6[o];
    }
    LDS_PHASE_BARRIER();
    if (oidx >= 0) {
      double acc = 0.0;
#pragma unroll
      for (int ic = 0; ic < 6; ic++) acc += (double)pr[pos16][ic][oidx];
      s_acc += acc;
      q_acc += acc * acc;
    }
  }
  __syncthreads();
  reduce12_sel(oidx, s_acc, q_acc, partials2);
}

// ---- fuse2 + stats3: own 4x5 pooled, halo 6x7 (252 conv threads) ----
// Raw tile 14x16 x6ch, parity-major til[2][6][14][9]. WG: (b, oy 0..1, ox 0..19).
__global__ void fuse2_stats(const float* __restrict__ in, const float* __restrict__ w2g,
                            const float* __restrict__ w3g,
                            const float* __restrict__ mean2, const float* __restrict__ sg2,
                            const float* __restrict__ beta2,
                            float* __restrict__ pool2, double* __restrict__ partials3) {
  __shared__ float wsm2[324];
  __shared__ float wsm3[324];
  __shared__ float til[2][6][14][9];
  __shared__ float phl[6][6][7];
  __shared__ float pr[20][6][7];  // [pos][i][o]

  int tid = threadIdx.x;
  for (int k = tid; k < 324; k += 256) { wsm2[k] = w2g[k]; wsm3[k] = w3g[k]; }

  int wg = blockIdx.x;
  int b = wg / 40;
  int rem = wg % 40;
  int oy = rem / 20, ox = rem % 20;
  int iy0 = 8 * oy - 3, ix0 = 10 * ox - 3;
  constexpr int HW = H2 * W2;

  // staging: 6ch x 14 x 16 = 1344 raw elems, 6 slots/thread
  bool s_in[6];
  int s_off[6], s_lofs[6];
#pragma unroll
  for (int j = 0; j < 6; j++) {
    int k = tid + 256 * j;
    bool valid = k < 1344;
    int i = k / 224;
    int r2 = k % 224;
    int rr = r2 / 16, cc = r2 % 16;
    int hh = iy0 + rr, ww = ix0 + cc;
    s_in[j] = valid && hh >= 0 && hh < H2 && ww >= 0 && ww < W2;
    s_off[j] = i * HW + hh * W2 + ww;
    s_lofs[j] = valid ? ((cc & 1) * 756 + i * 126 + rr * 9 + (cc >> 1)) : -1;
  }
  float* tilf = &til[0][0][0][0];

  bool active = tid < 252;
  int ch = 0, hy = 0, hx = 0, py = 0, px = 0;
  bool pvalid = false, own = false;
  if (active) {
    ch = tid / 42;
    int r = tid % 42;
    hy = r / 7; hx = r % 7;
    py = 4 * oy - 1 + hy; px = 5 * ox - 1 + hx;
    pvalid = (py >= 0 && py < P2H && px >= 0 && px < P2W);
    own = (hy >= 1 && hy <= 4 && hx >= 1 && hx <= 5);
  }
  float m = active ? mean2[ch] : 0.0f;
  float sc = active ? sg2[ch] : 0.0f;
  float be = active ? beta2[ch] : 0.0f;

  int oidx = (tid < 120) ? (tid / 20) : -1;  // out-ch (reduce) / in-ch (partial)
  int pos = tid % 20;
  int psy = pos / 5, psx = pos % 5;

  float v[4] = {0.0f, 0.0f, 0.0f, 0.0f};
  double s_acc = 0.0, q_acc = 0.0;

  // prologue: prefetch t=0
  float rs[6] = {0.0f, 0.0f, 0.0f, 0.0f, 0.0f, 0.0f};
  {
    const float* xb = in + (size_t)(0 * B + b) * 6 * HW;
#pragma unroll
    for (int j = 0; j < 6; j++)
      if (s_in[j]) rs[j] = xb[s_off[j]];
  }

  for (int t = 0; t < T; t++) {
    __syncthreads();  // full drain
#pragma unroll
    for (int j = 0; j < 6; j++)
      if (s_lofs[j] >= 0) tilf[s_lofs[j]] = rs[j];
    if (t + 1 < T) {
      const float* xb = in + (size_t)((t + 1) * B + b) * 6 * HW;
#pragma unroll
      for (int j = 0; j < 6; j++)
        if (s_in[j]) rs[j] = xb[s_off[j]];
    }
    LDS_PHASE_BARRIER();  // tile ready; prefetch NOT drained
    if (active) {
      float smax = 0.0f;
      if (pvalid) {
        int ry = 2 * hy;
        float acc4[4] = {0.0f, 0.0f, 0.0f, 0.0f};
#pragma unroll
        for (int i = 0; i < 6; i++) {
          float p[16];
#pragma unroll
          for (int r = 0; r < 4; r++) {
            p[r * 4 + 0] = til[0][i][ry + r][hx];
            p[r * 4 + 1] = til[1][i][ry + r][hx];
            p[r * 4 + 2] = til[0][i][ry + r][hx + 1];
            p[r * 4 + 3] = til[1][i][ry + r][hx + 1];
          }
          const float* wo = &wsm2[(ch * 6 + i) * 9];
#pragma unroll
          for (int dy = 0; dy < 2; dy++)
#pragma unroll
            for (int dx = 0; dx < 2; dx++) {
              float a = acc4[dy * 2 + dx];
#pragma unroll
              for (int ky = 0; ky < 3; ky++)
#pragma unroll
                for (int kx = 0; kx < 3; kx++)
                  a = fmaf(p[(dy + ky) * 4 + dx + kx], wo[ky * 3 + kx], a);
              acc4[dy * 2 + dx] = a;
            }
        }
#pragma unroll
        for (int p4 = 0; p4 < 4; p4++) {
          float y = (acc4[p4] - m) * sc + be;
          float sp = lif_step(v[p4], y);
          smax = fmaxf(smax, sp);
        }
      }
      phl[ch][hy][hx] = smax;
      if (own)
        pool2[((size_t)(t * B + b) * 6 + ch) * (P2H * P2W) + py * P2W + px] = smax;
    }
    LDS_PHASE_BARRIER();  // phl ready
    if (oidx >= 0) {  // partial: input ch oidx, own pos (psy,psx)
      float pt[9];
#pragma unroll
      for (int ky = 0; ky < 3; ky++)
#pragma unroll
        for (int kx = 0; kx < 3; kx++)
          pt[ky * 3 + kx] = phl[oidx][psy + ky][psx + kx];
      float p6[6];
#pragma unroll
      for (int o = 0; o < 6; o++) {
        float a = 0.0f;
#pragma unroll
        for (int k2 = 0; k2 < 9; k2++) a = fmaf(pt[k2], wsm3[(o * 6 + oidx) * 9 + k2], a);
        p6[o] = a;
      }
#pragma unroll
      for (int o = 0; o < 6; o++) pr[pos][oidx][o] = p6[o];
    }
    LDS_PHASE_BARRIER();  // pr ready
    if (oidx >= 0) {
      double acc = 0.0;
#pragma unroll
      for (int ic = 0; ic < 6; ic++) acc += (double)pr[pos][ic][oidx];
      s_acc += acc;
      q_acc += acc * acc;
    }
  }
  __syncthreads();
  reduce12_sel(oidx, s_acc, q_acc, partials3);
}

// ---- block 3 fuse: conv(6->6)+BN+LIF+pool, parity-split LDS tiles ----
template <int H, int W, int PH, int PW, int TH, int TW>
__global__ void block6_fuse_lds(const float* __restrict__ in, const float* __restrict__ wt,
                                const float* __restrict__ mean, const float* __restrict__ sg,
                                const float* __restrict__ beta, float* __restrict__ out) {
  constexpr int NTH = PH / TH, NTW = PW / TW;
  constexpr int IH = 2 * TH + 2, IW = 2 * TW + 2;
  constexpr int EW = IW / 2;
  constexpr int TILE_N = IH * IW;
  constexpr int NACT = 6 * TH * TW;
  constexpr int HW = H * W;
  __shared__ float wsm[324];
  __shared__ float til_e[6][IH][EW];
  __shared__ float til_o[6][IH][EW];

  for (int k = threadIdx.x; k < 324; k += blockDim.x) wsm[k] = wt[k];

  int wg = blockIdx.x;
  int b = wg / (NTH * NTW);
  int tid2 = wg % (NTH * NTW);
  int ty = tid2 / NTW, tx = tid2 % NTW;
  int h_in0 = 2 * (ty * TH) - 1, w_in0 = 2 * (tx * TW) - 1;

  int tid = threadIdx.x;
  int o = 0, lph = 0, lpw = 0;
  if (tid < NACT) {
    o = tid / (TH * TW);
    int r = tid % (TH * TW);
    lph = r / TW; lpw = r % TW;
  }
  float m = mean[o], s = sg[o], be = beta[o];
  float v[4] = {0.0f, 0.0f, 0.0f, 0.0f};

  for (int t = 0; t < T; t++) {
    __syncthreads();
    const float* xb = in + (size_t)(t * B + b) * 6 * HW;
    for (int k = tid; k < 6 * TILE_N; k += blockDim.x) {
      int i = k / TILE_N;
      int r2 = k % TILE_N;
      int rr = r2 / IW, cc = r2 % IW;
      int hh = h_in0 + rr, ww = w_in0 + cc;
      float val = (hh >= 0 && hh < H && ww >= 0 && ww < W) ? xb[i * HW + hh * W + ww] : 0.0f;
      if (cc & 1) til_o[i][rr][cc >> 1] = val;
      else        til_e[i][rr][cc >> 1] = val;
    }
    __syncthreads();
    if (tid < NACT) {
      int ry = 2 * lph;
      float acc[4] = {0.0f, 0.0f, 0.0f, 0.0f};
#pragma unroll
      for (int i = 0; i < 6; i++) {
        float p[16];
#pragma unroll
        for (int r = 0; r < 4; r++) {
          p[r * 4 + 0] = til_e[i][ry + r][lpw];
          p[r * 4 + 1] = til_o[i][ry + r][lpw];
          p[r * 4 + 2] = til_e[i][ry + r][lpw + 1];
          p[r * 4 + 3] = til_o[i][ry + r][lpw + 1];
        }
        const float* wo = &wsm[(o * 6 + i) * 9];
#pragma unroll
        for (int dy = 0; dy < 2; dy++)
#pragma unroll
          for (int dx = 0; dx < 2; dx++) {
            float a = acc[dy * 2 + dx];
#pragma unroll
            for (int ky = 0; ky < 3; ky++)
#pragma unroll
              for (int kx = 0; kx < 3; kx++)
                a = fmaf(p[(dy + ky) * 4 + dx + kx], wo[ky * 3 + kx], a);
            acc[dy * 2 + dx] = a;
          }
      }
      float smax = 0.0f;
#pragma unroll
      for (int p4 = 0; p4 < 4; p4++) {
        float y = (acc[p4] - m) * s + be;
        float sp = lif_step(v[p4], y);
        smax = fmaxf(smax, sp);
      }
      out[((size_t)(t * B + b) * 6 + o) * (PH * PW) + (ty * TH + lph) * PW + (tx * TW + lpw)] = smax;
    }
  }
}

// ---- FC1 matmul ----
__global__ void fc1_mm(const float* __restrict__ p3, const float* __restrict__ fw1,
                       float* __restrict__ u1) {
  int idx = blockIdx.x * blockDim.x + threadIdx.x;
  if (idx >= T * B * 100) return;
  int o = idx % 100;
  int tb = idx / 100;
  const float4* x4 = (const float4*)(p3 + (size_t)tb * 1200);
  const float4* w4 = (const float4*)(fw1 + (size_t)o * 1200);
  float acc = 0.0f;
#pragma unroll 4
  for (int k = 0; k < 300; k++) {
    float4 a = x4[k], w = w4[k];
    acc = fmaf(a.x, w.x, acc);
    acc = fmaf(a.y, w.y, acc);
    acc = fmaf(a.z, w.z, acc);
    acc = fmaf(a.w, w.w, acc);
  }
  u1[idx] = acc;
}

// ---- fc tail: fc1-LIF + fc2 + fc2-LIF, one WG per batch ----
__global__ void fc_tail(const float* __restrict__ u1, const float* __restrict__ fw2,
                        float* __restrict__ outp) {
  __shared__ float s1[100];
  __shared__ float w2s[200];
  int b = blockIdx.x;
  int tid = threadIdx.x;
  for (int k = tid; k < 200; k += 128) w2s[k] = fw2[k];
  float v1 = 0.0f, v2 = 0.0f;
  __syncthreads();
  for (int t = 0; t < T; t++) {
    if (tid < 100) {
      float sp = lif_step(v1, u1[(size_t)(t * B + b) * 100 + tid]);
      s1[tid] = sp;
    }
    __syncthreads();
    if (tid < 2) {
      const float* wr = &w2s[tid * 100];
      float acc = 0.0f;
#pragma unroll
      for (int k = 0; k < 100; k++) acc = fmaf(s1[k], wr[k], acc);
      float sp = lif_step(v2, acc);
      outp[(size_t)(t * B + b) * 2 + tid] = sp;
    }
    __syncthreads();
  }
}

extern "C" void kernel_launch(void* const* d_in, const int* in_sizes, int n_in,
                              void* d_out, int out_size, void* d_ws, size_t ws_size,
                              hipStream_t stream) {
  const float* x   = (const float*)d_in[0];
  const float* w1  = (const float*)d_in[1];
  const float* g1  = (const float*)d_in[2];
  const float* b1  = (const float*)d_in[3];
  const float* w2  = (const float*)d_in[4];
  const float* g2  = (const float*)d_in[5];
  const float* b2  = (const float*)d_in[6];
  const float* w3  = (const float*)d_in[7];
  const float* g3  = (const float*)d_in[8];
  const float* b3  = (const float*)d_in[9];
  const float* fw1 = (const float*)d_in[10];
  const float* fw2 = (const float*)d_in[11];
  float* out = (float*)d_out;

  char* ws = (char*)d_ws;
  double* part1  = (double*)(ws + OFF_PART1);
  double* partf1 = (double*)(ws + OFF_PARTF1);
  double* partf2 = (double*)(ws + OFF_PARTF2);
  float* mean1 = (float*)(ws + OFF_STATS + 0);
  float* sg1   = (float*)(ws + OFF_STATS + 32);
  float* mean2 = (float*)(ws + OFF_STATS + 64);
  float* sg2   = (float*)(ws + OFF_STATS + 96);
  float* mean3 = (float*)(ws + OFF_STATS + 128);
  float* sg3   = (float*)(ws + OFF_STATS + 160);
  float* pool1 = (float*)(ws + OFF_POOL1);
  float* pool2 = (float*)(ws + OFF_POOL2);
  float* pool3 = (float*)(ws + OFF_POOL3);
  float* u1    = (float*)(ws + OFF_U1);

  // Block 1 stats + finalize
  conv_stats_lds<1, H1, W1, 32, 100><<<NWG_S1, 256, 0, stream>>>(x, w1, part1);
  finalize_stats<<<1, 256, 0, stream>>>(part1, NWG_S1, (double)T * B * H1 * W1, g1, mean1, sg1);
  // fuse1 (+ stats for block2)
  fuse1_stats<<<NWG_F1, 256, 0, stream>>>(x, w1, w2, mean1, sg1, b1, pool1, partf1);
  finalize_stats<<<1, 256, 0, stream>>>(partf1, NWG_F1, (double)T * B * H2 * W2, g2, mean2, sg2);
  // fuse2 (+ stats for block3)
  fuse2_stats<<<NWG_F2, 256, 0, stream>>>(pool1, w2, w3, mean2, sg2, b2, pool2, partf2);
  finalize_stats<<<1, 256, 0, stream>>>(partf2, NWG_F2, (double)T * B * H3 * W3, g3, mean3, sg3);
  // Block 3 fuse: own 2x5 tiles, 64-thread WGs -> 640 WGs across all CUs
  {
    int nwg = B * (P3H / 2) * (P3W / 5);  // 640
    block6_fuse_lds<H3, W3, P3H, P3W, 2, 5><<<nwg, 64, 0, stream>>>(pool2, w3, mean3, sg3, b3, pool3);
  }
  // FC head
  {
    int n = T * B * 100;
    fc1_mm<<<(n + 255) / 256, 256, 0, stream>>>(pool3, fw1, u1);
  }
  fc_tail<<<B, 128, 0, stream>>>(u1, fw2, out);
}

// Round 15
// 432.981 us; speedup vs baseline: 2.2467x; 1.2136x over previous
//
#include <hip/hip_runtime.h>

// SNN forward: 3x (conv3x3 -> tdBN -> LIF -> maxpool2) + 2x (FC -> LIF)
// x [16,32,1,32,400] -> pool1 [16,32,6,16,200] -> pool2 [16,32,6,8,100]
//   -> pool3 [16,32,6,4,50] -> fc1 [16,32,100] -> out [16,32,2]
//
// Round-14 (resubmit): fuse1 retile own-2x8 -> own-4x10 (halo 6x12). Halo
// recompute waste 2.5x -> 1.8x (conv lane-ops -28%), WGs 6400 -> 2560
// (barrier count -60%), staging -34%, partial/reduce phases 96 -> 240 active.
// Conv/pool FMA order per position unchanged -> bit-identical output path.

namespace {

constexpr int T = 16, B = 32;
constexpr int H1 = 32, W1 = 400, P1H = 16, P1W = 200;
constexpr int H2 = 16, W2 = 200, P2H = 8,  P2W = 100;
constexpr int H3 = 8,  W3 = 100, P3H = 4,  P3W = 50;

constexpr int NWG_S1 = T * B * (H1 / 32) * (W1 / 100);  // 2048
constexpr int NWG_F1 = B * (P1H / 4) * (P1W / 10);      // 2560
constexpr int NWG_F2 = B * (P2H / 4) * (P2W / 5);       // 1280

constexpr size_t OFF_PART1  = 0;
constexpr size_t OFF_PARTF1 = OFF_PART1 + (size_t)NWG_S1 * 12 * 8;
constexpr size_t OFF_PARTF2 = OFF_PARTF1 + (size_t)6400 * 12 * 8;  // slack
constexpr size_t OFF_STATS  = OFF_PARTF2 + (size_t)2560 * 12 * 8;
constexpr size_t OFF_POOL1  = 1310720;
constexpr size_t OFF_POOL2  = OFF_POOL1 + (size_t)T * B * 6 * P1H * P1W * 4;
constexpr size_t OFF_POOL3  = OFF_POOL2 + (size_t)T * B * 6 * P2H * P2W * 4;
constexpr size_t OFF_U1     = OFF_POOL3 + (size_t)T * B * 6 * P3H * P3W * 4;

} // namespace

// LDS-only phase barrier: waits own ds ops, does NOT drain vmcnt (prefetch
// loads stay in flight across it).
#define LDS_PHASE_BARRIER()                                   \
  do {                                                        \
    asm volatile("s_waitcnt lgkmcnt(0)" ::: "memory");        \
    __builtin_amdgcn_s_barrier();                             \
    __builtin_amdgcn_sched_barrier(0);                        \
  } while (0)

__device__ __forceinline__ float lif_step(float& v, float y) {
  v = v + (y - v) * 0.5f;                 // tau=2, decay_input
  float sp = (v >= 1.0f) ? 1.0f : 0.0f;   // threshold 1.0
  v = (sp > 0.0f) ? 0.0f : v;             // hard reset
  return sp;
}

// Block reduction of per-thread 6+6 double counters (array form).
__device__ __forceinline__ void reduce12(double* s, double* q, double* partials) {
  __shared__ double lds[4][12];
  int lane = threadIdx.x & 63, wid = threadIdx.x >> 6;
#pragma unroll
  for (int k = 0; k < 12; k++) {
    double v = (k < 6) ? s[k] : q[k - 6];
#pragma unroll
    for (int off = 32; off >= 1; off >>= 1) v += __shfl_down(v, off, 64);
    if (lane == 0) lds[wid][k] = v;
  }
  __syncthreads();
  if (threadIdx.x < 12) {
    partials[(size_t)blockIdx.x * 12 + threadIdx.x] =
        lds[0][threadIdx.x] + lds[1][threadIdx.x] + lds[2][threadIdx.x] + lds[3][threadIdx.x];
  }
}

// Select form: thread contributes (s_acc,q_acc) only to counter `oidx` (<0: none).
__device__ __forceinline__ void reduce12_sel(int oidx, double s_acc, double q_acc,
                                             double* partials) {
  __shared__ double lds[4][12];
  int lane = threadIdx.x & 63, wid = threadIdx.x >> 6;
#pragma unroll
  for (int k = 0; k < 12; k++) {
    double v = (k == oidx) ? s_acc : ((k == oidx + 6) ? q_acc : 0.0);
#pragma unroll
    for (int off = 32; off >= 1; off >>= 1) v += __shfl_down(v, off, 64);
    if (lane == 0) lds[wid][k] = v;
  }
  __syncthreads();
  if (threadIdx.x < 12) {
    partials[(size_t)blockIdx.x * 12 + threadIdx.x] =
        lds[0][threadIdx.x] + lds[1][threadIdx.x] + lds[2][threadIdx.x] + lds[3][threadIdx.x];
  }
}

// ---- block1 stats: conv(1->6) over x, LDS-tiled (single-shot) ----
template <int NC, int H, int W, int TH, int TW>
__global__ void conv_stats_lds(const float* __restrict__ in, const float* __restrict__ wt,
                               double* __restrict__ partials) {
  constexpr int IH = TH + 2, IW = TW + 2;
  constexpr int IWP = (IW & 1) ? IW : IW + 1;  // odd row stride
  constexpr int NW = NC * 54;
  constexpr int NTH = H / TH, NTW = W / TW;
  constexpr int NT = NTH * NTW;
  __shared__ float wsm[NW];
  __shared__ float tile[NC][IH][IWP];

  int tid = threadIdx.x;
  for (int k = tid; k < NW; k += blockDim.x) wsm[k] = wt[k];

  int wg = blockIdx.x;
  int tb = wg / NT;
  int ti = wg % NT;
  int ty = ti / NTW, tx = ti % NTW;
  int h0 = ty * TH - 1, w0 = tx * TW - 1;
  const float* xb = in + (size_t)tb * NC * H * W;

  for (int k = tid; k < NC * IH * IW; k += blockDim.x) {
    int i = k / (IH * IW);
    int r = k % (IH * IW);
    int rr = r / IW, cc = r % IW;
    int hh = h0 + rr, ww = w0 + cc;
    tile[i][rr][cc] = (hh >= 0 && hh < H && ww >= 0 && ww < W) ? xb[i * H * W + hh * W + ww] : 0.0f;
  }
  __syncthreads();

  double s[6] = {0, 0, 0, 0, 0, 0}, q[6] = {0, 0, 0, 0, 0, 0};
  for (int pos = tid; pos < TH * TW; pos += blockDim.x) {
    int ly = pos / TW, lx = pos % TW;
    float acc[6] = {0, 0, 0, 0, 0, 0};
#pragma unroll
    for (int i = 0; i < NC; i++) {
      float p[9];
#pragma unroll
      for (int ky = 0; ky < 3; ky++)
#pragma unroll
        for (int kx = 0; kx < 3; kx++) p[ky * 3 + kx] = tile[i][ly + ky][lx + kx];
#pragma unroll
      for (int o = 0; o < 6; o++) {
        float a = acc[o];
#pragma unroll
        for (int k2 = 0; k2 < 9; k2++) a = fmaf(p[k2], wsm[(o * NC + i) * 9 + k2], a);
        acc[o] = a;
      }
    }
#pragma unroll
    for (int o = 0; o < 6; o++) {
      s[o] += (double)acc[o];
      q[o] += (double)acc[o] * (double)acc[o];
    }
  }
  reduce12(s, q, partials);
}

// ---- finalize: partials -> mean[6], sg[6] ----
__global__ void finalize_stats(const double* __restrict__ partials, int nb, double n,
                               const float* __restrict__ gamma,
                               float* __restrict__ mean_out, float* __restrict__ sg_out) {
  __shared__ double lds[12][21];
  __shared__ double sums[12];
  int t = threadIdx.x;
  int k = t % 12, j = t / 12;
  if (t < 252) {
    double acc = 0.0;
    for (int b = j; b < nb; b += 21) acc += partials[(size_t)b * 12 + k];
    lds[k][j] = acc;
  }
  __syncthreads();
  if (t < 12) {
    double acc = 0.0;
#pragma unroll
    for (int j2 = 0; j2 < 21; j2++) acc += lds[t][j2];
    sums[t] = acc;
  }
  __syncthreads();
  if (t < 6) {
    double mean = sums[t] / n;
    double var = sums[t + 6] / n - mean * mean;
    double invstd = 1.0 / sqrt(var + 1e-5);
    mean_out[t] = (float)mean;
    sg_out[t] = (float)(invstd * (double)gamma[t]);
  }
}

// ---- fuse1 + stats2: own 4x10 pooled, halo 6x12 (432 positions, 2/thread) ----
// Input tile 14x26, parity-major til[2][14][13]. WG: (b, oy 0..3, ox 0..19).
__global__ void fuse1_stats(const float* __restrict__ x, const float* __restrict__ w1g,
                            const float* __restrict__ w2g,
                            const float* __restrict__ mean1, const float* __restrict__ sg1,
                            const float* __restrict__ beta1,
                            float* __restrict__ pool1, double* __restrict__ partials2) {
  __shared__ float wsm1[54];
  __shared__ float wsm2[324];
  __shared__ float til[2][14][13];
  __shared__ float phl[432];      // [ch][hy][hx] flat = ch*72 + hy*12 + hx
  __shared__ float pr[40][7][7];  // [pos][i][o], pos stride 49 (odd)

  int tid = threadIdx.x;
  for (int k = tid; k < 54; k += 256) wsm1[k] = w1g[k];
  for (int k = tid; k < 324; k += 256) wsm2[k] = w2g[k];

  int wg = blockIdx.x;
  int b = wg / 80;
  int rem = wg % 80;
  int oy = rem / 20, ox = rem % 20;
  int iy0 = 8 * oy - 3, ix0 = 20 * ox - 3;  // input tile origin (14x26)

  // staging geometry (t-invariant): 364 raw elems, 2 slots/thread
  bool s_in[2];
  int s_off[2], s_lofs[2];
#pragma unroll
  for (int j = 0; j < 2; j++) {
    int k = tid + 256 * j;
    bool valid = k < 364;
    int srr = k / 26, scc = k % 26;
    int shh = iy0 + srr, sww = ix0 + scc;
    s_in[j] = valid && shh >= 0 && shh < H1 && sww >= 0 && sww < W1;
    s_off[j] = shh * W1 + sww;
    s_lofs[j] = valid ? ((scc & 1) * 182 + srr * 13 + (scc >> 1)) : -1;
  }
  float* tilf = &til[0][0][0];

  // halo-conv geometry: 2 slots, pos = tid + 256*sl < 432
  int hch[2], hhy[2], hhx[2], hpy[2], hpx[2];
  bool hact[2], hval[2], hown[2];
  float m_[2], sc_[2], be_[2];
  float wv[2][9];
#pragma unroll
  for (int sl = 0; sl < 2; sl++) {
    int pos = tid + 256 * sl;
    hact[sl] = pos < 432;
    int p2 = hact[sl] ? pos : 0;
    int ch = p2 / 72;
    int r = p2 % 72;
    int hy = r / 12, hx = r % 12;
    hch[sl] = ch; hhy[sl] = hy; hhx[sl] = hx;
    int py = 4 * oy - 1 + hy, px = 10 * ox - 1 + hx;
    hpy[sl] = py; hpx[sl] = px;
    hval[sl] = hact[sl] && py >= 0 && py < P1H && px >= 0 && px < P1W;
    hown[sl] = hact[sl] && hy >= 1 && hy <= 4 && hx >= 1 && hx <= 10;
#pragma unroll
    for (int k = 0; k < 9; k++) wv[sl][k] = w1g[ch * 9 + k];
    m_[sl] = mean1[ch]; sc_[sl] = sg1[ch]; be_[sl] = beta1[ch];
  }

  // stats phases: 240 threads. partial: in-ch i2 = tid/40, pos40 = tid%40.
  // reduce: out-ch oidx = tid/40 over same pos40.
  int oidx = (tid < 240) ? (tid / 40) : -1;
  int pos40 = tid % 40;
  int psy = pos40 / 10, psx = pos40 % 10;

  float v[2][4];
#pragma unroll
  for (int sl = 0; sl < 2; sl++)
#pragma unroll
    for (int k = 0; k < 4; k++) v[sl][k] = 0.0f;
  double s_acc = 0.0, q_acc = 0.0;

  // prologue: prefetch t=0
  float rs[2] = {0.0f, 0.0f};
#pragma unroll
  for (int j = 0; j < 2; j++)
    if (s_in[j]) rs[j] = x[(size_t)(0 * B + b) * (H1 * W1) + s_off[j]];

  for (int t = 0; t < T; t++) {
    __syncthreads();  // full drain: prefetch complete, prev-iter readers done
#pragma unroll
    for (int j = 0; j < 2; j++)
      if (s_lofs[j] >= 0) tilf[s_lofs[j]] = rs[j];
    if (t + 1 < T) {
#pragma unroll
      for (int j = 0; j < 2; j++)
        if (s_in[j]) rs[j] = x[(size_t)((t + 1) * B + b) * (H1 * W1) + s_off[j]];
    }
    LDS_PHASE_BARRIER();  // tile ready; prefetch NOT drained
#pragma unroll
    for (int sl = 0; sl < 2; sl++) {
      if (hact[sl]) {
        float smax = 0.0f;
        if (hval[sl]) {
          int ry = 2 * hhy[sl], hx = hhx[sl];
          float p[16];
#pragma unroll
          for (int r = 0; r < 4; r++) {
            p[r * 4 + 0] = til[0][ry + r][hx];
            p[r * 4 + 1] = til[1][ry + r][hx];
            p[r * 4 + 2] = til[0][ry + r][hx + 1];
            p[r * 4 + 3] = til[1][ry + r][hx + 1];
          }
#pragma unroll
          for (int dy = 0; dy < 2; dy++) {
#pragma unroll
            for (int dx = 0; dx < 2; dx++) {
              float acc = 0.0f;
#pragma unroll
              for (int ky = 0; ky < 3; ky++)
#pragma unroll
                for (int kx = 0; kx < 3; kx++)
                  acc = fmaf(p[(dy + ky) * 4 + dx + kx], wv[sl][ky * 3 + kx], acc);
              float y = (acc - m_[sl]) * sc_[sl] + be_[sl];
              float sp = lif_step(v[sl][dy * 2 + dx], y);
              smax = fmaxf(smax, sp);
            }
          }
        }
        phl[tid + 256 * sl] = smax;  // == ch*72 + hy*12 + hx
        if (hown[sl])
          pool1[((size_t)(t * B + b) * 6 + hch[sl]) * (P1H * P1W) + hpy[sl] * P1W + hpx[sl]] = smax;
      }
    }
    LDS_PHASE_BARRIER();  // phl ready
    if (oidx >= 0) {  // partial: in-ch oidx(=i2), own pos (psy,psx)
      int i2 = oidx;
      float pt[9];
#pragma unroll
      for (int ky = 0; ky < 3; ky++)
#pragma unroll
        for (int kx = 0; kx < 3; kx++)
          pt[ky * 3 + kx] = phl[i2 * 72 + (psy + ky) * 12 + (psx + kx)];
      float p6[6];
#pragma unroll
      for (int o = 0; o < 6; o++) {
        float a = 0.0f;
#pragma unroll
        for (int k2 = 0; k2 < 9; k2++) a = fmaf(pt[k2], wsm2[(o * 6 + i2) * 9 + k2], a);
        p6[o] = a;
      }
#pragma unroll
      for (int o = 0; o < 6; o++) pr[pos40][i2][o] = p6[o];
    }
    LDS_PHASE_BARRIER();  // pr ready
    if (oidx >= 0) {  // reduce: out-ch oidx at pos40
      double acc = 0.0;
#pragma unroll
      for (int ic = 0; ic < 6; ic++) acc += (double)pr[pos40][ic][oidx];
      s_acc += acc;
      q_acc += acc * acc;
    }
  }
  __syncthreads();
  reduce12_sel(oidx, s_acc, q_acc, partials2);
}

// ---- fuse2 + stats3: own 4x5 pooled, halo 6x7 (252 conv threads) ----
__global__ void fuse2_stats(const float* __restrict__ in, const float* __restrict__ w2g,
                            const float* __restrict__ w3g,
                            const float* __restrict__ mean2, const float* __restrict__ sg2,
                            const float* __restrict__ beta2,
                            float* __restrict__ pool2, double* __restrict__ partials3) {
  __shared__ float wsm2[324];
  __shared__ float wsm3[324];
  __shared__ float til[2][6][14][9];
  __shared__ float phl[6][6][7];
  __shared__ float pr[20][6][7];  // [pos][i][o]

  int tid = threadIdx.x;
  for (int k = tid; k < 324; k += 256) { wsm2[k] = w2g[k]; wsm3[k] = w3g[k]; }

  int wg = blockIdx.x;
  int b = wg / 40;
  int rem = wg % 40;
  int oy = rem / 20, ox = rem % 20;
  int iy0 = 8 * oy - 3, ix0 = 10 * ox - 3;
  constexpr int HW = H2 * W2;

  bool s_in[6];
  int s_off[6], s_lofs[6];
#pragma unroll
  for (int j = 0; j < 6; j++) {
    int k = tid + 256 * j;
    bool valid = k < 1344;
    int i = k / 224;
    int r2 = k % 224;
    int rr = r2 / 16, cc = r2 % 16;
    int hh = iy0 + rr, ww = ix0 + cc;
    s_in[j] = valid && hh >= 0 && hh < H2 && ww >= 0 && ww < W2;
    s_off[j] = i * HW + hh * W2 + ww;
    s_lofs[j] = valid ? ((cc & 1) * 756 + i * 126 + rr * 9 + (cc >> 1)) : -1;
  }
  float* tilf = &til[0][0][0][0];

  bool active = tid < 252;
  int ch = 0, hy = 0, hx = 0, py = 0, px = 0;
  bool pvalid = false, own = false;
  if (active) {
    ch = tid / 42;
    int r = tid % 42;
    hy = r / 7; hx = r % 7;
    py = 4 * oy - 1 + hy; px = 5 * ox - 1 + hx;
    pvalid = (py >= 0 && py < P2H && px >= 0 && px < P2W);
    own = (hy >= 1 && hy <= 4 && hx >= 1 && hx <= 5);
  }
  float m = active ? mean2[ch] : 0.0f;
  float sc = active ? sg2[ch] : 0.0f;
  float be = active ? beta2[ch] : 0.0f;

  int oidx = (tid < 120) ? (tid / 20) : -1;
  int pos = tid % 20;
  int psy = pos / 5, psx = pos % 5;

  float v[4] = {0.0f, 0.0f, 0.0f, 0.0f};
  double s_acc = 0.0, q_acc = 0.0;

  float rs[6] = {0.0f, 0.0f, 0.0f, 0.0f, 0.0f, 0.0f};
  {
    const float* xb = in + (size_t)(0 * B + b) * 6 * HW;
#pragma unroll
    for (int j = 0; j < 6; j++)
      if (s_in[j]) rs[j] = xb[s_off[j]];
  }

  for (int t = 0; t < T; t++) {
    __syncthreads();
#pragma unroll
    for (int j = 0; j < 6; j++)
      if (s_lofs[j] >= 0) tilf[s_lofs[j]] = rs[j];
    if (t + 1 < T) {
      const float* xb = in + (size_t)((t + 1) * B + b) * 6 * HW;
#pragma unroll
      for (int j = 0; j < 6; j++)
        if (s_in[j]) rs[j] = xb[s_off[j]];
    }
    LDS_PHASE_BARRIER();
    if (active) {
      float smax = 0.0f;
      if (pvalid) {
        int ry = 2 * hy;
        float acc4[4] = {0.0f, 0.0f, 0.0f, 0.0f};
#pragma unroll
        for (int i = 0; i < 6; i++) {
          float p[16];
#pragma unroll
          for (int r = 0; r < 4; r++) {
            p[r * 4 + 0] = til[0][i][ry + r][hx];
            p[r * 4 + 1] = til[1][i][ry + r][hx];
            p[r * 4 + 2] = til[0][i][ry + r][hx + 1];
            p[r * 4 + 3] = til[1][i][ry + r][hx + 1];
          }
          const float* wo = &wsm2[(ch * 6 + i) * 9];
#pragma unroll
          for (int dy = 0; dy < 2; dy++)
#pragma unroll
            for (int dx = 0; dx < 2; dx++) {
              float a = acc4[dy * 2 + dx];
#pragma unroll
              for (int ky = 0; ky < 3; ky++)
#pragma unroll
                for (int kx = 0; kx < 3; kx++)
                  a = fmaf(p[(dy + ky) * 4 + dx + kx], wo[ky * 3 + kx], a);
              acc4[dy * 2 + dx] = a;
            }
        }
#pragma unroll
        for (int p4 = 0; p4 < 4; p4++) {
          float y = (acc4[p4] - m) * sc + be;
          float sp = lif_step(v[p4], y);
          smax = fmaxf(smax, sp);
        }
      }
      phl[ch][hy][hx] = smax;
      if (own)
        pool2[((size_t)(t * B + b) * 6 + ch) * (P2H * P2W) + py * P2W + px] = smax;
    }
    LDS_PHASE_BARRIER();
    if (oidx >= 0) {
      float pt[9];
#pragma unroll
      for (int ky = 0; ky < 3; ky++)
#pragma unroll
        for (int kx = 0; kx < 3; kx++)
          pt[ky * 3 + kx] = phl[oidx][psy + ky][psx + kx];
      float p6[6];
#pragma unroll
      for (int o = 0; o < 6; o++) {
        float a = 0.0f;
#pragma unroll
        for (int k2 = 0; k2 < 9; k2++) a = fmaf(pt[k2], wsm3[(o * 6 + oidx) * 9 + k2], a);
        p6[o] = a;
      }
#pragma unroll
      for (int o = 0; o < 6; o++) pr[pos][oidx][o] = p6[o];
    }
    LDS_PHASE_BARRIER();
    if (oidx >= 0) {
      double acc = 0.0;
#pragma unroll
      for (int ic = 0; ic < 6; ic++) acc += (double)pr[pos][ic][oidx];
      s_acc += acc;
      q_acc += acc * acc;
    }
  }
  __syncthreads();
  reduce12_sel(oidx, s_acc, q_acc, partials3);
}

// ---- block 3 fuse: conv(6->6)+BN+LIF+pool, parity-split LDS tiles ----
template <int H, int W, int PH, int PW, int TH, int TW>
__global__ void block6_fuse_lds(const float* __restrict__ in, const float* __restrict__ wt,
                                const float* __restrict__ mean, const float* __restrict__ sg,
                                const float* __restrict__ beta, float* __restrict__ out) {
  constexpr int NTH = PH / TH, NTW = PW / TW;
  constexpr int IH = 2 * TH + 2, IW = 2 * TW + 2;
  constexpr int EW = IW / 2;
  constexpr int TILE_N = IH * IW;
  constexpr int NACT = 6 * TH * TW;
  constexpr int HW = H * W;
  __shared__ float wsm[324];
  __shared__ float til_e[6][IH][EW];
  __shared__ float til_o[6][IH][EW];

  for (int k = threadIdx.x; k < 324; k += blockDim.x) wsm[k] = wt[k];

  int wg = blockIdx.x;
  int b = wg / (NTH * NTW);
  int tid2 = wg % (NTH * NTW);
  int ty = tid2 / NTW, tx = tid2 % NTW;
  int h_in0 = 2 * (ty * TH) - 1, w_in0 = 2 * (tx * TW) - 1;

  int tid = threadIdx.x;
  int o = 0, lph = 0, lpw = 0;
  if (tid < NACT) {
    o = tid / (TH * TW);
    int r = tid % (TH * TW);
    lph = r / TW; lpw = r % TW;
  }
  float m = mean[o], s = sg[o], be = beta[o];
  float v[4] = {0.0f, 0.0f, 0.0f, 0.0f};

  for (int t = 0; t < T; t++) {
    __syncthreads();
    const float* xb = in + (size_t)(t * B + b) * 6 * HW;
    for (int k = tid; k < 6 * TILE_N; k += blockDim.x) {
      int i = k / TILE_N;
      int r2 = k % TILE_N;
      int rr = r2 / IW, cc = r2 % IW;
      int hh = h_in0 + rr, ww = w_in0 + cc;
      float val = (hh >= 0 && hh < H && ww >= 0 && ww < W) ? xb[i * HW + hh * W + ww] : 0.0f;
      if (cc & 1) til_o[i][rr][cc >> 1] = val;
      else        til_e[i][rr][cc >> 1] = val;
    }
    __syncthreads();
    if (tid < NACT) {
      int ry = 2 * lph;
      float acc[4] = {0.0f, 0.0f, 0.0f, 0.0f};
#pragma unroll
      for (int i = 0; i < 6; i++) {
        float p[16];
#pragma unroll
        for (int r = 0; r < 4; r++) {
          p[r * 4 + 0] = til_e[i][ry + r][lpw];
          p[r * 4 + 1] = til_o[i][ry + r][lpw];
          p[r * 4 + 2] = til_e[i][ry + r][lpw + 1];
          p[r * 4 + 3] = til_o[i][ry + r][lpw + 1];
        }
        const float* wo = &wsm[(o * 6 + i) * 9];
#pragma unroll
        for (int dy = 0; dy < 2; dy++)
#pragma unroll
          for (int dx = 0; dx < 2; dx++) {
            float a = acc[dy * 2 + dx];
#pragma unroll
            for (int ky = 0; ky < 3; ky++)
#pragma unroll
              for (int kx = 0; kx < 3; kx++)
                a = fmaf(p[(dy + ky) * 4 + dx + kx], wo[ky * 3 + kx], a);
            acc[dy * 2 + dx] = a;
          }
      }
      float smax = 0.0f;
#pragma unroll
      for (int p4 = 0; p4 < 4; p4++) {
        float y = (acc[p4] - m) * s + be;
        float sp = lif_step(v[p4], y);
        smax = fmaxf(smax, sp);
      }
      out[((size_t)(t * B + b) * 6 + o) * (PH * PW) + (ty * TH + lph) * PW + (tx * TW + lpw)] = smax;
    }
  }
}

// ---- FC1 matmul ----
__global__ void fc1_mm(const float* __restrict__ p3, const float* __restrict__ fw1,
                       float* __restrict__ u1) {
  int idx = blockIdx.x * blockDim.x + threadIdx.x;
  if (idx >= T * B * 100) return;
  int o = idx % 100;
  int tb = idx / 100;
  const float4* x4 = (const float4*)(p3 + (size_t)tb * 1200);
  const float4* w4 = (const float4*)(fw1 + (size_t)o * 1200);
  float acc = 0.0f;
#pragma unroll 4
  for (int k = 0; k < 300; k++) {
    float4 a = x4[k], w = w4[k];
    acc = fmaf(a.x, w.x, acc);
    acc = fmaf(a.y, w.y, acc);
    acc = fmaf(a.z, w.z, acc);
    acc = fmaf(a.w, w.w, acc);
  }
  u1[idx] = acc;
}

// ---- fc tail: fc1-LIF + fc2 + fc2-LIF, one WG per batch ----
__global__ void fc_tail(const float* __restrict__ u1, const float* __restrict__ fw2,
                        float* __restrict__ outp) {
  __shared__ float s1[100];
  __shared__ float w2s[200];
  int b = blockIdx.x;
  int tid = threadIdx.x;
  for (int k = tid; k < 200; k += 128) w2s[k] = fw2[k];
  float v1 = 0.0f, v2 = 0.0f;
  __syncthreads();
  for (int t = 0; t < T; t++) {
    if (tid < 100) {
      float sp = lif_step(v1, u1[(size_t)(t * B + b) * 100 + tid]);
      s1[tid] = sp;
    }
    __syncthreads();
    if (tid < 2) {
      const float* wr = &w2s[tid * 100];
      float acc = 0.0f;
#pragma unroll
      for (int k = 0; k < 100; k++) acc = fmaf(s1[k], wr[k], acc);
      float sp = lif_step(v2, acc);
      outp[(size_t)(t * B + b) * 2 + tid] = sp;
    }
    __syncthreads();
  }
}

extern "C" void kernel_launch(void* const* d_in, const int* in_sizes, int n_in,
                              void* d_out, int out_size, void* d_ws, size_t ws_size,
                              hipStream_t stream) {
  const float* x   = (const float*)d_in[0];
  const float* w1  = (const float*)d_in[1];
  const float* g1  = (const float*)d_in[2];
  const float* b1  = (const float*)d_in[3];
  const float* w2  = (const float*)d_in[4];
  const float* g2  = (const float*)d_in[5];
  const float* b2  = (const float*)d_in[6];
  const float* w3  = (const float*)d_in[7];
  const float* g3  = (const float*)d_in[8];
  const float* b3  = (const float*)d_in[9];
  const float* fw1 = (const float*)d_in[10];
  const float* fw2 = (const float*)d_in[11];
  float* out = (float*)d_out;

  char* ws = (char*)d_ws;
  double* part1  = (double*)(ws + OFF_PART1);
  double* partf1 = (double*)(ws + OFF_PARTF1);
  double* partf2 = (double*)(ws + OFF_PARTF2);
  float* mean1 = (float*)(ws + OFF_STATS + 0);
  float* sg1   = (float*)(ws + OFF_STATS + 32);
  float* mean2 = (float*)(ws + OFF_STATS + 64);
  float* sg2   = (float*)(ws + OFF_STATS + 96);
  float* mean3 = (float*)(ws + OFF_STATS + 128);
  float* sg3   = (float*)(ws + OFF_STATS + 160);
  float* pool1 = (float*)(ws + OFF_POOL1);
  float* pool2 = (float*)(ws + OFF_POOL2);
  float* pool3 = (float*)(ws + OFF_POOL3);
  float* u1    = (float*)(ws + OFF_U1);

  // Block 1 stats + finalize
  conv_stats_lds<1, H1, W1, 32, 100><<<NWG_S1, 256, 0, stream>>>(x, w1, part1);
  finalize_stats<<<1, 256, 0, stream>>>(part1, NWG_S1, (double)T * B * H1 * W1, g1, mean1, sg1);
  // fuse1 (+ stats for block2)
  fuse1_stats<<<NWG_F1, 256, 0, stream>>>(x, w1, w2, mean1, sg1, b1, pool1, partf1);
  finalize_stats<<<1, 256, 0, stream>>>(partf1, NWG_F1, (double)T * B * H2 * W2, g2, mean2, sg2);
  // fuse2 (+ stats for block3)
  fuse2_stats<<<NWG_F2, 256, 0, stream>>>(pool1, w2, w3, mean2, sg2, b2, pool2, partf2);
  finalize_stats<<<1, 256, 0, stream>>>(partf2, NWG_F2, (double)T * B * H3 * W3, g3, mean3, sg3);
  // Block 3 fuse
  {
    int nwg = B * (P3H / 2) * (P3W / 5);  // 640
    block6_fuse_lds<H3, W3, P3H, P3W, 2, 5><<<nwg, 64, 0, stream>>>(pool2, w3, mean3, sg3, b3, pool3);
  }
  // FC head
  {
    int n = T * B * 100;
    fc1_mm<<<(n + 255) / 256, 256, 0, stream>>>(pool3, fw1, u1);
  }
  fc_tail<<<B, 128, 0, stream>>>(u1, fw2, out);
}